// Round 1
// baseline (4064.981 us; speedup 1.0000x reference)
//
#include <hip/hip_runtime.h>
#include <cstdint>
#include <cmath>

// ---------------------------------------------------------------------------
// Informer encoder forward (B=4, L=2048, ENC_IN=32, D_MODEL=512, D_FF=2048,
// E_LAYERS=2, H=8, FACTOR=5) — full fp32 implementation.
// ---------------------------------------------------------------------------

#define NB 4          // batch
#define DM 512        // d_model
#define NH 8          // heads
#define HD 64         // head dim

// ---------------- Threefry2x32 (exact JAX semantics) -----------------------
__host__ __device__ inline void threefry2x32(uint32_t k0, uint32_t k1,
                                             uint32_t c0, uint32_t c1,
                                             uint32_t* o0, uint32_t* o1) {
  uint32_t ks0 = k0, ks1 = k1, ks2 = k0 ^ k1 ^ 0x1BD11BDAu;
  uint32_t x0 = c0 + ks0;
  uint32_t x1 = c1 + ks1;
  const uint32_t rotA[4] = {13u, 15u, 26u, 6u};
  const uint32_t rotB[4] = {17u, 29u, 16u, 24u};
  uint32_t ks[3] = {ks0, ks1, ks2};
  #pragma unroll
  for (int i = 0; i < 5; ++i) {
    const uint32_t* r = (i & 1) ? rotB : rotA;
    #pragma unroll
    for (int j = 0; j < 4; ++j) {
      x0 += x1;
      x1 = (x1 << r[j]) | (x1 >> (32u - r[j]));
      x1 ^= x0;
    }
    x0 += ks[(i + 1) % 3];
    x1 += ks[(i + 2) % 3] + (uint32_t)(i + 1);
  }
  *o0 = x0; *o1 = x1;
}

// idx[i] = (tf0 ^ tf1)(k2, c=(0,i)) & mask   (partitionable random_bits, 32-bit)
__global__ void gen_idx_k(int* __restrict__ idx, int n, int mask,
                          uint32_t k0, uint32_t k1) {
  int i = blockIdx.x * 256 + threadIdx.x;
  if (i < n) {
    uint32_t o0, o1;
    threefry2x32(k0, k1, 0u, (uint32_t)i, &o0, &o1);
    idx[i] = (int)((o0 ^ o1) & (uint32_t)mask);
  }
}

// ---------------- wave helpers ---------------------------------------------
__device__ inline float wave_sum64(float v) {
  #pragma unroll
  for (int o = 32; o > 0; o >>= 1) v += __shfl_xor(v, o, 64);
  return v;
}

// ---------------- token embedding + positional encoding --------------------
// X[b,l,d] = sum_{c,t} x_enc[b,(l+t-1)%2048,c]*tok_w[d,c,t] + pe[l,d]
__global__ __launch_bounds__(256) void token_embed_k(
    const float* __restrict__ xe, const float* __restrict__ w,
    float* __restrict__ X) {
  int bl = blockIdx.x;
  int b = bl >> 11, l = bl & 2047;
  __shared__ float xin[3][32];
  int t = threadIdx.x;
  if (t < 96) {
    int tt = t >> 5, c = t & 31;
    int ls = (l + tt - 1) & 2047;
    xin[tt][c] = xe[((size_t)b * 2048 + ls) * 32 + c];
  }
  __syncthreads();
  float pos = (float)l;
  for (int d = t; d < DM; d += 256) {
    float acc = 0.f;
    const float* wd = &w[d * 96];
    #pragma unroll
    for (int c = 0; c < 32; ++c) {
      acc += xin[0][c] * wd[c * 3 + 0] + xin[1][c] * wd[c * 3 + 1] +
             xin[2][c] * wd[c * 3 + 2];
    }
    int j2 = d & ~1;
    float div = expf((float)j2 * -1.7988946039e-2f);  // -ln(10000)/512
    float pe = (d & 1) ? cosf(pos * div) : sinf(pos * div);
    X[((size_t)b * 2048 + l) * DM + d] = acc + pe;
  }
}

// ---------------- generic GEMM: C = act(A @ W^T + bias) --------------------
// A: M x K (row-major), W: N x K (row-major), C: M x N.  M%64==0, K%16==0.
#define BM 64
#define BN 64
#define BK 16
template <int ACT>  // 0 = none, 1 = exact GELU
__global__ __launch_bounds__(256) void gemm_k(
    const float* __restrict__ A, const float* __restrict__ W,
    const float* __restrict__ bias, float* __restrict__ C,
    int M, int N, int K) {
  __shared__ float As[BK][BM + 4];
  __shared__ float Ws[BK][BN + 4];
  int m0 = blockIdx.y * BM, n0 = blockIdx.x * BN;
  int t = threadIdx.x;
  int tx = t & 15, ty = t >> 4;
  float acc[4][4] = {};
  for (int k0 = 0; k0 < K; k0 += BK) {
    #pragma unroll
    for (int i = 0; i < 4; ++i) {
      int li = t + i * 256;
      int m = li >> 4, kk = li & 15;
      As[kk][m] = A[(size_t)(m0 + m) * K + k0 + kk];
    }
    #pragma unroll
    for (int i = 0; i < 4; ++i) {
      int li = t + i * 256;
      int n = li >> 4, kk = li & 15;
      int gn = n0 + n;
      Ws[kk][n] = (gn < N) ? W[(size_t)gn * K + k0 + kk] : 0.0f;
    }
    __syncthreads();
    #pragma unroll
    for (int kk = 0; kk < BK; ++kk) {
      float4 av = *(const float4*)&As[kk][ty * 4];
      float4 bv = *(const float4*)&Ws[kk][tx * 4];
      float a[4] = {av.x, av.y, av.z, av.w};
      float bb[4] = {bv.x, bv.y, bv.z, bv.w};
      #pragma unroll
      for (int i = 0; i < 4; ++i)
        #pragma unroll
        for (int j = 0; j < 4; ++j) acc[i][j] += a[i] * bb[j];
    }
    __syncthreads();
  }
  #pragma unroll
  for (int i = 0; i < 4; ++i) {
    int m = m0 + ty * 4 + i;
    #pragma unroll
    for (int j = 0; j < 4; ++j) {
      int n = n0 + tx * 4 + j;
      if (n < N) {
        float v = acc[i][j] + bias[n];
        if (ACT == 1) v = 0.5f * v * (1.0f + erff(v * 0.70710678118654752f));
        C[(size_t)m * N + n] = v;
      }
    }
  }
}

// ---------------- LayerNorm over last dim (512), optional residual ---------
__global__ __launch_bounds__(128) void ln_k(
    const float* __restrict__ A, const float* __restrict__ Bres,
    const float* __restrict__ g, const float* __restrict__ be,
    float* __restrict__ O) {
  int r = blockIdx.x, t = threadIdx.x;
  __shared__ float lds[2];
  float4 v = ((const float4*)(A + (size_t)r * DM))[t];
  if (Bres) {
    float4 u = ((const float4*)(Bres + (size_t)r * DM))[t];
    v.x += u.x; v.y += u.y; v.z += u.z; v.w += u.w;
  }
  float s = wave_sum64(v.x + v.y + v.z + v.w);
  int w = t >> 6;
  if ((t & 63) == 0) lds[w] = s;
  __syncthreads();
  float mu = (lds[0] + lds[1]) * (1.0f / 512.0f);
  __syncthreads();
  float dx = v.x - mu, dy = v.y - mu, dz = v.z - mu, dw = v.w - mu;
  float sq = wave_sum64(dx * dx + dy * dy + dz * dz + dw * dw);
  if ((t & 63) == 0) lds[w] = sq;
  __syncthreads();
  float var = (lds[0] + lds[1]) * (1.0f / 512.0f);
  float inv = 1.0f / sqrtf(var + 1e-5f);
  float4 gv = ((const float4*)g)[t];
  float4 bv = ((const float4*)be)[t];
  float4 o;
  o.x = dx * inv * gv.x + bv.x;
  o.y = dy * inv * gv.y + bv.y;
  o.z = dz * inv * gv.z + bv.z;
  o.w = dw * inv * gv.w + bv.w;
  ((float4*)(O + (size_t)r * DM))[t] = o;
}

// ---------------- M[b,h,l] = max_u(q.k_idx) - sum_u(q.k_idx)/Lx ------------
__global__ __launch_bounds__(256) void qk_m_k(
    const float* __restrict__ Q, const float* __restrict__ K,
    const int* __restrict__ idx, float* __restrict__ Mout, int Lx, int U) {
  int item = (blockIdx.x << 2) | (threadIdx.x >> 6);
  int lane = threadIdx.x & 63;
  int l = item % Lx;
  int bh = item / Lx;
  int h = bh & 7, b = bh >> 3;
  float qd = Q[((size_t)b * Lx + l) * DM + h * HD + lane];
  float maxv = -INFINITY, sumv = 0.f;
  for (int u = 0; u < U; ++u) {
    int ki = idx[l * U + u];
    float kd = K[((size_t)b * Lx + ki) * DM + h * HD + lane];
    float p = qd * kd;
    p = wave_sum64(p);
    maxv = fmaxf(maxv, p);
    sumv += p;
  }
  if (lane == 0) Mout[item] = maxv - sumv / (float)Lx;
}

// ---------------- top-U indices of M per (b,h), jax tie-breaking -----------
__global__ __launch_bounds__(256) void topk_k(
    const float* __restrict__ Mbuf, int* __restrict__ Mtop, int Lx, int U) {
  int bh = blockIdx.x;
  const float* m = Mbuf + (size_t)bh * Lx;
  __shared__ float mcopy[2048];
  __shared__ float sv[256];
  __shared__ int si[256];
  int t = threadIdx.x;
  for (int i = t; i < Lx; i += 256) mcopy[i] = m[i];
  __syncthreads();
  for (int u = 0; u < U; ++u) {
    float bv = -INFINITY;
    int bi = 0x7fffffff;
    for (int i = t; i < Lx; i += 256) {
      float v = mcopy[i];
      if (v > bv || (v == bv && i < bi)) { bv = v; bi = i; }
    }
    sv[t] = bv; si[t] = bi;
    __syncthreads();
    for (int s = 128; s > 0; s >>= 1) {
      if (t < s) {
        float v2 = sv[t + s]; int i2 = si[t + s];
        if (v2 > sv[t] || (v2 == sv[t] && i2 < si[t])) { sv[t] = v2; si[t] = i2; }
      }
      __syncthreads();
    }
    if (t == 0) {
      Mtop[bh * U + u] = si[0];
      mcopy[si[0]] = -INFINITY;
    }
    __syncthreads();
  }
}

// ---------------- meanV[b,h,d] over sequence -------------------------------
__global__ void meanv_k(const float* __restrict__ V, float* __restrict__ mv,
                        int Lx) {
  int bh = blockIdx.x;
  int d = threadIdx.x;  // 64
  int h = bh & 7, b = bh >> 3;
  const float* vp = V + (size_t)b * Lx * DM + h * HD + d;
  float s = 0.f;
  for (int l = 0; l < Lx; ++l) s += vp[(size_t)l * DM];
  mv[bh * HD + d] = s / (float)Lx;
}

// ---------------- ctx[b,l,:] = meanV (broadcast) ---------------------------
__global__ void fillctx_k(float* __restrict__ ctx, const float* __restrict__ mv,
                          int Lx) {
  size_t i = (size_t)blockIdx.x * 256 + threadIdx.x;
  int col = (int)(i & 511);
  size_t row = i >> 9;
  int b = (int)(row / (size_t)Lx);
  ctx[i] = mv[b * DM + col];
}

// ---------------- full attention for top-U queries, scatter into ctx -------
__global__ __launch_bounds__(256) void attn_top_k(
    const float* __restrict__ Q, const float* __restrict__ K,
    const float* __restrict__ V, const int* __restrict__ Mtop,
    float* __restrict__ ctx, int Lx, int U) {
  int item = blockIdx.x;  // (b*8+h)*U + u
  int u = item % U;
  int bh = item / U;
  int h = bh & 7, b = bh >> 3;
  __shared__ float sc[2048];
  __shared__ float qrow[64];
  __shared__ float red[256];
  int t = threadIdx.x;
  int qi = Mtop[bh * U + u];
  if (t < 64) qrow[t] = Q[((size_t)b * Lx + qi) * DM + h * HD + t];
  __syncthreads();
  for (int k = t; k < Lx; k += 256) {
    const float* kr = K + ((size_t)b * Lx + k) * DM + h * HD;
    float acc = 0.f;
    #pragma unroll
    for (int d = 0; d < 64; d += 4) {
      float4 kv = *(const float4*)&kr[d];
      acc += qrow[d] * kv.x + qrow[d + 1] * kv.y + qrow[d + 2] * kv.z +
             qrow[d + 3] * kv.w;
    }
    sc[k] = acc * 0.125f;  // 1/sqrt(64)
  }
  __syncthreads();
  float mx = -INFINITY;
  for (int k = t; k < Lx; k += 256) mx = fmaxf(mx, sc[k]);
  red[t] = mx;
  __syncthreads();
  for (int s = 128; s > 0; s >>= 1) {
    if (t < s) red[t] = fmaxf(red[t], red[t + s]);
    __syncthreads();
  }
  mx = red[0];
  __syncthreads();
  float ps = 0.f;
  for (int k = t; k < Lx; k += 256) {
    float e = expf(sc[k] - mx);
    sc[k] = e;
    ps += e;
  }
  red[t] = ps;
  __syncthreads();
  for (int s = 128; s > 0; s >>= 1) {
    if (t < s) red[t] += red[t + s];
    __syncthreads();
  }
  float denom = red[0];
  __syncthreads();
  int d = t & 63, chunk = t >> 6;
  int kpc = Lx >> 2;
  float acc = 0.f;
  const float* vb = V + (size_t)b * Lx * DM + h * HD + d;
  for (int k = chunk * kpc; k < (chunk + 1) * kpc; ++k)
    acc += sc[k] * vb[(size_t)k * DM];
  red[t] = acc;
  __syncthreads();
  if (t < 64) {
    float r = red[t] + red[64 + t] + red[128 + t] + red[192 + t];
    ctx[((size_t)b * Lx + qi) * DM + h * HD + t] = r / denom;
  }
}

// ---------------- im2col for distil conv (circular, k=3) -------------------
__global__ void im2col_k(const float* __restrict__ X, float* __restrict__ A2) {
  size_t gid = (size_t)blockIdx.x * 256 + threadIdx.x;  // 8192*1536
  int col = (int)(gid % 1536);
  size_t row = gid / 1536;
  int i = col / 3, tt = col % 3;
  int b = (int)(row >> 11), l = (int)(row & 2047);
  int ls = (l + tt - 1) & 2047;
  A2[gid] = X[((size_t)b * 2048 + ls) * DM + i];
}

// ---------------- batch-norm stats (two-pass) per channel ------------------
__global__ __launch_bounds__(256) void bn_stats_k(
    const float* __restrict__ Y, float* __restrict__ mu,
    float* __restrict__ var) {
  int c = blockIdx.x;
  __shared__ float red[256];
  int t = threadIdx.x;
  float s = 0.f;
  for (int j = t; j < 8192; j += 256) s += Y[(size_t)j * DM + c];
  red[t] = s;
  __syncthreads();
  for (int o = 128; o > 0; o >>= 1) {
    if (t < o) red[t] += red[t + o];
    __syncthreads();
  }
  float m = red[0] / 8192.f;
  __syncthreads();
  float sq = 0.f;
  for (int j = t; j < 8192; j += 256) {
    float dlt = Y[(size_t)j * DM + c] - m;
    sq += dlt * dlt;
  }
  red[t] = sq;
  __syncthreads();
  for (int o = 128; o > 0; o >>= 1) {
    if (t < o) red[t] += red[t + o];
    __syncthreads();
  }
  if (t == 0) { mu[c] = m; var[c] = red[0] / 8192.f; }
}

__global__ void bn_elu_k(const float* __restrict__ Y,
                         const float* __restrict__ mu,
                         const float* __restrict__ var,
                         const float* __restrict__ g,
                         const float* __restrict__ be, float* __restrict__ O) {
  size_t i = (size_t)blockIdx.x * 256 + threadIdx.x;
  int c = (int)(i & 511);
  float v = (Y[i] - mu[c]) / sqrtf(var[c] + 1e-5f) * g[c] + be[c];
  O[i] = v > 0.f ? v : expm1f(v);
}

// ---------------- maxpool k=3 s=2 pad=1 over sequence ----------------------
__global__ void maxpool_k(const float* __restrict__ Y, float* __restrict__ O) {
  size_t i = (size_t)blockIdx.x * 256 + threadIdx.x;  // 4*1024*512
  int c = (int)(i & 511);
  size_t row = i >> 9;
  int lo = (int)(row & 1023);
  int b = (int)(row >> 10);
  int l0 = 2 * lo - 1;
  float m = -INFINITY;
  #pragma unroll
  for (int tt = 0; tt < 3; ++tt) {
    int l = l0 + tt;
    if (l >= 0 && l < 2048) m = fmaxf(m, Y[((size_t)b * 2048 + l) * DM + c]);
  }
  O[i] = m;
}

// ---------------------------------------------------------------------------
extern "C" void kernel_launch(void* const* d_in, const int* in_sizes, int n_in,
                              void* d_out, int out_size, void* d_ws,
                              size_t ws_size, hipStream_t stream) {
  (void)in_sizes; (void)n_in; (void)out_size; (void)ws_size;
  const float* x_enc  = (const float*)d_in[0];
  const float* tok_w  = (const float*)d_in[1];
  const float* Wq     = (const float*)d_in[2];
  const float* bq     = (const float*)d_in[3];
  const float* Wk     = (const float*)d_in[4];
  const float* bk     = (const float*)d_in[5];
  const float* Wv     = (const float*)d_in[6];
  const float* bv     = (const float*)d_in[7];
  const float* Wo     = (const float*)d_in[8];
  const float* bo     = (const float*)d_in[9];
  const float* W1     = (const float*)d_in[10];
  const float* b1     = (const float*)d_in[11];
  const float* W2     = (const float*)d_in[12];
  const float* b2     = (const float*)d_in[13];
  const float* ln1_g  = (const float*)d_in[14];
  const float* ln1_b  = (const float*)d_in[15];
  const float* ln2_g  = (const float*)d_in[16];
  const float* ln2_b  = (const float*)d_in[17];
  const float* conv_w = (const float*)d_in[18];
  const float* conv_b = (const float*)d_in[19];
  const float* bn_g   = (const float*)d_in[20];
  const float* bn_b   = (const float*)d_in[21];
  const float* normf_g = (const float*)d_in[22];
  const float* normf_b = (const float*)d_in[23];
  const float* proj_w = (const float*)d_in[24];
  const float* proj_b = (const float*)d_in[25];
  float* out = (float*)d_out;
  float* ws = (float*)d_ws;

  // workspace layout (floats)
  float* X    = ws;                  // 4,194,304
  float* Qb   = ws + 4194304;        // 4,194,304
  float* Kb   = ws + 8388608;        // 4,194,304
  float* Vb   = ws + 12582912;       // 4,194,304
  float* CTX  = ws + 16777216;       // 4,194,304
  float* H    = ws + 20971520;       // 16,777,216 (FFN hidden / im2col / elu buf)
  float* Y2   = ws + 37748736;       // 4,194,304
  float* Mb   = ws + 41943040;       // 65,536
  float* MV   = ws + 42008576;       // 2,048
  float* BNmu = ws + 42010624;       // 512
  float* BNvr = ws + 42011136;       // 512
  int*   IDX  = (int*)(ws + 42011648);  // 81,920
  int*   MT   = (int*)(ws + 42093568);  // 1,280

  // 1. token embedding + positional encoding
  token_embed_k<<<NB * 2048, 256, 0, stream>>>(x_enc, tok_w, X);

  for (int layer = 0; layer < 2; ++layer) {
    const int Lx = (layer == 0) ? 2048 : 1024;
    const int U  = (layer == 0) ? 40 : 35;   // FACTOR*ceil(ln(Lx))
    const int M  = NB * Lx;

    // sampling indices: JAX partitionable threefry
    uint32_t kl0, kl1, s0, s1, d0, d1;
    threefry2x32(0u, 42u, 0u, (uint32_t)layer, &kl0, &kl1);  // keys[layer]
    threefry2x32(kl0, kl1, 0u, 1u, &s0, &s1);                // k2 = split(key)[1]
    d0 = s0; d1 = s1;
    int nidx = Lx * U;
    gen_idx_k<<<(nidx + 255) / 256, 256, 0, stream>>>(IDX, nidx, Lx - 1, d0, d1);

    const float* wq = Wq + (size_t)layer * DM * DM;
    const float* wk = Wk + (size_t)layer * DM * DM;
    const float* wv = Wv + (size_t)layer * DM * DM;
    const float* wo = Wo + (size_t)layer * DM * DM;

    gemm_k<0><<<dim3(8, M / 64), 256, 0, stream>>>(X, wq, bq + layer * DM, Qb, M, DM, DM);
    gemm_k<0><<<dim3(8, M / 64), 256, 0, stream>>>(X, wk, bk + layer * DM, Kb, M, DM, DM);
    gemm_k<0><<<dim3(8, M / 64), 256, 0, stream>>>(X, wv, bv + layer * DM, Vb, M, DM, DM);

    qk_m_k<<<NB * NH * Lx / 4, 256, 0, stream>>>(Qb, Kb, IDX, Mb, Lx, U);
    topk_k<<<NB * NH, 256, 0, stream>>>(Mb, MT, Lx, U);
    meanv_k<<<NB * NH, 64, 0, stream>>>(Vb, MV, Lx);
    fillctx_k<<<(M * DM) / 256, 256, 0, stream>>>(CTX, MV, Lx);
    attn_top_k<<<NB * NH * U, 256, 0, stream>>>(Qb, Kb, Vb, MT, CTX, Lx, U);

    gemm_k<0><<<dim3(8, M / 64), 256, 0, stream>>>(CTX, wo, bo + layer * DM, Y2, M, DM, DM);
    ln_k<<<M, 128, 0, stream>>>(X, Y2, ln1_g + layer * DM, ln1_b + layer * DM, X);

    gemm_k<1><<<dim3(32, M / 64), 256, 0, stream>>>(
        X, W1 + (size_t)layer * 2048 * DM, b1 + layer * 2048, H, M, 2048, DM);
    gemm_k<0><<<dim3(8, M / 64), 256, 0, stream>>>(
        H, W2 + (size_t)layer * DM * 2048, b2 + layer * DM, Y2, M, DM, 2048);
    ln_k<<<M, 128, 0, stream>>>(X, Y2, ln2_g + layer * DM, ln2_b + layer * DM, X);

    if (layer == 0) {
      im2col_k<<<(8192 * 1536) / 256, 256, 0, stream>>>(X, H);
      gemm_k<0><<<dim3(8, 8192 / 64), 256, 0, stream>>>(H, conv_w, conv_b, CTX,
                                                        8192, DM, 1536);
      bn_stats_k<<<512, 256, 0, stream>>>(CTX, BNmu, BNvr);
      bn_elu_k<<<(8192 * 512) / 256, 256, 0, stream>>>(CTX, BNmu, BNvr, bn_g,
                                                       bn_b, H);
      maxpool_k<<<(NB * 1024 * 512) / 256, 256, 0, stream>>>(H, X);
    }
  }

  // final layer norm + projection to ENC_IN=32
  ln_k<<<NB * 1024, 128, 0, stream>>>(X, nullptr, normf_g, normf_b, Qb);
  gemm_k<0><<<dim3(1, 4096 / 64), 256, 0, stream>>>(Qb, proj_w, proj_b, out,
                                                    4096, 32, DM);
}

// Round 2
// 1974.704 us; speedup vs baseline: 2.0585x; 2.0585x over previous
//
#include <hip/hip_runtime.h>
#include <cstdint>
#include <cmath>

// ---------------------------------------------------------------------------
// Informer encoder forward (B=4, L=2048, ENC_IN=32, D_MODEL=512, D_FF=2048,
// E_LAYERS=2, H=8, FACTOR=5).
// Round 2: bf16-MFMA GEMMs (m97 structure), parallel meanV / BN stats.
// ---------------------------------------------------------------------------

#define NB 4
#define DM 512
#define NH 8
#define HD 64

typedef unsigned short ushort_t;
typedef __bf16 bf16x8 __attribute__((ext_vector_type(8)));
typedef float floatx4 __attribute__((ext_vector_type(4)));

// ---------------- fp32 -> bf16 (RNE) ---------------------------------------
__device__ inline ushort_t f2b(float f) {
  uint32_t u = __float_as_uint(f);
  uint32_t r = (u + 0x7fffu + ((u >> 16) & 1u)) >> 16;
  return (ushort_t)r;
}

__global__ void castb_k(const float* __restrict__ in,
                        ushort_t* __restrict__ out, int n4) {
  int i = blockIdx.x * 256 + threadIdx.x;
  if (i < n4) {
    float4 v = ((const float4*)in)[i];
    ushort4 o;
    o.x = f2b(v.x); o.y = f2b(v.y); o.z = f2b(v.z); o.w = f2b(v.w);
    ((ushort4*)out)[i] = o;
  }
}

// ---------------- Threefry2x32 (exact JAX semantics) -----------------------
__host__ __device__ inline void threefry2x32(uint32_t k0, uint32_t k1,
                                             uint32_t c0, uint32_t c1,
                                             uint32_t* o0, uint32_t* o1) {
  uint32_t ks0 = k0, ks1 = k1, ks2 = k0 ^ k1 ^ 0x1BD11BDAu;
  uint32_t x0 = c0 + ks0;
  uint32_t x1 = c1 + ks1;
  const uint32_t rotA[4] = {13u, 15u, 26u, 6u};
  const uint32_t rotB[4] = {17u, 29u, 16u, 24u};
  uint32_t ks[3] = {ks0, ks1, ks2};
  #pragma unroll
  for (int i = 0; i < 5; ++i) {
    const uint32_t* r = (i & 1) ? rotB : rotA;
    #pragma unroll
    for (int j = 0; j < 4; ++j) {
      x0 += x1;
      x1 = (x1 << r[j]) | (x1 >> (32u - r[j]));
      x1 ^= x0;
    }
    x0 += ks[(i + 1) % 3];
    x1 += ks[(i + 2) % 3] + (uint32_t)(i + 1);
  }
  *o0 = x0; *o1 = x1;
}

__global__ void gen_idx_k(int* __restrict__ idx, int n, int mask,
                          uint32_t k0, uint32_t k1) {
  int i = blockIdx.x * 256 + threadIdx.x;
  if (i < n) {
    uint32_t o0, o1;
    threefry2x32(k0, k1, 0u, (uint32_t)i, &o0, &o1);
    idx[i] = (int)((o0 ^ o1) & (uint32_t)mask);
  }
}

// ---------------- wave helpers ---------------------------------------------
__device__ inline float wave_sum64(float v) {
  #pragma unroll
  for (int o = 32; o > 0; o >>= 1) v += __shfl_xor(v, o, 64);
  return v;
}

// ---------------- token embedding + positional encoding --------------------
__global__ __launch_bounds__(256) void token_embed_k(
    const float* __restrict__ xe, const float* __restrict__ w,
    float* __restrict__ X) {
  int bl = blockIdx.x;
  int b = bl >> 11, l = bl & 2047;
  __shared__ float xin[3][32];
  int t = threadIdx.x;
  if (t < 96) {
    int tt = t >> 5, c = t & 31;
    int ls = (l + tt - 1) & 2047;
    xin[tt][c] = xe[((size_t)b * 2048 + ls) * 32 + c];
  }
  __syncthreads();
  float pos = (float)l;
  for (int d = t; d < DM; d += 256) {
    float acc = 0.f;
    const float* wd = &w[d * 96];
    #pragma unroll
    for (int c = 0; c < 32; ++c) {
      acc += xin[0][c] * wd[c * 3 + 0] + xin[1][c] * wd[c * 3 + 1] +
             xin[2][c] * wd[c * 3 + 2];
    }
    int j2 = d & ~1;
    float div = expf((float)j2 * -1.7988946039e-2f);  // -ln(10000)/512
    float pe = (d & 1) ? cosf(pos * div) : sinf(pos * div);
    X[((size_t)b * 2048 + l) * DM + d] = acc + pe;
  }
}

// ---------------- bf16 MFMA GEMM: C = act(A @ W^T + bias) ------------------
// A: M x K bf16 row-major; W: N x K bf16 row-major; M%128==0, N%128==0, K%32==0.
// m97 structure: 128x128 tile, BK=32, global_load_lds(16B), 4 waves x 4x4 tiles.
__device__ inline void gload16(const ushort_t* g, ushort_t* l) {
  __builtin_amdgcn_global_load_lds(
      (const __attribute__((address_space(1))) unsigned int*)(const void*)g,
      (__attribute__((address_space(3))) unsigned int*)(void*)l, 16, 0, 0);
}

template <int GELU, int OBF>
__global__ __launch_bounds__(256) void mgemm_k(
    const ushort_t* __restrict__ A, const ushort_t* __restrict__ W,
    const float* __restrict__ bias, float* __restrict__ Cf,
    ushort_t* __restrict__ Cb, int M, int N, int K) {
  __shared__ ushort_t As[128 * 32];
  __shared__ ushort_t Bs[128 * 32];
  int m0 = blockIdx.y * 128, n0 = blockIdx.x * 128;
  int t = threadIdx.x;
  int lane = t & 63, wv = t >> 6;
  // staging addresses: chunk = wv*2 + i covers rows [chunk*16, chunk*16+16)
  int sr = lane >> 2, sc = (lane & 3) * 8;
  int ra0 = wv * 32 + sr, ra1 = ra0 + 16;
  const ushort_t* gA0 = A + (size_t)(m0 + ra0) * K + sc;
  const ushort_t* gA1 = A + (size_t)(m0 + ra1) * K + sc;
  const ushort_t* gB0 = W + (size_t)(n0 + ra0) * K + sc;
  const ushort_t* gB1 = W + (size_t)(n0 + ra1) * K + sc;
  ushort_t* lA0 = As + wv * 1024;
  ushort_t* lA1 = lA0 + 512;
  ushort_t* lB0 = Bs + wv * 1024;
  ushort_t* lB1 = lB0 + 512;

  int quad = lane >> 4, lr = lane & 15;
  int wm = wv >> 1, wn = wv & 1;

  floatx4 acc[4][4] = {};
  for (int ks = 0; ks < K; ks += 32) {
    gload16(gA0, lA0);
    gload16(gA1, lA1);
    gload16(gB0, lB0);
    gload16(gB1, lB1);
    gA0 += 32; gA1 += 32; gB0 += 32; gB1 += 32;
    __syncthreads();
    bf16x8 av[4], bv[4];
    #pragma unroll
    for (int mt = 0; mt < 4; ++mt)
      av[mt] = *(const bf16x8*)&As[(wm * 64 + mt * 16 + lr) * 32 + quad * 8];
    #pragma unroll
    for (int nt = 0; nt < 4; ++nt)
      bv[nt] = *(const bf16x8*)&Bs[(wn * 64 + nt * 16 + lr) * 32 + quad * 8];
    #pragma unroll
    for (int mt = 0; mt < 4; ++mt)
      #pragma unroll
      for (int nt = 0; nt < 4; ++nt)
        acc[mt][nt] = __builtin_amdgcn_mfma_f32_16x16x32_bf16(
            av[mt], bv[nt], acc[mt][nt], 0, 0, 0);
    __syncthreads();
  }
  #pragma unroll
  for (int nt = 0; nt < 4; ++nt) {
    int col = n0 + wn * 64 + nt * 16 + lr;
    float bsv = bias[col];
    #pragma unroll
    for (int mt = 0; mt < 4; ++mt) {
      int row0 = m0 + wm * 64 + mt * 16 + quad * 4;
      #pragma unroll
      for (int r = 0; r < 4; ++r) {
        float v = acc[mt][nt][r] + bsv;
        if (GELU) v = 0.5f * v * (1.0f + erff(v * 0.70710678118654752f));
        if (OBF)
          Cb[(size_t)(row0 + r) * N + col] = f2b(v);
        else
          Cf[(size_t)(row0 + r) * N + col] = v;
      }
    }
  }
}

// ---------------- fp32 fallback GEMM (final projection, N=32) --------------
__global__ __launch_bounds__(256) void gemm_k(
    const float* __restrict__ A, const float* __restrict__ W,
    const float* __restrict__ bias, float* __restrict__ C,
    int M, int N, int K) {
  __shared__ float As2[16][64 + 4];
  __shared__ float Ws2[16][64 + 4];
  int m0 = blockIdx.y * 64, n0 = blockIdx.x * 64;
  int t = threadIdx.x;
  int tx = t & 15, ty = t >> 4;
  float acc[4][4] = {};
  for (int k0 = 0; k0 < K; k0 += 16) {
    #pragma unroll
    for (int i = 0; i < 4; ++i) {
      int li = t + i * 256;
      int m = li >> 4, kk = li & 15;
      As2[kk][m] = A[(size_t)(m0 + m) * K + k0 + kk];
    }
    #pragma unroll
    for (int i = 0; i < 4; ++i) {
      int li = t + i * 256;
      int n = li >> 4, kk = li & 15;
      int gn = n0 + n;
      Ws2[kk][n] = (gn < N) ? W[(size_t)gn * K + k0 + kk] : 0.0f;
    }
    __syncthreads();
    #pragma unroll
    for (int kk = 0; kk < 16; ++kk) {
      float4 avv = *(const float4*)&As2[kk][ty * 4];
      float4 bvv = *(const float4*)&Ws2[kk][tx * 4];
      float a[4] = {avv.x, avv.y, avv.z, avv.w};
      float bb[4] = {bvv.x, bvv.y, bvv.z, bvv.w};
      #pragma unroll
      for (int i = 0; i < 4; ++i)
        #pragma unroll
        for (int j = 0; j < 4; ++j) acc[i][j] += a[i] * bb[j];
    }
    __syncthreads();
  }
  #pragma unroll
  for (int i = 0; i < 4; ++i) {
    int m = m0 + ty * 4 + i;
    #pragma unroll
    for (int j = 0; j < 4; ++j) {
      int n = n0 + tx * 4 + j;
      if (n < N) C[(size_t)m * N + n] = acc[i][j] + bias[n];
    }
  }
}

// ---------------- LayerNorm over last dim (512), optional residual ---------
__global__ __launch_bounds__(128) void ln_k(
    const float* __restrict__ A, const float* __restrict__ Bres,
    const float* __restrict__ g, const float* __restrict__ be,
    float* __restrict__ O) {
  int r = blockIdx.x, t = threadIdx.x;
  __shared__ float lds[2];
  float4 v = ((const float4*)(A + (size_t)r * DM))[t];
  if (Bres) {
    float4 u = ((const float4*)(Bres + (size_t)r * DM))[t];
    v.x += u.x; v.y += u.y; v.z += u.z; v.w += u.w;
  }
  float s = wave_sum64(v.x + v.y + v.z + v.w);
  int w = t >> 6;
  if ((t & 63) == 0) lds[w] = s;
  __syncthreads();
  float mu = (lds[0] + lds[1]) * (1.0f / 512.0f);
  __syncthreads();
  float dx = v.x - mu, dy = v.y - mu, dz = v.z - mu, dw = v.w - mu;
  float sq = wave_sum64(dx * dx + dy * dy + dz * dz + dw * dw);
  if ((t & 63) == 0) lds[w] = sq;
  __syncthreads();
  float var = (lds[0] + lds[1]) * (1.0f / 512.0f);
  float inv = 1.0f / sqrtf(var + 1e-5f);
  float4 gv = ((const float4*)g)[t];
  float4 bv = ((const float4*)be)[t];
  float4 o;
  o.x = dx * inv * gv.x + bv.x;
  o.y = dy * inv * gv.y + bv.y;
  o.z = dz * inv * gv.z + bv.z;
  o.w = dw * inv * gv.w + bv.w;
  ((float4*)(O + (size_t)r * DM))[t] = o;
}

// ---------------- M[b,h,l] = max_u(q.k_idx) - sum_u(q.k_idx)/Lx ------------
__global__ __launch_bounds__(256) void qk_m_k(
    const float* __restrict__ Q, const float* __restrict__ K,
    const int* __restrict__ idx, float* __restrict__ Mout, int Lx, int U) {
  int item = (blockIdx.x << 2) | (threadIdx.x >> 6);
  int lane = threadIdx.x & 63;
  int l = item % Lx;
  int bh = item / Lx;
  int h = bh & 7, b = bh >> 3;
  float qd = Q[((size_t)b * Lx + l) * DM + h * HD + lane];
  float maxv = -INFINITY, sumv = 0.f;
  for (int u = 0; u < U; ++u) {
    int ki = idx[l * U + u];
    float kd = K[((size_t)b * Lx + ki) * DM + h * HD + lane];
    float p = qd * kd;
    p = wave_sum64(p);
    maxv = fmaxf(maxv, p);
    sumv += p;
  }
  if (lane == 0) Mout[item] = maxv - sumv / (float)Lx;
}

// ---------------- top-U indices of M per (b,h) -----------------------------
__global__ __launch_bounds__(256) void topk_k(
    const float* __restrict__ Mbuf, int* __restrict__ Mtop, int Lx, int U) {
  int bh = blockIdx.x;
  const float* m = Mbuf + (size_t)bh * Lx;
  __shared__ float mcopy[2048];
  __shared__ float sv[256];
  __shared__ int si[256];
  int t = threadIdx.x;
  for (int i = t; i < Lx; i += 256) mcopy[i] = m[i];
  __syncthreads();
  for (int u = 0; u < U; ++u) {
    float bv = -INFINITY;
    int bi = 0x7fffffff;
    for (int i = t; i < Lx; i += 256) {
      float v = mcopy[i];
      if (v > bv || (v == bv && i < bi)) { bv = v; bi = i; }
    }
    sv[t] = bv; si[t] = bi;
    __syncthreads();
    for (int s = 128; s > 0; s >>= 1) {
      if (t < s) {
        float v2 = sv[t + s]; int i2 = si[t + s];
        if (v2 > sv[t] || (v2 == sv[t] && i2 < si[t])) { sv[t] = v2; si[t] = i2; }
      }
      __syncthreads();
    }
    if (t == 0) {
      Mtop[bh * U + u] = si[0];
      mcopy[si[0]] = -INFINITY;
    }
    __syncthreads();
  }
}

// ---------------- meanV: two-stage coalesced column reduction --------------
__global__ __launch_bounds__(512) void meanv1_k(const float* __restrict__ V,
                                                float* __restrict__ part,
                                                int Lx) {
  int b = blockIdx.x >> 4, chunk = blockIdx.x & 15;
  int rows = Lx >> 4;
  int t = threadIdx.x;  // 512
  const float* vp = V + ((size_t)b * Lx + (size_t)chunk * rows) * DM + t;
  float s = 0.f;
  for (int l = 0; l < rows; ++l) s += vp[(size_t)l * DM];
  part[(size_t)blockIdx.x * DM + t] = s;
}
__global__ __launch_bounds__(512) void meanv2_k(const float* __restrict__ part,
                                                float* __restrict__ mv,
                                                int Lx) {
  int b = blockIdx.x, t = threadIdx.x;
  float s = 0.f;
  #pragma unroll
  for (int c = 0; c < 16; ++c) s += part[(size_t)(b * 16 + c) * DM + t];
  mv[b * DM + t] = s / (float)Lx;
}

__global__ void fillctx_k(float* __restrict__ ctx, const float* __restrict__ mv,
                          int Lx) {
  size_t i = (size_t)blockIdx.x * 256 + threadIdx.x;
  int col = (int)(i & 511);
  size_t row = i >> 9;
  int b = (int)(row / (size_t)Lx);
  ctx[i] = mv[b * DM + col];
}

// ---------------- full attention for top-U queries -------------------------
__global__ __launch_bounds__(256) void attn_top_k(
    const float* __restrict__ Q, const float* __restrict__ K,
    const float* __restrict__ V, const int* __restrict__ Mtop,
    float* __restrict__ ctx, int Lx, int U) {
  int item = blockIdx.x;
  int u = item % U;
  int bh = item / U;
  int h = bh & 7, b = bh >> 3;
  __shared__ float sc[2048];
  __shared__ float qrow[64];
  __shared__ float red[256];
  int t = threadIdx.x;
  int qi = Mtop[bh * U + u];
  if (t < 64) qrow[t] = Q[((size_t)b * Lx + qi) * DM + h * HD + t];
  __syncthreads();
  for (int k = t; k < Lx; k += 256) {
    const float* kr = K + ((size_t)b * Lx + k) * DM + h * HD;
    float acc = 0.f;
    #pragma unroll
    for (int d = 0; d < 64; d += 4) {
      float4 kv = *(const float4*)&kr[d];
      acc += qrow[d] * kv.x + qrow[d + 1] * kv.y + qrow[d + 2] * kv.z +
             qrow[d + 3] * kv.w;
    }
    sc[k] = acc * 0.125f;
  }
  __syncthreads();
  float mx = -INFINITY;
  for (int k = t; k < Lx; k += 256) mx = fmaxf(mx, sc[k]);
  red[t] = mx;
  __syncthreads();
  for (int s = 128; s > 0; s >>= 1) {
    if (t < s) red[t] = fmaxf(red[t], red[t + s]);
    __syncthreads();
  }
  mx = red[0];
  __syncthreads();
  float ps = 0.f;
  for (int k = t; k < Lx; k += 256) {
    float e = expf(sc[k] - mx);
    sc[k] = e;
    ps += e;
  }
  red[t] = ps;
  __syncthreads();
  for (int s = 128; s > 0; s >>= 1) {
    if (t < s) red[t] += red[t + s];
    __syncthreads();
  }
  float denom = red[0];
  __syncthreads();
  int d = t & 63, chunk = t >> 6;
  int kpc = Lx >> 2;
  float acc = 0.f;
  const float* vb = V + (size_t)b * Lx * DM + h * HD + d;
  for (int k = chunk * kpc; k < (chunk + 1) * kpc; ++k)
    acc += sc[k] * vb[(size_t)k * DM];
  red[t] = acc;
  __syncthreads();
  if (t < 64) {
    float r = red[t] + red[64 + t] + red[128 + t] + red[192 + t];
    ctx[((size_t)b * Lx + qi) * DM + h * HD + t] = r / denom;
  }
}

// ---------------- im2col (circular, k=3) -> bf16 ---------------------------
__global__ void im2col_k(const float* __restrict__ X,
                         ushort_t* __restrict__ A2) {
  size_t gid = (size_t)blockIdx.x * 256 + threadIdx.x;  // 8192*1536
  int col = (int)(gid % 1536);
  size_t row = gid / 1536;
  int i = col / 3, tt = col % 3;
  int b = (int)(row >> 11), l = (int)(row & 2047);
  int ls = (l + tt - 1) & 2047;
  A2[gid] = f2b(X[((size_t)b * 2048 + ls) * DM + i]);
}

// ---------------- batch-norm stats: coalesced two-stage --------------------
__global__ __launch_bounds__(256) void bn1_k(const float* __restrict__ Y,
                                             float* __restrict__ ps,
                                             float* __restrict__ pq) {
  int blk = blockIdx.x;  // 32 blocks x 256 rows
  int t = threadIdx.x;
  float s0 = 0, q0 = 0, s1 = 0, q1 = 0;
  const float* base = Y + (size_t)blk * 256 * DM;
  for (int r = 0; r < 256; ++r) {
    float a = base[(size_t)r * DM + t];
    float b = base[(size_t)r * DM + t + 256];
    s0 += a; q0 += a * a; s1 += b; q1 += b * b;
  }
  ps[blk * DM + t] = s0; ps[blk * DM + t + 256] = s1;
  pq[blk * DM + t] = q0; pq[blk * DM + t + 256] = q1;
}
__global__ __launch_bounds__(512) void bn2_k(const float* __restrict__ ps,
                                             const float* __restrict__ pq,
                                             float* __restrict__ mu,
                                             float* __restrict__ var) {
  int t = threadIdx.x;
  float s = 0, q = 0;
  #pragma unroll
  for (int c = 0; c < 32; ++c) { s += ps[c * DM + t]; q += pq[c * DM + t]; }
  float m = s * (1.0f / 8192.f);
  mu[t] = m;
  var[t] = q * (1.0f / 8192.f) - m * m;
}

__global__ void bn_elu_k(const float* __restrict__ Y,
                         const float* __restrict__ mu,
                         const float* __restrict__ var,
                         const float* __restrict__ g,
                         const float* __restrict__ be, float* __restrict__ O) {
  size_t i = (size_t)blockIdx.x * 256 + threadIdx.x;
  int c = (int)(i & 511);
  float v = (Y[i] - mu[c]) / sqrtf(var[c] + 1e-5f) * g[c] + be[c];
  O[i] = v > 0.f ? v : expm1f(v);
}

__global__ void maxpool_k(const float* __restrict__ Y, float* __restrict__ O) {
  size_t i = (size_t)blockIdx.x * 256 + threadIdx.x;  // 4*1024*512
  int c = (int)(i & 511);
  size_t row = i >> 9;
  int lo = (int)(row & 1023);
  int b = (int)(row >> 10);
  int l0 = 2 * lo - 1;
  float m = -INFINITY;
  #pragma unroll
  for (int tt = 0; tt < 3; ++tt) {
    int l = l0 + tt;
    if (l >= 0 && l < 2048) m = fmaxf(m, Y[((size_t)b * 2048 + l) * DM + c]);
  }
  O[i] = m;
}

// ---------------------------------------------------------------------------
extern "C" void kernel_launch(void* const* d_in, const int* in_sizes, int n_in,
                              void* d_out, int out_size, void* d_ws,
                              size_t ws_size, hipStream_t stream) {
  (void)in_sizes; (void)n_in; (void)out_size; (void)ws_size;
  const float* x_enc  = (const float*)d_in[0];
  const float* tok_w  = (const float*)d_in[1];
  const float* Wq     = (const float*)d_in[2];
  const float* bq     = (const float*)d_in[3];
  const float* Wk     = (const float*)d_in[4];
  const float* bk     = (const float*)d_in[5];
  const float* Wv     = (const float*)d_in[6];
  const float* bv     = (const float*)d_in[7];
  const float* Wo     = (const float*)d_in[8];
  const float* bo     = (const float*)d_in[9];
  const float* W1     = (const float*)d_in[10];
  const float* b1     = (const float*)d_in[11];
  const float* W2     = (const float*)d_in[12];
  const float* b2     = (const float*)d_in[13];
  const float* ln1_g  = (const float*)d_in[14];
  const float* ln1_b  = (const float*)d_in[15];
  const float* ln2_g  = (const float*)d_in[16];
  const float* ln2_b  = (const float*)d_in[17];
  const float* conv_w = (const float*)d_in[18];
  const float* conv_b = (const float*)d_in[19];
  const float* bn_g   = (const float*)d_in[20];
  const float* bn_b   = (const float*)d_in[21];
  const float* normf_g = (const float*)d_in[22];
  const float* normf_b = (const float*)d_in[23];
  const float* proj_w = (const float*)d_in[24];
  const float* proj_b = (const float*)d_in[25];
  float* out = (float*)d_out;
  float* ws = (float*)d_ws;

  // ---- fp32 workspace layout (float offsets) ----
  float* X    = ws;                    // 4,194,304
  float* Qb   = ws + 4194304;          // 4,194,304
  float* Kb   = ws + 8388608;          // 4,194,304
  float* Vb   = ws + 12582912;         // 4,194,304
  float* CTX  = ws + 16777216;         // 4,194,304
  float* Y2   = ws + 20971520;         // 4,194,304
  float* Mb   = ws + 25165824;         // 65,536
  float* MV   = ws + 25231360;         // 2,048
  float* MVP  = ws + 25233408;         // 32,768
  float* BNps = ws + 25266176;         // 16,384
  float* BNpq = ws + 25282560;         // 16,384
  float* BNmu = ws + 25298944;         // 512
  float* BNvr = ws + 25299456;         // 512
  int*   IDX  = (int*)(ws + 25299968); // 81,920
  int*   MT   = (int*)(ws + 25381888); // 1,280
  // ---- bf16 workspace (ushort offsets from U0) ----
  ushort_t* U0  = (ushort_t*)(ws + 25383168);
  ushort_t* Xb  = U0;                  // 4,194,304 (act cast, reused)
  ushort_t* Hb  = U0 + 4194304;        // 16,777,216 (FFN hidden / im2col)
  ushort_t* Wqb = U0 + 20971520;       // 524,288
  ushort_t* Wkb = U0 + 21495808;
  ushort_t* Wvb = U0 + 22020096;
  ushort_t* Wob = U0 + 22544384;
  ushort_t* W1b = U0 + 23068672;       // 2,097,152
  ushort_t* W2b = U0 + 25165824;       // 2,097,152
  ushort_t* Cwb = U0 + 27262976;       // 786,432

  // ---- weight casts (fp32 -> bf16), once per launch ----
  castb_k<<<524288 / 4 / 256, 256, 0, stream>>>(Wq, Wqb, 131072);
  castb_k<<<524288 / 4 / 256, 256, 0, stream>>>(Wk, Wkb, 131072);
  castb_k<<<524288 / 4 / 256, 256, 0, stream>>>(Wv, Wvb, 131072);
  castb_k<<<524288 / 4 / 256, 256, 0, stream>>>(Wo, Wob, 131072);
  castb_k<<<2097152 / 4 / 256, 256, 0, stream>>>(W1, W1b, 524288);
  castb_k<<<2097152 / 4 / 256, 256, 0, stream>>>(W2, W2b, 524288);
  castb_k<<<786432 / 4 / 256, 256, 0, stream>>>(conv_w, Cwb, 196608);

  token_embed_k<<<NB * 2048, 256, 0, stream>>>(x_enc, tok_w, X);

  for (int layer = 0; layer < 2; ++layer) {
    const int Lx = (layer == 0) ? 2048 : 1024;
    const int U  = (layer == 0) ? 40 : 35;
    const int M  = NB * Lx;
    const int n4 = M * DM / 4;

    uint32_t kl0, kl1, s0, s1;
    threefry2x32(0u, 42u, 0u, (uint32_t)layer, &kl0, &kl1);
    threefry2x32(kl0, kl1, 0u, 1u, &s0, &s1);
    int nidx = Lx * U;
    gen_idx_k<<<(nidx + 255) / 256, 256, 0, stream>>>(IDX, nidx, Lx - 1, s0, s1);

    // QKV (bf16 MFMA)
    castb_k<<<(n4 + 255) / 256, 256, 0, stream>>>(X, Xb, n4);
    mgemm_k<0, 0><<<dim3(4, M / 128), 256, 0, stream>>>(
        Xb, Wqb + (size_t)layer * 262144, bq + layer * DM, Qb, nullptr, M, DM, DM);
    mgemm_k<0, 0><<<dim3(4, M / 128), 256, 0, stream>>>(
        Xb, Wkb + (size_t)layer * 262144, bk + layer * DM, Kb, nullptr, M, DM, DM);
    mgemm_k<0, 0><<<dim3(4, M / 128), 256, 0, stream>>>(
        Xb, Wvb + (size_t)layer * 262144, bv + layer * DM, Vb, nullptr, M, DM, DM);

    // ProbSparse attention
    qk_m_k<<<NB * NH * Lx / 4, 256, 0, stream>>>(Qb, Kb, IDX, Mb, Lx, U);
    topk_k<<<NB * NH, 256, 0, stream>>>(Mb, MT, Lx, U);
    meanv1_k<<<NB * 16, 512, 0, stream>>>(Vb, MVP, Lx);
    meanv2_k<<<NB, 512, 0, stream>>>(MVP, MV, Lx);
    fillctx_k<<<(M * DM) / 256, 256, 0, stream>>>(CTX, MV, Lx);
    attn_top_k<<<NB * NH * U, 256, 0, stream>>>(Qb, Kb, Vb, MT, CTX, Lx, U);

    // output projection + residual + LN1
    castb_k<<<(n4 + 255) / 256, 256, 0, stream>>>(CTX, Xb, n4);
    mgemm_k<0, 0><<<dim3(4, M / 128), 256, 0, stream>>>(
        Xb, Wob + (size_t)layer * 262144, bo + layer * DM, Y2, nullptr, M, DM, DM);
    ln_k<<<M, 128, 0, stream>>>(X, Y2, ln1_g + layer * DM, ln1_b + layer * DM, X);

    // FFN (GELU fused; hidden kept in bf16)
    castb_k<<<(n4 + 255) / 256, 256, 0, stream>>>(X, Xb, n4);
    mgemm_k<1, 1><<<dim3(16, M / 128), 256, 0, stream>>>(
        Xb, W1b + (size_t)layer * 1048576, b1 + layer * 2048, nullptr, Hb,
        M, 2048, DM);
    mgemm_k<0, 0><<<dim3(4, M / 128), 256, 0, stream>>>(
        Hb, W2b + (size_t)layer * 1048576, b2 + layer * DM, Y2, nullptr,
        M, DM, 2048);
    ln_k<<<M, 128, 0, stream>>>(X, Y2, ln2_g + layer * DM, ln2_b + layer * DM, X);

    if (layer == 0) {
      im2col_k<<<(8192 * 1536) / 256, 256, 0, stream>>>(X, Hb);
      mgemm_k<0, 0><<<dim3(4, 64), 256, 0, stream>>>(
          Hb, Cwb, conv_b, CTX, nullptr, 8192, DM, 1536);
      bn1_k<<<32, 256, 0, stream>>>(CTX, BNps, BNpq);
      bn2_k<<<1, 512, 0, stream>>>(BNps, BNpq, BNmu, BNvr);
      bn_elu_k<<<(8192 * 512) / 256, 256, 0, stream>>>(CTX, BNmu, BNvr, bn_g,
                                                       bn_b, Qb);
      maxpool_k<<<(NB * 1024 * 512) / 256, 256, 0, stream>>>(Qb, X);
    }
  }

  // final LN + projection (N=32, fp32)
  ln_k<<<NB * 1024, 128, 0, stream>>>(X, nullptr, normf_g, normf_b, Qb);
  gemm_k<<<dim3(1, 4096 / 64), 256, 0, stream>>>(Qb, proj_w, proj_b, out,
                                                 4096, 32, DM);
}

// Round 3
// 1386.125 us; speedup vs baseline: 2.9326x; 1.4246x over previous
//
#include <hip/hip_runtime.h>
#include <cstdint>
#include <cmath>

// ---------------------------------------------------------------------------
// Informer encoder forward (B=4, L=2048, ENC_IN=32, D_MODEL=512, D_FF=2048,
// E_LAYERS=2, H=8, FACTOR=5).
// Round 3: flash-style split-K ProbSparse attention (fp32), replacing the
// latency-bound per-query attn_top_k.
// ---------------------------------------------------------------------------

#define NB 4
#define DM 512
#define NH 8
#define HD 64

typedef unsigned short ushort_t;
typedef __bf16 bf16x8 __attribute__((ext_vector_type(8)));
typedef float floatx4 __attribute__((ext_vector_type(4)));

// ---------------- fp32 -> bf16 (RNE) ---------------------------------------
__device__ inline ushort_t f2b(float f) {
  uint32_t u = __float_as_uint(f);
  uint32_t r = (u + 0x7fffu + ((u >> 16) & 1u)) >> 16;
  return (ushort_t)r;
}

__global__ void castb_k(const float* __restrict__ in,
                        ushort_t* __restrict__ out, int n4) {
  int i = blockIdx.x * 256 + threadIdx.x;
  if (i < n4) {
    float4 v = ((const float4*)in)[i];
    ushort4 o;
    o.x = f2b(v.x); o.y = f2b(v.y); o.z = f2b(v.z); o.w = f2b(v.w);
    ((ushort4*)out)[i] = o;
  }
}

// ---------------- Threefry2x32 (exact JAX semantics) -----------------------
__host__ __device__ inline void threefry2x32(uint32_t k0, uint32_t k1,
                                             uint32_t c0, uint32_t c1,
                                             uint32_t* o0, uint32_t* o1) {
  uint32_t ks0 = k0, ks1 = k1, ks2 = k0 ^ k1 ^ 0x1BD11BDAu;
  uint32_t x0 = c0 + ks0;
  uint32_t x1 = c1 + ks1;
  const uint32_t rotA[4] = {13u, 15u, 26u, 6u};
  const uint32_t rotB[4] = {17u, 29u, 16u, 24u};
  uint32_t ks[3] = {ks0, ks1, ks2};
  #pragma unroll
  for (int i = 0; i < 5; ++i) {
    const uint32_t* r = (i & 1) ? rotB : rotA;
    #pragma unroll
    for (int j = 0; j < 4; ++j) {
      x0 += x1;
      x1 = (x1 << r[j]) | (x1 >> (32u - r[j]));
      x1 ^= x0;
    }
    x0 += ks[(i + 1) % 3];
    x1 += ks[(i + 2) % 3] + (uint32_t)(i + 1);
  }
  *o0 = x0; *o1 = x1;
}

__global__ void gen_idx_k(int* __restrict__ idx, int n, int mask,
                          uint32_t k0, uint32_t k1) {
  int i = blockIdx.x * 256 + threadIdx.x;
  if (i < n) {
    uint32_t o0, o1;
    threefry2x32(k0, k1, 0u, (uint32_t)i, &o0, &o1);
    idx[i] = (int)((o0 ^ o1) & (uint32_t)mask);
  }
}

// ---------------- wave helpers ---------------------------------------------
__device__ inline float wave_sum64(float v) {
  #pragma unroll
  for (int o = 32; o > 0; o >>= 1) v += __shfl_xor(v, o, 64);
  return v;
}
__device__ inline float wave_max64(float v) {
  #pragma unroll
  for (int o = 32; o > 0; o >>= 1) v = fmaxf(v, __shfl_xor(v, o, 64));
  return v;
}

// ---------------- token embedding + positional encoding --------------------
__global__ __launch_bounds__(256) void token_embed_k(
    const float* __restrict__ xe, const float* __restrict__ w,
    float* __restrict__ X) {
  int bl = blockIdx.x;
  int b = bl >> 11, l = bl & 2047;
  __shared__ float xin[3][32];
  int t = threadIdx.x;
  if (t < 96) {
    int tt = t >> 5, c = t & 31;
    int ls = (l + tt - 1) & 2047;
    xin[tt][c] = xe[((size_t)b * 2048 + ls) * 32 + c];
  }
  __syncthreads();
  float pos = (float)l;
  for (int d = t; d < DM; d += 256) {
    float acc = 0.f;
    const float* wd = &w[d * 96];
    #pragma unroll
    for (int c = 0; c < 32; ++c) {
      acc += xin[0][c] * wd[c * 3 + 0] + xin[1][c] * wd[c * 3 + 1] +
             xin[2][c] * wd[c * 3 + 2];
    }
    int j2 = d & ~1;
    float div = expf((float)j2 * -1.7988946039e-2f);  // -ln(10000)/512
    float pe = (d & 1) ? cosf(pos * div) : sinf(pos * div);
    X[((size_t)b * 2048 + l) * DM + d] = acc + pe;
  }
}

// ---------------- bf16 MFMA GEMM: C = act(A @ W^T + bias) ------------------
__device__ inline void gload16(const ushort_t* g, ushort_t* l) {
  __builtin_amdgcn_global_load_lds(
      (const __attribute__((address_space(1))) unsigned int*)(const void*)g,
      (__attribute__((address_space(3))) unsigned int*)(void*)l, 16, 0, 0);
}

template <int GELU, int OBF>
__global__ __launch_bounds__(256) void mgemm_k(
    const ushort_t* __restrict__ A, const ushort_t* __restrict__ W,
    const float* __restrict__ bias, float* __restrict__ Cf,
    ushort_t* __restrict__ Cb, int M, int N, int K) {
  __shared__ ushort_t As[128 * 32];
  __shared__ ushort_t Bs[128 * 32];
  int m0 = blockIdx.y * 128, n0 = blockIdx.x * 128;
  int t = threadIdx.x;
  int lane = t & 63, wv = t >> 6;
  int sr = lane >> 2, sc = (lane & 3) * 8;
  int ra0 = wv * 32 + sr, ra1 = ra0 + 16;
  const ushort_t* gA0 = A + (size_t)(m0 + ra0) * K + sc;
  const ushort_t* gA1 = A + (size_t)(m0 + ra1) * K + sc;
  const ushort_t* gB0 = W + (size_t)(n0 + ra0) * K + sc;
  const ushort_t* gB1 = W + (size_t)(n0 + ra1) * K + sc;
  ushort_t* lA0 = As + wv * 1024;
  ushort_t* lA1 = lA0 + 512;
  ushort_t* lB0 = Bs + wv * 1024;
  ushort_t* lB1 = lB0 + 512;

  int quad = lane >> 4, lr = lane & 15;
  int wm = wv >> 1, wn = wv & 1;

  floatx4 acc[4][4] = {};
  for (int ks = 0; ks < K; ks += 32) {
    gload16(gA0, lA0);
    gload16(gA1, lA1);
    gload16(gB0, lB0);
    gload16(gB1, lB1);
    gA0 += 32; gA1 += 32; gB0 += 32; gB1 += 32;
    __syncthreads();
    bf16x8 av[4], bv[4];
    #pragma unroll
    for (int mt = 0; mt < 4; ++mt)
      av[mt] = *(const bf16x8*)&As[(wm * 64 + mt * 16 + lr) * 32 + quad * 8];
    #pragma unroll
    for (int nt = 0; nt < 4; ++nt)
      bv[nt] = *(const bf16x8*)&Bs[(wn * 64 + nt * 16 + lr) * 32 + quad * 8];
    #pragma unroll
    for (int mt = 0; mt < 4; ++mt)
      #pragma unroll
      for (int nt = 0; nt < 4; ++nt)
        acc[mt][nt] = __builtin_amdgcn_mfma_f32_16x16x32_bf16(
            av[mt], bv[nt], acc[mt][nt], 0, 0, 0);
    __syncthreads();
  }
  #pragma unroll
  for (int nt = 0; nt < 4; ++nt) {
    int col = n0 + wn * 64 + nt * 16 + lr;
    float bsv = bias[col];
    #pragma unroll
    for (int mt = 0; mt < 4; ++mt) {
      int row0 = m0 + wm * 64 + mt * 16 + quad * 4;
      #pragma unroll
      for (int r = 0; r < 4; ++r) {
        float v = acc[mt][nt][r] + bsv;
        if (GELU) v = 0.5f * v * (1.0f + erff(v * 0.70710678118654752f));
        if (OBF)
          Cb[(size_t)(row0 + r) * N + col] = f2b(v);
        else
          Cf[(size_t)(row0 + r) * N + col] = v;
      }
    }
  }
}

// ---------------- fp32 fallback GEMM (final projection, N=32) --------------
__global__ __launch_bounds__(256) void gemm_k(
    const float* __restrict__ A, const float* __restrict__ W,
    const float* __restrict__ bias, float* __restrict__ C,
    int M, int N, int K) {
  __shared__ float As2[16][64 + 4];
  __shared__ float Ws2[16][64 + 4];
  int m0 = blockIdx.y * 64, n0 = blockIdx.x * 64;
  int t = threadIdx.x;
  int tx = t & 15, ty = t >> 4;
  float acc[4][4] = {};
  for (int k0 = 0; k0 < K; k0 += 16) {
    #pragma unroll
    for (int i = 0; i < 4; ++i) {
      int li = t + i * 256;
      int m = li >> 4, kk = li & 15;
      As2[kk][m] = A[(size_t)(m0 + m) * K + k0 + kk];
    }
    #pragma unroll
    for (int i = 0; i < 4; ++i) {
      int li = t + i * 256;
      int n = li >> 4, kk = li & 15;
      int gn = n0 + n;
      Ws2[kk][n] = (gn < N) ? W[(size_t)gn * K + k0 + kk] : 0.0f;
    }
    __syncthreads();
    #pragma unroll
    for (int kk = 0; kk < 16; ++kk) {
      float4 avv = *(const float4*)&As2[kk][ty * 4];
      float4 bvv = *(const float4*)&Ws2[kk][tx * 4];
      float a[4] = {avv.x, avv.y, avv.z, avv.w};
      float bb[4] = {bvv.x, bvv.y, bvv.z, bvv.w};
      #pragma unroll
      for (int i = 0; i < 4; ++i)
        #pragma unroll
        for (int j = 0; j < 4; ++j) acc[i][j] += a[i] * bb[j];
    }
    __syncthreads();
  }
  #pragma unroll
  for (int i = 0; i < 4; ++i) {
    int m = m0 + ty * 4 + i;
    #pragma unroll
    for (int j = 0; j < 4; ++j) {
      int n = n0 + tx * 4 + j;
      if (n < N) C[(size_t)m * N + n] = acc[i][j] + bias[n];
    }
  }
}

// ---------------- LayerNorm over last dim (512), optional residual ---------
__global__ __launch_bounds__(128) void ln_k(
    const float* __restrict__ A, const float* __restrict__ Bres,
    const float* __restrict__ g, const float* __restrict__ be,
    float* __restrict__ O) {
  int r = blockIdx.x, t = threadIdx.x;
  __shared__ float lds[2];
  float4 v = ((const float4*)(A + (size_t)r * DM))[t];
  if (Bres) {
    float4 u = ((const float4*)(Bres + (size_t)r * DM))[t];
    v.x += u.x; v.y += u.y; v.z += u.z; v.w += u.w;
  }
  float s = wave_sum64(v.x + v.y + v.z + v.w);
  int w = t >> 6;
  if ((t & 63) == 0) lds[w] = s;
  __syncthreads();
  float mu = (lds[0] + lds[1]) * (1.0f / 512.0f);
  __syncthreads();
  float dx = v.x - mu, dy = v.y - mu, dz = v.z - mu, dw = v.w - mu;
  float sq = wave_sum64(dx * dx + dy * dy + dz * dz + dw * dw);
  if ((t & 63) == 0) lds[w] = sq;
  __syncthreads();
  float var = (lds[0] + lds[1]) * (1.0f / 512.0f);
  float inv = 1.0f / sqrtf(var + 1e-5f);
  float4 gv = ((const float4*)g)[t];
  float4 bv = ((const float4*)be)[t];
  float4 o;
  o.x = dx * inv * gv.x + bv.x;
  o.y = dy * inv * gv.y + bv.y;
  o.z = dz * inv * gv.z + bv.z;
  o.w = dw * inv * gv.w + bv.w;
  ((float4*)(O + (size_t)r * DM))[t] = o;
}

// ---------------- M[b,h,l] = max_u(q.k_idx) - sum_u(q.k_idx)/Lx ------------
__global__ __launch_bounds__(256) void qk_m_k(
    const float* __restrict__ Q, const float* __restrict__ K,
    const int* __restrict__ idx, float* __restrict__ Mout, int Lx, int U) {
  int item = (blockIdx.x << 2) | (threadIdx.x >> 6);
  int lane = threadIdx.x & 63;
  int l = item % Lx;
  int bh = item / Lx;
  int h = bh & 7, b = bh >> 3;
  float qd = Q[((size_t)b * Lx + l) * DM + h * HD + lane];
  float maxv = -INFINITY, sumv = 0.f;
  for (int u = 0; u < U; ++u) {
    int ki = idx[l * U + u];
    float kd = K[((size_t)b * Lx + ki) * DM + h * HD + lane];
    float p = qd * kd;
    p = wave_sum64(p);
    maxv = fmaxf(maxv, p);
    sumv += p;
  }
  if (lane == 0) Mout[item] = maxv - sumv / (float)Lx;
}

// ---------------- top-U indices of M per (b,h) -----------------------------
__global__ __launch_bounds__(256) void topk_k(
    const float* __restrict__ Mbuf, int* __restrict__ Mtop, int Lx, int U) {
  int bh = blockIdx.x;
  const float* m = Mbuf + (size_t)bh * Lx;
  __shared__ float mcopy[2048];
  __shared__ float sv[256];
  __shared__ int si[256];
  int t = threadIdx.x;
  for (int i = t; i < Lx; i += 256) mcopy[i] = m[i];
  __syncthreads();
  for (int u = 0; u < U; ++u) {
    float bv = -INFINITY;
    int bi = 0x7fffffff;
    for (int i = t; i < Lx; i += 256) {
      float v = mcopy[i];
      if (v > bv || (v == bv && i < bi)) { bv = v; bi = i; }
    }
    sv[t] = bv; si[t] = bi;
    __syncthreads();
    for (int s = 128; s > 0; s >>= 1) {
      if (t < s) {
        float v2 = sv[t + s]; int i2 = si[t + s];
        if (v2 > sv[t] || (v2 == sv[t] && i2 < si[t])) { sv[t] = v2; si[t] = i2; }
      }
      __syncthreads();
    }
    if (t == 0) {
      Mtop[bh * U + u] = si[0];
      mcopy[si[0]] = -INFINITY;
    }
    __syncthreads();
  }
}

// ---------------- meanV: two-stage coalesced column reduction --------------
__global__ __launch_bounds__(512) void meanv1_k(const float* __restrict__ V,
                                                float* __restrict__ part,
                                                int Lx) {
  int b = blockIdx.x >> 4, chunk = blockIdx.x & 15;
  int rows = Lx >> 4;
  int t = threadIdx.x;  // 512
  const float* vp = V + ((size_t)b * Lx + (size_t)chunk * rows) * DM + t;
  float s = 0.f;
  for (int l = 0; l < rows; ++l) s += vp[(size_t)l * DM];
  part[(size_t)blockIdx.x * DM + t] = s;
}
__global__ __launch_bounds__(512) void meanv2_k(const float* __restrict__ part,
                                                float* __restrict__ mv,
                                                int Lx) {
  int b = blockIdx.x, t = threadIdx.x;
  float s = 0.f;
  #pragma unroll
  for (int c = 0; c < 16; ++c) s += part[(size_t)(b * 16 + c) * DM + t];
  mv[b * DM + t] = s / (float)Lx;
}

__global__ void fillctx_k(float* __restrict__ ctx, const float* __restrict__ mv,
                          int Lx) {
  size_t i = (size_t)blockIdx.x * 256 + threadIdx.x;
  int col = (int)(i & 511);
  size_t row = i >> 9;
  int b = (int)(row / (size_t)Lx);
  ctx[i] = mv[b * DM + col];
}

// ---------------- flash split-K attention for top-U queries ----------------
// grid: (b*8+h)*nchunk + chunk; 512 threads.
// partials: part[((bh*nchunk+chunk)*U + u)*66 + {0..63 O, 64 m, 65 l}]
__global__ __launch_bounds__(512) void attn_flash_k(
    const float* __restrict__ Q, const float* __restrict__ K,
    const float* __restrict__ V, const int* __restrict__ Mtop,
    float* __restrict__ part, int Lx, int U, int nchunk) {
  int blk = blockIdx.x;
  int chunk = blk % nchunk, bh = blk / nchunk;
  int h = bh & 7, b = bh >> 3;
  int rows = Lx / nchunk;
  int ntile = rows >> 6;
  __shared__ float s_q[40 * 64];
  __shared__ float s_k[64 * 65];
  __shared__ float s_v[64 * 65];
  __shared__ float s_p[40 * 64];
  __shared__ float s_m[40], s_l[40], s_a[40];
  int t = threadIdx.x;
  int d = t & 63, wv = t >> 6;  // d = lane, wv = wave id (0..7)

  for (int i = t; i < U * 64; i += 512) {
    int u = i >> 6, dd = i & 63;
    int qi = Mtop[bh * U + u];
    s_q[i] = Q[((size_t)b * Lx + qi) * DM + h * HD + dd] * 0.125f;
  }
  if (t < U) { s_m[t] = -INFINITY; s_l[t] = 0.f; s_a[t] = 0.f; }
  float o[5] = {0.f, 0.f, 0.f, 0.f, 0.f};
  __syncthreads();

  const float* Kp = K + (size_t)b * Lx * DM + h * HD;
  const float* Vp = V + (size_t)b * Lx * DM + h * HD;

  for (int tile = 0; tile < ntile; ++tile) {
    int kr0 = chunk * rows + tile * 64;
    // stage K,V tile (64 x 64) into padded LDS
    {
      int r = t >> 4, c4 = (t & 15) * 4;
      #pragma unroll
      for (int pass = 0; pass < 2; ++pass) {
        int rr = r + pass * 32;
        float4 kv = *(const float4*)&Kp[(size_t)(kr0 + rr) * DM + c4];
        float4 vv = *(const float4*)&Vp[(size_t)(kr0 + rr) * DM + c4];
        float* kd = &s_k[rr * 65 + c4];
        kd[0] = kv.x; kd[1] = kv.y; kd[2] = kv.z; kd[3] = kv.w;
        float* vd = &s_v[rr * 65 + c4];
        vd[0] = vv.x; vd[1] = vv.y; vd[2] = vv.z; vd[3] = vv.w;
      }
    }
    __syncthreads();
    // QK: this thread owns k-row = d; hoist row to registers
    {
      float kr[64];
      #pragma unroll
      for (int dd = 0; dd < 64; ++dd) kr[dd] = s_k[d * 65 + dd];
      for (int u = wv; u < U; u += 8) {
        float acc = 0.f;
        #pragma unroll
        for (int c = 0; c < 16; ++c) {
          float4 qv = *(const float4*)&s_q[u * 64 + c * 4];
          acc += qv.x * kr[c * 4] + qv.y * kr[c * 4 + 1] +
                 qv.z * kr[c * 4 + 2] + qv.w * kr[c * 4 + 3];
        }
        s_p[u * 64 + d] = acc;
      }
    }
    __syncthreads();
    // online softmax: wave wv handles rows u = wv, wv+8, ...
    for (int u = wv; u < U; u += 8) {
      float sv_ = s_p[u * 64 + d];
      float mx = wave_max64(sv_);
      float mold = s_m[u];
      float mnew = fmaxf(mold, mx);
      float e = expf(sv_ - mnew);
      float se = wave_sum64(e);
      s_p[u * 64 + d] = e;
      if (d == 0) {
        float alpha = expf(mold - mnew);
        s_a[u] = alpha;
        s_l[u] = s_l[u] * alpha + se;
        s_m[u] = mnew;
      }
    }
    __syncthreads();
    // PV: this thread owns output dim = d; hoist V column to registers
    {
      float vr[64];
      #pragma unroll
      for (int k = 0; k < 64; ++k) vr[k] = s_v[k * 65 + d];
      int i = 0;
      for (int u = wv; u < U; u += 8, ++i) {
        float acc = 0.f;
        #pragma unroll
        for (int c = 0; c < 16; ++c) {
          float4 pv = *(const float4*)&s_p[u * 64 + c * 4];
          acc += pv.x * vr[c * 4] + pv.y * vr[c * 4 + 1] +
                 pv.z * vr[c * 4 + 2] + pv.w * vr[c * 4 + 3];
        }
        o[i] = o[i] * s_a[u] + acc;
      }
    }
    __syncthreads();
  }
  // write partials
  {
    int i = 0;
    for (int u = wv; u < U; u += 8, ++i) {
      float* pp = part + ((size_t)(bh * nchunk + chunk) * U + u) * 66;
      pp[d] = o[i];
      if (d == 0) { pp[64] = s_m[u]; pp[65] = s_l[u]; }
    }
  }
}

// merge partials and scatter into ctx
__global__ __launch_bounds__(64) void attn_merge_k(
    const float* __restrict__ part, const int* __restrict__ Mtop,
    float* __restrict__ ctx, int Lx, int U, int nchunk) {
  int bu = blockIdx.x;  // bh*U + u
  int u = bu % U, bh = bu / U;
  int h = bh & 7, b = bh >> 3;
  int d = threadIdx.x;  // 64
  float M = -INFINITY;
  for (int c = 0; c < nchunk; ++c)
    M = fmaxf(M, part[((size_t)(bh * nchunk + c) * U + u) * 66 + 64]);
  float L = 0.f, O = 0.f;
  for (int c = 0; c < nchunk; ++c) {
    const float* pp = part + ((size_t)(bh * nchunk + c) * U + u) * 66;
    float w = expf(pp[64] - M);
    L += pp[65] * w;
    O += pp[d] * w;
  }
  int qi = Mtop[bh * U + u];
  ctx[((size_t)b * Lx + qi) * DM + h * HD + d] = O / L;
}

// ---------------- im2col (circular, k=3) -> bf16 ---------------------------
__global__ void im2col_k(const float* __restrict__ X,
                         ushort_t* __restrict__ A2) {
  size_t gid = (size_t)blockIdx.x * 256 + threadIdx.x;  // 8192*1536
  int col = (int)(gid % 1536);
  size_t row = gid / 1536;
  int i = col / 3, tt = col % 3;
  int b = (int)(row >> 11), l = (int)(row & 2047);
  int ls = (l + tt - 1) & 2047;
  A2[gid] = f2b(X[((size_t)b * 2048 + ls) * DM + i]);
}

// ---------------- batch-norm stats: coalesced two-stage --------------------
__global__ __launch_bounds__(256) void bn1_k(const float* __restrict__ Y,
                                             float* __restrict__ ps,
                                             float* __restrict__ pq) {
  int blk = blockIdx.x;  // 32 blocks x 256 rows
  int t = threadIdx.x;
  float s0 = 0, q0 = 0, s1 = 0, q1 = 0;
  const float* base = Y + (size_t)blk * 256 * DM;
  for (int r = 0; r < 256; ++r) {
    float a = base[(size_t)r * DM + t];
    float b = base[(size_t)r * DM + t + 256];
    s0 += a; q0 += a * a; s1 += b; q1 += b * b;
  }
  ps[blk * DM + t] = s0; ps[blk * DM + t + 256] = s1;
  pq[blk * DM + t] = q0; pq[blk * DM + t + 256] = q1;
}
__global__ __launch_bounds__(512) void bn2_k(const float* __restrict__ ps,
                                             const float* __restrict__ pq,
                                             float* __restrict__ mu,
                                             float* __restrict__ var) {
  int t = threadIdx.x;
  float s = 0, q = 0;
  #pragma unroll
  for (int c = 0; c < 32; ++c) { s += ps[c * DM + t]; q += pq[c * DM + t]; }
  float m = s * (1.0f / 8192.f);
  mu[t] = m;
  var[t] = q * (1.0f / 8192.f) - m * m;
}

__global__ void bn_elu_k(const float* __restrict__ Y,
                         const float* __restrict__ mu,
                         const float* __restrict__ var,
                         const float* __restrict__ g,
                         const float* __restrict__ be, float* __restrict__ O) {
  size_t i = (size_t)blockIdx.x * 256 + threadIdx.x;
  int c = (int)(i & 511);
  float v = (Y[i] - mu[c]) / sqrtf(var[c] + 1e-5f) * g[c] + be[c];
  O[i] = v > 0.f ? v : expm1f(v);
}

__global__ void maxpool_k(const float* __restrict__ Y, float* __restrict__ O) {
  size_t i = (size_t)blockIdx.x * 256 + threadIdx.x;  // 4*1024*512
  int c = (int)(i & 511);
  size_t row = i >> 9;
  int lo = (int)(row & 1023);
  int b = (int)(row >> 10);
  int l0 = 2 * lo - 1;
  float m = -INFINITY;
  #pragma unroll
  for (int tt = 0; tt < 3; ++tt) {
    int l = l0 + tt;
    if (l >= 0 && l < 2048) m = fmaxf(m, Y[((size_t)b * 2048 + l) * DM + c]);
  }
  O[i] = m;
}

// ---------------------------------------------------------------------------
extern "C" void kernel_launch(void* const* d_in, const int* in_sizes, int n_in,
                              void* d_out, int out_size, void* d_ws,
                              size_t ws_size, hipStream_t stream) {
  (void)in_sizes; (void)n_in; (void)out_size; (void)ws_size;
  const float* x_enc  = (const float*)d_in[0];
  const float* tok_w  = (const float*)d_in[1];
  const float* Wq     = (const float*)d_in[2];
  const float* bq     = (const float*)d_in[3];
  const float* Wk     = (const float*)d_in[4];
  const float* bk     = (const float*)d_in[5];
  const float* Wv     = (const float*)d_in[6];
  const float* bv     = (const float*)d_in[7];
  const float* Wo     = (const float*)d_in[8];
  const float* bo     = (const float*)d_in[9];
  const float* W1     = (const float*)d_in[10];
  const float* b1     = (const float*)d_in[11];
  const float* W2     = (const float*)d_in[12];
  const float* b2     = (const float*)d_in[13];
  const float* ln1_g  = (const float*)d_in[14];
  const float* ln1_b  = (const float*)d_in[15];
  const float* ln2_g  = (const float*)d_in[16];
  const float* ln2_b  = (const float*)d_in[17];
  const float* conv_w = (const float*)d_in[18];
  const float* conv_b = (const float*)d_in[19];
  const float* bn_g   = (const float*)d_in[20];
  const float* bn_b   = (const float*)d_in[21];
  const float* normf_g = (const float*)d_in[22];
  const float* normf_b = (const float*)d_in[23];
  const float* proj_w = (const float*)d_in[24];
  const float* proj_b = (const float*)d_in[25];
  float* out = (float*)d_out;
  float* ws = (float*)d_ws;

  // ---- fp32 workspace layout (float offsets) ----
  float* X    = ws;                    // 4,194,304
  float* Qb   = ws + 4194304;          // 4,194,304
  float* Kb   = ws + 8388608;          // 4,194,304
  float* Vb   = ws + 12582912;         // 4,194,304
  float* CTX  = ws + 16777216;         // 4,194,304
  float* Y2   = ws + 20971520;         // 4,194,304 (also attn partials)
  float* Mb   = ws + 25165824;         // 65,536
  float* MV   = ws + 25231360;         // 2,048
  float* MVP  = ws + 25233408;         // 32,768
  float* BNps = ws + 25266176;         // 16,384
  float* BNpq = ws + 25282560;         // 16,384
  float* BNmu = ws + 25298944;         // 512
  float* BNvr = ws + 25299456;         // 512
  int*   IDX  = (int*)(ws + 25299968); // 81,920
  int*   MT   = (int*)(ws + 25381888); // 1,280
  // ---- bf16 workspace ----
  ushort_t* U0  = (ushort_t*)(ws + 25383168);
  ushort_t* Xb  = U0;                  // 4,194,304
  ushort_t* Hb  = U0 + 4194304;        // 16,777,216
  ushort_t* Wqb = U0 + 20971520;
  ushort_t* Wkb = U0 + 21495808;
  ushort_t* Wvb = U0 + 22020096;
  ushort_t* Wob = U0 + 22544384;
  ushort_t* W1b = U0 + 23068672;
  ushort_t* W2b = U0 + 25165824;
  ushort_t* Cwb = U0 + 27262976;

  castb_k<<<512, 256, 0, stream>>>(Wq, Wqb, 131072);
  castb_k<<<512, 256, 0, stream>>>(Wk, Wkb, 131072);
  castb_k<<<512, 256, 0, stream>>>(Wv, Wvb, 131072);
  castb_k<<<512, 256, 0, stream>>>(Wo, Wob, 131072);
  castb_k<<<2048, 256, 0, stream>>>(W1, W1b, 524288);
  castb_k<<<2048, 256, 0, stream>>>(W2, W2b, 524288);
  castb_k<<<768, 256, 0, stream>>>(conv_w, Cwb, 196608);

  token_embed_k<<<NB * 2048, 256, 0, stream>>>(x_enc, tok_w, X);

  for (int layer = 0; layer < 2; ++layer) {
    const int Lx = (layer == 0) ? 2048 : 1024;
    const int U  = (layer == 0) ? 40 : 35;
    const int M  = NB * Lx;
    const int n4 = M * DM / 4;
    const int NCH = 8;

    uint32_t kl0, kl1, s0, s1;
    threefry2x32(0u, 42u, 0u, (uint32_t)layer, &kl0, &kl1);
    threefry2x32(kl0, kl1, 0u, 1u, &s0, &s1);
    int nidx = Lx * U;
    gen_idx_k<<<(nidx + 255) / 256, 256, 0, stream>>>(IDX, nidx, Lx - 1, s0, s1);

    // QKV (bf16 MFMA)
    castb_k<<<(n4 + 255) / 256, 256, 0, stream>>>(X, Xb, n4);
    mgemm_k<0, 0><<<dim3(4, M / 128), 256, 0, stream>>>(
        Xb, Wqb + (size_t)layer * 262144, bq + layer * DM, Qb, nullptr, M, DM, DM);
    mgemm_k<0, 0><<<dim3(4, M / 128), 256, 0, stream>>>(
        Xb, Wkb + (size_t)layer * 262144, bk + layer * DM, Kb, nullptr, M, DM, DM);
    mgemm_k<0, 0><<<dim3(4, M / 128), 256, 0, stream>>>(
        Xb, Wvb + (size_t)layer * 262144, bv + layer * DM, Vb, nullptr, M, DM, DM);

    // ProbSparse attention
    qk_m_k<<<NB * NH * Lx / 4, 256, 0, stream>>>(Qb, Kb, IDX, Mb, Lx, U);
    topk_k<<<NB * NH, 256, 0, stream>>>(Mb, MT, Lx, U);
    meanv1_k<<<NB * 16, 512, 0, stream>>>(Vb, MVP, Lx);
    meanv2_k<<<NB, 512, 0, stream>>>(MVP, MV, Lx);
    fillctx_k<<<(M * DM) / 256, 256, 0, stream>>>(CTX, MV, Lx);
    attn_flash_k<<<NB * NH * NCH, 512, 0, stream>>>(Qb, Kb, Vb, MT, Y2, Lx, U, NCH);
    attn_merge_k<<<NB * NH * U, 64, 0, stream>>>(Y2, MT, CTX, Lx, U, NCH);

    // output projection + residual + LN1
    castb_k<<<(n4 + 255) / 256, 256, 0, stream>>>(CTX, Xb, n4);
    mgemm_k<0, 0><<<dim3(4, M / 128), 256, 0, stream>>>(
        Xb, Wob + (size_t)layer * 262144, bo + layer * DM, Y2, nullptr, M, DM, DM);
    ln_k<<<M, 128, 0, stream>>>(X, Y2, ln1_g + layer * DM, ln1_b + layer * DM, X);

    // FFN (GELU fused; hidden kept in bf16)
    castb_k<<<(n4 + 255) / 256, 256, 0, stream>>>(X, Xb, n4);
    mgemm_k<1, 1><<<dim3(16, M / 128), 256, 0, stream>>>(
        Xb, W1b + (size_t)layer * 1048576, b1 + layer * 2048, nullptr, Hb,
        M, 2048, DM);
    mgemm_k<0, 0><<<dim3(4, M / 128), 256, 0, stream>>>(
        Hb, W2b + (size_t)layer * 1048576, b2 + layer * DM, Y2, nullptr,
        M, DM, 2048);
    ln_k<<<M, 128, 0, stream>>>(X, Y2, ln2_g + layer * DM, ln2_b + layer * DM, X);

    if (layer == 0) {
      im2col_k<<<(8192 * 1536) / 256, 256, 0, stream>>>(X, Hb);
      mgemm_k<0, 0><<<dim3(4, 64), 256, 0, stream>>>(
          Hb, Cwb, conv_b, CTX, nullptr, 8192, DM, 1536);
      bn1_k<<<32, 256, 0, stream>>>(CTX, BNps, BNpq);
      bn2_k<<<1, 512, 0, stream>>>(BNps, BNpq, BNmu, BNvr);
      bn_elu_k<<<(8192 * 512) / 256, 256, 0, stream>>>(CTX, BNmu, BNvr, bn_g,
                                                       bn_b, Qb);
      maxpool_k<<<(NB * 1024 * 512) / 256, 256, 0, stream>>>(Qb, X);
    }
  }

  // final LN + projection (N=32, fp32)
  ln_k<<<NB * 1024, 128, 0, stream>>>(X, nullptr, normf_g, normf_b, Qb);
  gemm_k<<<dim3(1, 4096 / 64), 256, 0, stream>>>(Qb, proj_w, proj_b, out,
                                                 4096, 32, DM);
}

// Round 4
// 1292.970 us; speedup vs baseline: 3.1439x; 1.0720x over previous
//
#include <hip/hip_runtime.h>
#include <cstdint>
#include <cmath>

// ---------------------------------------------------------------------------
// Informer encoder forward (B=4, L=2048, ENC_IN=32, D_MODEL=512, D_FF=2048,
// E_LAYERS=2, H=8, FACTOR=5).
// Round 4: ILP-8 qk_m gather kernel; bf16 outputs fused into producers
// (token_embed / ln / maxpool / fillctx / merge) — castb passes removed.
// ---------------------------------------------------------------------------

#define NB 4
#define DM 512
#define NH 8
#define HD 64

typedef unsigned short ushort_t;
typedef __bf16 bf16x8 __attribute__((ext_vector_type(8)));
typedef float floatx4 __attribute__((ext_vector_type(4)));

// ---------------- fp32 -> bf16 (RNE) ---------------------------------------
__device__ inline ushort_t f2b(float f) {
  uint32_t u = __float_as_uint(f);
  uint32_t r = (u + 0x7fffu + ((u >> 16) & 1u)) >> 16;
  return (ushort_t)r;
}

__global__ void castb_k(const float* __restrict__ in,
                        ushort_t* __restrict__ out, int n4) {
  int i = blockIdx.x * 256 + threadIdx.x;
  if (i < n4) {
    float4 v = ((const float4*)in)[i];
    ushort4 o;
    o.x = f2b(v.x); o.y = f2b(v.y); o.z = f2b(v.z); o.w = f2b(v.w);
    ((ushort4*)out)[i] = o;
  }
}

// ---------------- Threefry2x32 (exact JAX semantics) -----------------------
__host__ __device__ inline void threefry2x32(uint32_t k0, uint32_t k1,
                                             uint32_t c0, uint32_t c1,
                                             uint32_t* o0, uint32_t* o1) {
  uint32_t ks0 = k0, ks1 = k1, ks2 = k0 ^ k1 ^ 0x1BD11BDAu;
  uint32_t x0 = c0 + ks0;
  uint32_t x1 = c1 + ks1;
  const uint32_t rotA[4] = {13u, 15u, 26u, 6u};
  const uint32_t rotB[4] = {17u, 29u, 16u, 24u};
  uint32_t ks[3] = {ks0, ks1, ks2};
  #pragma unroll
  for (int i = 0; i < 5; ++i) {
    const uint32_t* r = (i & 1) ? rotB : rotA;
    #pragma unroll
    for (int j = 0; j < 4; ++j) {
      x0 += x1;
      x1 = (x1 << r[j]) | (x1 >> (32u - r[j]));
      x1 ^= x0;
    }
    x0 += ks[(i + 1) % 3];
    x1 += ks[(i + 2) % 3] + (uint32_t)(i + 1);
  }
  *o0 = x0; *o1 = x1;
}

__global__ void gen_idx_k(int* __restrict__ idx, int n, int mask,
                          uint32_t k0, uint32_t k1) {
  int i = blockIdx.x * 256 + threadIdx.x;
  if (i < n) {
    uint32_t o0, o1;
    threefry2x32(k0, k1, 0u, (uint32_t)i, &o0, &o1);
    idx[i] = (int)((o0 ^ o1) & (uint32_t)mask);
  }
}

// ---------------- wave helpers ---------------------------------------------
__device__ inline float wave_sum64(float v) {
  #pragma unroll
  for (int o = 32; o > 0; o >>= 1) v += __shfl_xor(v, o, 64);
  return v;
}
__device__ inline float wave_max64(float v) {
  #pragma unroll
  for (int o = 32; o > 0; o >>= 1) v = fmaxf(v, __shfl_xor(v, o, 64));
  return v;
}

// ---------------- token embedding + positional encoding --------------------
__global__ __launch_bounds__(256) void token_embed_k(
    const float* __restrict__ xe, const float* __restrict__ w,
    float* __restrict__ X, ushort_t* __restrict__ Xb) {
  int bl = blockIdx.x;
  int b = bl >> 11, l = bl & 2047;
  __shared__ float xin[3][32];
  int t = threadIdx.x;
  if (t < 96) {
    int tt = t >> 5, c = t & 31;
    int ls = (l + tt - 1) & 2047;
    xin[tt][c] = xe[((size_t)b * 2048 + ls) * 32 + c];
  }
  __syncthreads();
  float pos = (float)l;
  for (int d = t; d < DM; d += 256) {
    float acc = 0.f;
    const float* wd = &w[d * 96];
    #pragma unroll
    for (int c = 0; c < 32; ++c) {
      acc += xin[0][c] * wd[c * 3 + 0] + xin[1][c] * wd[c * 3 + 1] +
             xin[2][c] * wd[c * 3 + 2];
    }
    int j2 = d & ~1;
    float div = expf((float)j2 * -1.7988946039e-2f);  // -ln(10000)/512
    float pe = (d & 1) ? cosf(pos * div) : sinf(pos * div);
    float v = acc + pe;
    size_t off = ((size_t)b * 2048 + l) * DM + d;
    X[off] = v;
    Xb[off] = f2b(v);
  }
}

// ---------------- bf16 MFMA GEMM: C = act(A @ W^T + bias) ------------------
__device__ inline void gload16(const ushort_t* g, ushort_t* l) {
  __builtin_amdgcn_global_load_lds(
      (const __attribute__((address_space(1))) unsigned int*)(const void*)g,
      (__attribute__((address_space(3))) unsigned int*)(void*)l, 16, 0, 0);
}

template <int GELU, int OBF>
__global__ __launch_bounds__(256) void mgemm_k(
    const ushort_t* __restrict__ A, const ushort_t* __restrict__ W,
    const float* __restrict__ bias, float* __restrict__ Cf,
    ushort_t* __restrict__ Cb, int M, int N, int K) {
  __shared__ ushort_t As[128 * 32];
  __shared__ ushort_t Bs[128 * 32];
  int m0 = blockIdx.y * 128, n0 = blockIdx.x * 128;
  int t = threadIdx.x;
  int lane = t & 63, wv = t >> 6;
  int sr = lane >> 2, sc = (lane & 3) * 8;
  int ra0 = wv * 32 + sr, ra1 = ra0 + 16;
  const ushort_t* gA0 = A + (size_t)(m0 + ra0) * K + sc;
  const ushort_t* gA1 = A + (size_t)(m0 + ra1) * K + sc;
  const ushort_t* gB0 = W + (size_t)(n0 + ra0) * K + sc;
  const ushort_t* gB1 = W + (size_t)(n0 + ra1) * K + sc;
  ushort_t* lA0 = As + wv * 1024;
  ushort_t* lA1 = lA0 + 512;
  ushort_t* lB0 = Bs + wv * 1024;
  ushort_t* lB1 = lB0 + 512;

  int quad = lane >> 4, lr = lane & 15;
  int wm = wv >> 1, wn = wv & 1;

  floatx4 acc[4][4] = {};
  for (int ks = 0; ks < K; ks += 32) {
    gload16(gA0, lA0);
    gload16(gA1, lA1);
    gload16(gB0, lB0);
    gload16(gB1, lB1);
    gA0 += 32; gA1 += 32; gB0 += 32; gB1 += 32;
    __syncthreads();
    bf16x8 av[4], bv[4];
    #pragma unroll
    for (int mt = 0; mt < 4; ++mt)
      av[mt] = *(const bf16x8*)&As[(wm * 64 + mt * 16 + lr) * 32 + quad * 8];
    #pragma unroll
    for (int nt = 0; nt < 4; ++nt)
      bv[nt] = *(const bf16x8*)&Bs[(wn * 64 + nt * 16 + lr) * 32 + quad * 8];
    #pragma unroll
    for (int mt = 0; mt < 4; ++mt)
      #pragma unroll
      for (int nt = 0; nt < 4; ++nt)
        acc[mt][nt] = __builtin_amdgcn_mfma_f32_16x16x32_bf16(
            av[mt], bv[nt], acc[mt][nt], 0, 0, 0);
    __syncthreads();
  }
  #pragma unroll
  for (int nt = 0; nt < 4; ++nt) {
    int col = n0 + wn * 64 + nt * 16 + lr;
    float bsv = bias[col];
    #pragma unroll
    for (int mt = 0; mt < 4; ++mt) {
      int row0 = m0 + wm * 64 + mt * 16 + quad * 4;
      #pragma unroll
      for (int r = 0; r < 4; ++r) {
        float v = acc[mt][nt][r] + bsv;
        if (GELU) v = 0.5f * v * (1.0f + erff(v * 0.70710678118654752f));
        if (OBF)
          Cb[(size_t)(row0 + r) * N + col] = f2b(v);
        else
          Cf[(size_t)(row0 + r) * N + col] = v;
      }
    }
  }
}

// ---------------- fp32 fallback GEMM (final projection, N=32) --------------
__global__ __launch_bounds__(256) void gemm_k(
    const float* __restrict__ A, const float* __restrict__ W,
    const float* __restrict__ bias, float* __restrict__ C,
    int M, int N, int K) {
  __shared__ float As2[16][64 + 4];
  __shared__ float Ws2[16][64 + 4];
  int m0 = blockIdx.y * 64, n0 = blockIdx.x * 64;
  int t = threadIdx.x;
  int tx = t & 15, ty = t >> 4;
  float acc[4][4] = {};
  for (int k0 = 0; k0 < K; k0 += 16) {
    #pragma unroll
    for (int i = 0; i < 4; ++i) {
      int li = t + i * 256;
      int m = li >> 4, kk = li & 15;
      As2[kk][m] = A[(size_t)(m0 + m) * K + k0 + kk];
    }
    #pragma unroll
    for (int i = 0; i < 4; ++i) {
      int li = t + i * 256;
      int n = li >> 4, kk = li & 15;
      int gn = n0 + n;
      Ws2[kk][n] = (gn < N) ? W[(size_t)gn * K + k0 + kk] : 0.0f;
    }
    __syncthreads();
    #pragma unroll
    for (int kk = 0; kk < 16; ++kk) {
      float4 avv = *(const float4*)&As2[kk][ty * 4];
      float4 bvv = *(const float4*)&Ws2[kk][tx * 4];
      float a[4] = {avv.x, avv.y, avv.z, avv.w};
      float bb[4] = {bvv.x, bvv.y, bvv.z, bvv.w};
      #pragma unroll
      for (int i = 0; i < 4; ++i)
        #pragma unroll
        for (int j = 0; j < 4; ++j) acc[i][j] += a[i] * bb[j];
    }
    __syncthreads();
  }
  #pragma unroll
  for (int i = 0; i < 4; ++i) {
    int m = m0 + ty * 4 + i;
    #pragma unroll
    for (int j = 0; j < 4; ++j) {
      int n = n0 + tx * 4 + j;
      if (n < N) C[(size_t)m * N + n] = acc[i][j] + bias[n];
    }
  }
}

// ---------------- LayerNorm (+optional residual, +optional bf16 copy) ------
__global__ __launch_bounds__(128) void ln_k(
    const float* __restrict__ A, const float* __restrict__ Bres,
    const float* __restrict__ g, const float* __restrict__ be,
    float* __restrict__ O, ushort_t* __restrict__ Ob) {
  int r = blockIdx.x, t = threadIdx.x;
  __shared__ float lds[2];
  float4 v = ((const float4*)(A + (size_t)r * DM))[t];
  if (Bres) {
    float4 u = ((const float4*)(Bres + (size_t)r * DM))[t];
    v.x += u.x; v.y += u.y; v.z += u.z; v.w += u.w;
  }
  float s = wave_sum64(v.x + v.y + v.z + v.w);
  int w = t >> 6;
  if ((t & 63) == 0) lds[w] = s;
  __syncthreads();
  float mu = (lds[0] + lds[1]) * (1.0f / 512.0f);
  __syncthreads();
  float dx = v.x - mu, dy = v.y - mu, dz = v.z - mu, dw = v.w - mu;
  float sq = wave_sum64(dx * dx + dy * dy + dz * dz + dw * dw);
  if ((t & 63) == 0) lds[w] = sq;
  __syncthreads();
  float var = (lds[0] + lds[1]) * (1.0f / 512.0f);
  float inv = 1.0f / sqrtf(var + 1e-5f);
  float4 gv = ((const float4*)g)[t];
  float4 bv = ((const float4*)be)[t];
  float4 o;
  o.x = dx * inv * gv.x + bv.x;
  o.y = dy * inv * gv.y + bv.y;
  o.z = dz * inv * gv.z + bv.z;
  o.w = dw * inv * gv.w + bv.w;
  ((float4*)(O + (size_t)r * DM))[t] = o;
  if (Ob) {
    ushort4 ob;
    ob.x = f2b(o.x); ob.y = f2b(o.y); ob.z = f2b(o.z); ob.w = f2b(o.w);
    ((ushort4*)(Ob + (size_t)r * DM))[t] = ob;
  }
}

// ---------------- M[b,h,l] = max_u(q.k_idx) - sum_u(q.k_idx)/Lx ------------
// ILP-8: 8 gathers in flight, 8 interleaved butterfly reduction chains.
template <int UU>
__global__ __launch_bounds__(256) void qk_m_k(
    const float* __restrict__ Q, const float* __restrict__ K,
    const int* __restrict__ idx, float* __restrict__ Mout, int Lx) {
  int item = (blockIdx.x << 2) | (threadIdx.x >> 6);
  int lane = threadIdx.x & 63;
  int l = item % Lx;
  int bh = item / Lx;
  int h = bh & 7, b = bh >> 3;
  const float* Kbase = K + (size_t)b * Lx * DM + h * HD + lane;
  float qd = Q[((size_t)b * Lx + l) * DM + h * HD + lane];
  float maxv = -INFINITY, sumv = 0.f;
  const int* ip = idx + (size_t)l * UU;
  #pragma unroll
  for (int u0 = 0; u0 < UU; u0 += 8) {
    float p[8];
    #pragma unroll
    for (int j = 0; j < 8; ++j) {
      if (u0 + j < UU) {
        int ki = ip[u0 + j];
        p[j] = Kbase[(size_t)ki * DM];
      } else {
        p[j] = 0.f;
      }
    }
    #pragma unroll
    for (int j = 0; j < 8; ++j)
      if (u0 + j < UU) p[j] *= qd;
    #pragma unroll
    for (int off = 32; off > 0; off >>= 1) {
      #pragma unroll
      for (int j = 0; j < 8; ++j)
        if (u0 + j < UU) p[j] += __shfl_xor(p[j], off, 64);
    }
    #pragma unroll
    for (int j = 0; j < 8; ++j) {
      if (u0 + j < UU) { maxv = fmaxf(maxv, p[j]); sumv += p[j]; }
    }
  }
  if (lane == 0) Mout[item] = maxv - sumv / (float)Lx;
}

// ---------------- top-U indices of M per (b,h) -----------------------------
__global__ __launch_bounds__(256) void topk_k(
    const float* __restrict__ Mbuf, int* __restrict__ Mtop, int Lx, int U) {
  int bh = blockIdx.x;
  const float* m = Mbuf + (size_t)bh * Lx;
  __shared__ float mcopy[2048];
  __shared__ float sv[256];
  __shared__ int si[256];
  int t = threadIdx.x;
  for (int i = t; i < Lx; i += 256) mcopy[i] = m[i];
  __syncthreads();
  for (int u = 0; u < U; ++u) {
    float bv = -INFINITY;
    int bi = 0x7fffffff;
    for (int i = t; i < Lx; i += 256) {
      float v = mcopy[i];
      if (v > bv || (v == bv && i < bi)) { bv = v; bi = i; }
    }
    sv[t] = bv; si[t] = bi;
    __syncthreads();
    for (int s = 128; s > 0; s >>= 1) {
      if (t < s) {
        float v2 = sv[t + s]; int i2 = si[t + s];
        if (v2 > sv[t] || (v2 == sv[t] && i2 < si[t])) { sv[t] = v2; si[t] = i2; }
      }
      __syncthreads();
    }
    if (t == 0) {
      Mtop[bh * U + u] = si[0];
      mcopy[si[0]] = -INFINITY;
    }
    __syncthreads();
  }
}

// ---------------- meanV: two-stage coalesced column reduction --------------
__global__ __launch_bounds__(512) void meanv1_k(const float* __restrict__ V,
                                                float* __restrict__ part,
                                                int Lx) {
  int b = blockIdx.x >> 4, chunk = blockIdx.x & 15;
  int rows = Lx >> 4;
  int t = threadIdx.x;  // 512
  const float* vp = V + ((size_t)b * Lx + (size_t)chunk * rows) * DM + t;
  float s = 0.f;
  for (int l = 0; l < rows; ++l) s += vp[(size_t)l * DM];
  part[(size_t)blockIdx.x * DM + t] = s;
}
__global__ __launch_bounds__(512) void meanv2_k(const float* __restrict__ part,
                                                float* __restrict__ mv,
                                                int Lx) {
  int b = blockIdx.x, t = threadIdx.x;
  float s = 0.f;
  #pragma unroll
  for (int c = 0; c < 16; ++c) s += part[(size_t)(b * 16 + c) * DM + t];
  mv[b * DM + t] = s / (float)Lx;
}

// ctx (bf16) broadcast fill with meanV
__global__ void fillctx_k(ushort_t* __restrict__ ctx,
                          const float* __restrict__ mv, int Lx) {
  size_t i4 = (size_t)blockIdx.x * 256 + threadIdx.x;  // element/4 index
  int col4 = (int)(i4 & 127);
  size_t row = i4 >> 7;
  int b = (int)(row / (size_t)Lx);
  const float* m = mv + b * DM + col4 * 4;
  ushort4 o;
  o.x = f2b(m[0]); o.y = f2b(m[1]); o.z = f2b(m[2]); o.w = f2b(m[3]);
  ((ushort4*)ctx)[i4] = o;
}

// ---------------- flash split-K attention for top-U queries ----------------
__global__ __launch_bounds__(512) void attn_flash_k(
    const float* __restrict__ Q, const float* __restrict__ K,
    const float* __restrict__ V, const int* __restrict__ Mtop,
    float* __restrict__ part, int Lx, int U, int nchunk) {
  int blk = blockIdx.x;
  int chunk = blk % nchunk, bh = blk / nchunk;
  int h = bh & 7, b = bh >> 3;
  int rows = Lx / nchunk;
  int ntile = rows >> 6;
  __shared__ float s_q[40 * 64];
  __shared__ float s_k[64 * 65];
  __shared__ float s_v[64 * 65];
  __shared__ float s_p[40 * 64];
  __shared__ float s_m[40], s_l[40], s_a[40];
  int t = threadIdx.x;
  int d = t & 63, wv = t >> 6;

  for (int i = t; i < U * 64; i += 512) {
    int u = i >> 6, dd = i & 63;
    int qi = Mtop[bh * U + u];
    s_q[i] = Q[((size_t)b * Lx + qi) * DM + h * HD + dd] * 0.125f;
  }
  if (t < U) { s_m[t] = -INFINITY; s_l[t] = 0.f; s_a[t] = 0.f; }
  float o[5] = {0.f, 0.f, 0.f, 0.f, 0.f};
  __syncthreads();

  const float* Kp = K + (size_t)b * Lx * DM + h * HD;
  const float* Vp = V + (size_t)b * Lx * DM + h * HD;

  for (int tile = 0; tile < ntile; ++tile) {
    int kr0 = chunk * rows + tile * 64;
    {
      int r = t >> 4, c4 = (t & 15) * 4;
      #pragma unroll
      for (int pass = 0; pass < 2; ++pass) {
        int rr = r + pass * 32;
        float4 kv = *(const float4*)&Kp[(size_t)(kr0 + rr) * DM + c4];
        float4 vv = *(const float4*)&Vp[(size_t)(kr0 + rr) * DM + c4];
        float* kd = &s_k[rr * 65 + c4];
        kd[0] = kv.x; kd[1] = kv.y; kd[2] = kv.z; kd[3] = kv.w;
        float* vd = &s_v[rr * 65 + c4];
        vd[0] = vv.x; vd[1] = vv.y; vd[2] = vv.z; vd[3] = vv.w;
      }
    }
    __syncthreads();
    {
      float kr[64];
      #pragma unroll
      for (int dd = 0; dd < 64; ++dd) kr[dd] = s_k[d * 65 + dd];
      for (int u = wv; u < U; u += 8) {
        float acc = 0.f;
        #pragma unroll
        for (int c = 0; c < 16; ++c) {
          float4 qv = *(const float4*)&s_q[u * 64 + c * 4];
          acc += qv.x * kr[c * 4] + qv.y * kr[c * 4 + 1] +
                 qv.z * kr[c * 4 + 2] + qv.w * kr[c * 4 + 3];
        }
        s_p[u * 64 + d] = acc;
      }
    }
    __syncthreads();
    for (int u = wv; u < U; u += 8) {
      float sv_ = s_p[u * 64 + d];
      float mx = wave_max64(sv_);
      float mold = s_m[u];
      float mnew = fmaxf(mold, mx);
      float e = expf(sv_ - mnew);
      float se = wave_sum64(e);
      s_p[u * 64 + d] = e;
      if (d == 0) {
        float alpha = expf(mold - mnew);
        s_a[u] = alpha;
        s_l[u] = s_l[u] * alpha + se;
        s_m[u] = mnew;
      }
    }
    __syncthreads();
    {
      float vr[64];
      #pragma unroll
      for (int k = 0; k < 64; ++k) vr[k] = s_v[k * 65 + d];
      int i = 0;
      for (int u = wv; u < U; u += 8, ++i) {
        float acc = 0.f;
        #pragma unroll
        for (int c = 0; c < 16; ++c) {
          float4 pv = *(const float4*)&s_p[u * 64 + c * 4];
          acc += pv.x * vr[c * 4] + pv.y * vr[c * 4 + 1] +
                 pv.z * vr[c * 4 + 2] + pv.w * vr[c * 4 + 3];
        }
        o[i] = o[i] * s_a[u] + acc;
      }
    }
    __syncthreads();
  }
  {
    int i = 0;
    for (int u = wv; u < U; u += 8, ++i) {
      float* pp = part + ((size_t)(bh * nchunk + chunk) * U + u) * 66;
      pp[d] = o[i];
      if (d == 0) { pp[64] = s_m[u]; pp[65] = s_l[u]; }
    }
  }
}

// merge partials, scatter into bf16 ctx
__global__ __launch_bounds__(64) void attn_merge_k(
    const float* __restrict__ part, const int* __restrict__ Mtop,
    ushort_t* __restrict__ ctx, int Lx, int U, int nchunk) {
  int bu = blockIdx.x;
  int u = bu % U, bh = bu / U;
  int h = bh & 7, b = bh >> 3;
  int d = threadIdx.x;  // 64
  float M = -INFINITY;
  for (int c = 0; c < nchunk; ++c)
    M = fmaxf(M, part[((size_t)(bh * nchunk + c) * U + u) * 66 + 64]);
  float L = 0.f, O = 0.f;
  for (int c = 0; c < nchunk; ++c) {
    const float* pp = part + ((size_t)(bh * nchunk + c) * U + u) * 66;
    float w = expf(pp[64] - M);
    L += pp[65] * w;
    O += pp[d] * w;
  }
  int qi = Mtop[bh * U + u];
  ctx[((size_t)b * Lx + qi) * DM + h * HD + d] = f2b(O / L);
}

// ---------------- im2col (circular, k=3) -> bf16 ---------------------------
__global__ void im2col_k(const float* __restrict__ X,
                         ushort_t* __restrict__ A2) {
  size_t gid = (size_t)blockIdx.x * 256 + threadIdx.x;  // 8192*1536
  int col = (int)(gid % 1536);
  size_t row = gid / 1536;
  int i = col / 3, tt = col % 3;
  int b = (int)(row >> 11), l = (int)(row & 2047);
  int ls = (l + tt - 1) & 2047;
  A2[gid] = f2b(X[((size_t)b * 2048 + ls) * DM + i]);
}

// ---------------- batch-norm stats: coalesced two-stage --------------------
__global__ __launch_bounds__(256) void bn1_k(const float* __restrict__ Y,
                                             float* __restrict__ ps,
                                             float* __restrict__ pq) {
  int blk = blockIdx.x;
  int t = threadIdx.x;
  float s0 = 0, q0 = 0, s1 = 0, q1 = 0;
  const float* base = Y + (size_t)blk * 256 * DM;
  for (int r = 0; r < 256; ++r) {
    float a = base[(size_t)r * DM + t];
    float b = base[(size_t)r * DM + t + 256];
    s0 += a; q0 += a * a; s1 += b; q1 += b * b;
  }
  ps[blk * DM + t] = s0; ps[blk * DM + t + 256] = s1;
  pq[blk * DM + t] = q0; pq[blk * DM + t + 256] = q1;
}
__global__ __launch_bounds__(512) void bn2_k(const float* __restrict__ ps,
                                             const float* __restrict__ pq,
                                             float* __restrict__ mu,
                                             float* __restrict__ var) {
  int t = threadIdx.x;
  float s = 0, q = 0;
  #pragma unroll
  for (int c = 0; c < 32; ++c) { s += ps[c * DM + t]; q += pq[c * DM + t]; }
  float m = s * (1.0f / 8192.f);
  mu[t] = m;
  var[t] = q * (1.0f / 8192.f) - m * m;
}

__global__ void bn_elu_k(const float* __restrict__ Y,
                         const float* __restrict__ mu,
                         const float* __restrict__ var,
                         const float* __restrict__ g,
                         const float* __restrict__ be, float* __restrict__ O) {
  size_t i = (size_t)blockIdx.x * 256 + threadIdx.x;
  int c = (int)(i & 511);
  float v = (Y[i] - mu[c]) / sqrtf(var[c] + 1e-5f) * g[c] + be[c];
  O[i] = v > 0.f ? v : expm1f(v);
}

// maxpool k=3 s=2 pad=1, emits fp32 + bf16
__global__ void maxpool_k(const float* __restrict__ Y, float* __restrict__ O,
                          ushort_t* __restrict__ Ob) {
  size_t i = (size_t)blockIdx.x * 256 + threadIdx.x;  // 4*1024*512
  int c = (int)(i & 511);
  size_t row = i >> 9;
  int lo = (int)(row & 1023);
  int b = (int)(row >> 10);
  int l0 = 2 * lo - 1;
  float m = -INFINITY;
  #pragma unroll
  for (int tt = 0; tt < 3; ++tt) {
    int l = l0 + tt;
    if (l >= 0 && l < 2048) m = fmaxf(m, Y[((size_t)b * 2048 + l) * DM + c]);
  }
  O[i] = m;
  Ob[i] = f2b(m);
}

// ---------------------------------------------------------------------------
extern "C" void kernel_launch(void* const* d_in, const int* in_sizes, int n_in,
                              void* d_out, int out_size, void* d_ws,
                              size_t ws_size, hipStream_t stream) {
  (void)in_sizes; (void)n_in; (void)out_size; (void)ws_size;
  const float* x_enc  = (const float*)d_in[0];
  const float* tok_w  = (const float*)d_in[1];
  const float* Wq     = (const float*)d_in[2];
  const float* bq     = (const float*)d_in[3];
  const float* Wk     = (const float*)d_in[4];
  const float* bk     = (const float*)d_in[5];
  const float* Wv     = (const float*)d_in[6];
  const float* bv     = (const float*)d_in[7];
  const float* Wo     = (const float*)d_in[8];
  const float* bo     = (const float*)d_in[9];
  const float* W1     = (const float*)d_in[10];
  const float* b1     = (const float*)d_in[11];
  const float* W2     = (const float*)d_in[12];
  const float* b2     = (const float*)d_in[13];
  const float* ln1_g  = (const float*)d_in[14];
  const float* ln1_b  = (const float*)d_in[15];
  const float* ln2_g  = (const float*)d_in[16];
  const float* ln2_b  = (const float*)d_in[17];
  const float* conv_w = (const float*)d_in[18];
  const float* conv_b = (const float*)d_in[19];
  const float* bn_g   = (const float*)d_in[20];
  const float* bn_b   = (const float*)d_in[21];
  const float* normf_g = (const float*)d_in[22];
  const float* normf_b = (const float*)d_in[23];
  const float* proj_w = (const float*)d_in[24];
  const float* proj_b = (const float*)d_in[25];
  float* out = (float*)d_out;
  float* ws = (float*)d_ws;

  // ---- fp32 workspace layout (float offsets) ----
  float* X    = ws;                    // 4,194,304
  float* Qb   = ws + 4194304;          // 4,194,304
  float* Kb   = ws + 8388608;          // 4,194,304
  float* Vb   = ws + 12582912;         // 4,194,304
  ushort_t* CTXb = (ushort_t*)(ws + 16777216);  // bf16 ctx (8 MB of 16 MB slot)
  float* Y2   = ws + 20971520;         // 4,194,304 (attn partials / conv out)
  float* Mb   = ws + 25165824;         // 65,536
  float* MV   = ws + 25231360;         // 2,048
  float* MVP  = ws + 25233408;         // 32,768
  float* BNps = ws + 25266176;         // 16,384
  float* BNpq = ws + 25282560;         // 16,384
  float* BNmu = ws + 25298944;         // 512
  float* BNvr = ws + 25299456;         // 512
  int*   IDX  = (int*)(ws + 25299968); // 81,920
  int*   MT   = (int*)(ws + 25381888); // 1,280
  // ---- bf16 workspace ----
  ushort_t* U0  = (ushort_t*)(ws + 25383168);
  ushort_t* Xb  = U0;                  // 4,194,304
  ushort_t* Hb  = U0 + 4194304;        // 16,777,216
  ushort_t* Wqb = U0 + 20971520;
  ushort_t* Wkb = U0 + 21495808;
  ushort_t* Wvb = U0 + 22020096;
  ushort_t* Wob = U0 + 22544384;
  ushort_t* W1b = U0 + 23068672;
  ushort_t* W2b = U0 + 25165824;
  ushort_t* Cwb = U0 + 27262976;

  castb_k<<<512, 256, 0, stream>>>(Wq, Wqb, 131072);
  castb_k<<<512, 256, 0, stream>>>(Wk, Wkb, 131072);
  castb_k<<<512, 256, 0, stream>>>(Wv, Wvb, 131072);
  castb_k<<<512, 256, 0, stream>>>(Wo, Wob, 131072);
  castb_k<<<2048, 256, 0, stream>>>(W1, W1b, 524288);
  castb_k<<<2048, 256, 0, stream>>>(W2, W2b, 524288);
  castb_k<<<768, 256, 0, stream>>>(conv_w, Cwb, 196608);

  token_embed_k<<<NB * 2048, 256, 0, stream>>>(x_enc, tok_w, X, Xb);

  for (int layer = 0; layer < 2; ++layer) {
    const int Lx = (layer == 0) ? 2048 : 1024;
    const int U  = (layer == 0) ? 40 : 35;
    const int M  = NB * Lx;
    const int NCH = 8;

    uint32_t kl0, kl1, s0, s1;
    threefry2x32(0u, 42u, 0u, (uint32_t)layer, &kl0, &kl1);
    threefry2x32(kl0, kl1, 0u, 1u, &s0, &s1);
    int nidx = Lx * U;
    gen_idx_k<<<(nidx + 255) / 256, 256, 0, stream>>>(IDX, nidx, Lx - 1, s0, s1);

    // QKV (bf16 MFMA); Xb produced by token_embed / maxpool / ln2
    mgemm_k<0, 0><<<dim3(4, M / 128), 256, 0, stream>>>(
        Xb, Wqb + (size_t)layer * 262144, bq + layer * DM, Qb, nullptr, M, DM, DM);
    mgemm_k<0, 0><<<dim3(4, M / 128), 256, 0, stream>>>(
        Xb, Wkb + (size_t)layer * 262144, bk + layer * DM, Kb, nullptr, M, DM, DM);
    mgemm_k<0, 0><<<dim3(4, M / 128), 256, 0, stream>>>(
        Xb, Wvb + (size_t)layer * 262144, bv + layer * DM, Vb, nullptr, M, DM, DM);

    // ProbSparse attention
    if (layer == 0)
      qk_m_k<40><<<NB * NH * Lx / 4, 256, 0, stream>>>(Qb, Kb, IDX, Mb, Lx);
    else
      qk_m_k<35><<<NB * NH * Lx / 4, 256, 0, stream>>>(Qb, Kb, IDX, Mb, Lx);
    topk_k<<<NB * NH, 256, 0, stream>>>(Mb, MT, Lx, U);
    meanv1_k<<<NB * 16, 512, 0, stream>>>(Vb, MVP, Lx);
    meanv2_k<<<NB, 512, 0, stream>>>(MVP, MV, Lx);
    fillctx_k<<<(M * DM / 4) / 256, 256, 0, stream>>>(CTXb, MV, Lx);
    attn_flash_k<<<NB * NH * NCH, 512, 0, stream>>>(Qb, Kb, Vb, MT, Y2, Lx, U, NCH);
    attn_merge_k<<<NB * NH * U, 64, 0, stream>>>(Y2, MT, CTXb, Lx, U, NCH);

    // output projection + residual + LN1 (emits bf16 for FFN1)
    mgemm_k<0, 0><<<dim3(4, M / 128), 256, 0, stream>>>(
        CTXb, Wob + (size_t)layer * 262144, bo + layer * DM, Y2, nullptr, M, DM, DM);
    ln_k<<<M, 128, 0, stream>>>(X, Y2, ln1_g + layer * DM, ln1_b + layer * DM, X, Xb);

    // FFN (GELU fused; hidden kept in bf16); LN2 emits bf16 for next layer QKV
    mgemm_k<1, 1><<<dim3(16, M / 128), 256, 0, stream>>>(
        Xb, W1b + (size_t)layer * 1048576, b1 + layer * 2048, nullptr, Hb,
        M, 2048, DM);
    mgemm_k<0, 0><<<dim3(4, M / 128), 256, 0, stream>>>(
        Hb, W2b + (size_t)layer * 1048576, b2 + layer * DM, Y2, nullptr,
        M, DM, 2048);
    ln_k<<<M, 128, 0, stream>>>(X, Y2, ln2_g + layer * DM, ln2_b + layer * DM, X, Xb);

    if (layer == 0) {
      im2col_k<<<(8192 * 1536) / 256, 256, 0, stream>>>(X, Hb);
      mgemm_k<0, 0><<<dim3(4, 64), 256, 0, stream>>>(
          Hb, Cwb, conv_b, Y2, nullptr, 8192, DM, 1536);
      bn1_k<<<32, 256, 0, stream>>>(Y2, BNps, BNpq);
      bn2_k<<<1, 512, 0, stream>>>(BNps, BNpq, BNmu, BNvr);
      bn_elu_k<<<(8192 * 512) / 256, 256, 0, stream>>>(Y2, BNmu, BNvr, bn_g,
                                                       bn_b, Qb);
      maxpool_k<<<(NB * 1024 * 512) / 256, 256, 0, stream>>>(Qb, X, Xb);
    }
  }

  // final LN + projection (N=32, fp32)
  ln_k<<<NB * 1024, 128, 0, stream>>>(X, nullptr, normf_g, normf_b, Qb, nullptr);
  gemm_k<<<dim3(1, 4096 / 64), 256, 0, stream>>>(Qb, proj_w, proj_b, out,
                                                 4096, 32, DM);
}

// Round 5
// 1150.273 us; speedup vs baseline: 3.5339x; 1.1241x over previous
//
#include <hip/hip_runtime.h>
#include <cstdint>
#include <cmath>

// ---------------------------------------------------------------------------
// Informer encoder forward (B=4, L=2048, ENC_IN=32, D_MODEL=512, D_FF=2048,
// E_LAYERS=2, H=8, FACTOR=5).
// Round 5: token embedding as bf16 MFMA GEMM (+PE table, fused epilogue);
// distil im2col vectorized via [t][c] layout (transposed conv weight).
// ---------------------------------------------------------------------------

#define NB 4
#define DM 512
#define NH 8
#define HD 64

typedef unsigned short ushort_t;
typedef __bf16 bf16x8 __attribute__((ext_vector_type(8)));
typedef float floatx4 __attribute__((ext_vector_type(4)));

__device__ inline ushort_t f2b(float f) {
  uint32_t u = __float_as_uint(f);
  uint32_t r = (u + 0x7fffu + ((u >> 16) & 1u)) >> 16;
  return (ushort_t)r;
}

__global__ void castb_k(const float* __restrict__ in,
                        ushort_t* __restrict__ out, int n4) {
  int i = blockIdx.x * 256 + threadIdx.x;
  if (i < n4) {
    float4 v = ((const float4*)in)[i];
    ushort4 o;
    o.x = f2b(v.x); o.y = f2b(v.y); o.z = f2b(v.z); o.w = f2b(v.w);
    ((ushort4*)out)[i] = o;
  }
}

__global__ void zerofill_k(float* __restrict__ p, int n) {
  int i = blockIdx.x * 256 + threadIdx.x;
  if (i < n) p[i] = 0.f;
}

// conv weight: (D, I, 3) -> bf16 (D, 3, I) so im2col is coalesced
__global__ void castw_conv_k(const float* __restrict__ in,
                             ushort_t* __restrict__ out) {
  int gid = blockIdx.x * 256 + threadIdx.x;  // 512*1536
  int d = gid / 1536, r = gid - d * 1536;
  int t = r >> 9, i = r & 511;
  out[gid] = f2b(in[d * 1536 + i * 3 + t]);
}

__host__ __device__ inline void threefry2x32(uint32_t k0, uint32_t k1,
                                             uint32_t c0, uint32_t c1,
                                             uint32_t* o0, uint32_t* o1) {
  uint32_t ks0 = k0, ks1 = k1, ks2 = k0 ^ k1 ^ 0x1BD11BDAu;
  uint32_t x0 = c0 + ks0;
  uint32_t x1 = c1 + ks1;
  const uint32_t rotA[4] = {13u, 15u, 26u, 6u};
  const uint32_t rotB[4] = {17u, 29u, 16u, 24u};
  uint32_t ks[3] = {ks0, ks1, ks2};
  #pragma unroll
  for (int i = 0; i < 5; ++i) {
    const uint32_t* r = (i & 1) ? rotB : rotA;
    #pragma unroll
    for (int j = 0; j < 4; ++j) {
      x0 += x1;
      x1 = (x1 << r[j]) | (x1 >> (32u - r[j]));
      x1 ^= x0;
    }
    x0 += ks[(i + 1) % 3];
    x1 += ks[(i + 2) % 3] + (uint32_t)(i + 1);
  }
  *o0 = x0; *o1 = x1;
}

__global__ void gen_idx_k(int* __restrict__ idx, int n, int mask,
                          uint32_t k0, uint32_t k1) {
  int i = blockIdx.x * 256 + threadIdx.x;
  if (i < n) {
    uint32_t o0, o1;
    threefry2x32(k0, k1, 0u, (uint32_t)i, &o0, &o1);
    idx[i] = (int)((o0 ^ o1) & (uint32_t)mask);
  }
}

__device__ inline float wave_sum64(float v) {
  #pragma unroll
  for (int o = 32; o > 0; o >>= 1) v += __shfl_xor(v, o, 64);
  return v;
}
__device__ inline float wave_max64(float v) {
  #pragma unroll
  for (int o = 32; o > 0; o >>= 1) v = fmaxf(v, __shfl_xor(v, o, 64));
  return v;
}

// ---------------- positional-encoding table (2048 x 512) -------------------
__global__ void pe_k(float* __restrict__ pe) {
  int i = blockIdx.x * 256 + threadIdx.x;  // 1,048,576
  int d = i & 511, l = i >> 9;
  int j2 = d & ~1;
  float div = expf((float)j2 * -1.7988946039e-2f);  // -ln(10000)/512
  float ang = (float)l * div;
  pe[i] = (d & 1) ? cosf(ang) : sinf(ang);
}

// ---------------- im2col for token conv: (B*L, 96) bf16 --------------------
__global__ void im2col_tok_k(const float* __restrict__ xe,
                             ushort_t* __restrict__ A) {
  int gid = blockIdx.x * 256 + threadIdx.x;  // 8192*96
  int col = gid % 96;
  int row = gid / 96;
  int c = col / 3, t = col - c * 3;
  int b = row >> 11, l = row & 2047;
  int ls = (l + t - 1) & 2047;
  A[gid] = f2b(xe[((size_t)b * 2048 + ls) * 32 + c]);
}

// ---------------- bf16 MFMA GEMM: C = act(A @ W^T + bias [+ pe]) -----------
__device__ inline void gload16(const ushort_t* g, ushort_t* l) {
  __builtin_amdgcn_global_load_lds(
      (const __attribute__((address_space(1))) unsigned int*)(const void*)g,
      (__attribute__((address_space(3))) unsigned int*)(void*)l, 16, 0, 0);
}

template <int GELU, int OMODE, int ADDPE>
__global__ __launch_bounds__(256) void mgemm_k(
    const ushort_t* __restrict__ A, const ushort_t* __restrict__ W,
    const float* __restrict__ bias, float* __restrict__ Cf,
    ushort_t* __restrict__ Cb, const float* __restrict__ pe,
    int M, int N, int K) {
  __shared__ ushort_t As[128 * 32];
  __shared__ ushort_t Bs[128 * 32];
  int m0 = blockIdx.y * 128, n0 = blockIdx.x * 128;
  int t = threadIdx.x;
  int lane = t & 63, wv = t >> 6;
  int sr = lane >> 2, sc = (lane & 3) * 8;
  int ra0 = wv * 32 + sr, ra1 = ra0 + 16;
  const ushort_t* gA0 = A + (size_t)(m0 + ra0) * K + sc;
  const ushort_t* gA1 = A + (size_t)(m0 + ra1) * K + sc;
  const ushort_t* gB0 = W + (size_t)(n0 + ra0) * K + sc;
  const ushort_t* gB1 = W + (size_t)(n0 + ra1) * K + sc;
  ushort_t* lA0 = As + wv * 1024;
  ushort_t* lA1 = lA0 + 512;
  ushort_t* lB0 = Bs + wv * 1024;
  ushort_t* lB1 = lB0 + 512;

  int quad = lane >> 4, lr = lane & 15;
  int wm = wv >> 1, wn = wv & 1;

  floatx4 acc[4][4] = {};
  for (int ks = 0; ks < K; ks += 32) {
    gload16(gA0, lA0);
    gload16(gA1, lA1);
    gload16(gB0, lB0);
    gload16(gB1, lB1);
    gA0 += 32; gA1 += 32; gB0 += 32; gB1 += 32;
    __syncthreads();
    bf16x8 av[4], bv[4];
    #pragma unroll
    for (int mt = 0; mt < 4; ++mt)
      av[mt] = *(const bf16x8*)&As[(wm * 64 + mt * 16 + lr) * 32 + quad * 8];
    #pragma unroll
    for (int nt = 0; nt < 4; ++nt)
      bv[nt] = *(const bf16x8*)&Bs[(wn * 64 + nt * 16 + lr) * 32 + quad * 8];
    #pragma unroll
    for (int mt = 0; mt < 4; ++mt)
      #pragma unroll
      for (int nt = 0; nt < 4; ++nt)
        acc[mt][nt] = __builtin_amdgcn_mfma_f32_16x16x32_bf16(
            av[mt], bv[nt], acc[mt][nt], 0, 0, 0);
    __syncthreads();
  }
  #pragma unroll
  for (int nt = 0; nt < 4; ++nt) {
    int col = n0 + wn * 64 + nt * 16 + lr;
    float bsv = bias[col];
    #pragma unroll
    for (int mt = 0; mt < 4; ++mt) {
      int row0 = m0 + wm * 64 + mt * 16 + quad * 4;
      #pragma unroll
      for (int r = 0; r < 4; ++r) {
        int row = row0 + r;
        float v = acc[mt][nt][r] + bsv;
        if (ADDPE) v += pe[(size_t)(row & 2047) * N + col];
        if (GELU) v = 0.5f * v * (1.0f + erff(v * 0.70710678118654752f));
        if (OMODE == 0 || OMODE == 2) Cf[(size_t)row * N + col] = v;
        if (OMODE == 1 || OMODE == 2) Cb[(size_t)row * N + col] = f2b(v);
      }
    }
  }
}

// ---------------- fp32 fallback GEMM (final projection, N=32) --------------
__global__ __launch_bounds__(256) void gemm_k(
    const float* __restrict__ A, const float* __restrict__ W,
    const float* __restrict__ bias, float* __restrict__ C,
    int M, int N, int K) {
  __shared__ float As2[16][64 + 4];
  __shared__ float Ws2[16][64 + 4];
  int m0 = blockIdx.y * 64, n0 = blockIdx.x * 64;
  int t = threadIdx.x;
  int tx = t & 15, ty = t >> 4;
  float acc[4][4] = {};
  for (int k0 = 0; k0 < K; k0 += 16) {
    #pragma unroll
    for (int i = 0; i < 4; ++i) {
      int li = t + i * 256;
      int m = li >> 4, kk = li & 15;
      As2[kk][m] = A[(size_t)(m0 + m) * K + k0 + kk];
    }
    #pragma unroll
    for (int i = 0; i < 4; ++i) {
      int li = t + i * 256;
      int n = li >> 4, kk = li & 15;
      int gn = n0 + n;
      Ws2[kk][n] = (gn < N) ? W[(size_t)gn * K + k0 + kk] : 0.0f;
    }
    __syncthreads();
    #pragma unroll
    for (int kk = 0; kk < 16; ++kk) {
      float4 avv = *(const float4*)&As2[kk][ty * 4];
      float4 bvv = *(const float4*)&Ws2[kk][tx * 4];
      float a[4] = {avv.x, avv.y, avv.z, avv.w};
      float bb[4] = {bvv.x, bvv.y, bvv.z, bvv.w};
      #pragma unroll
      for (int i = 0; i < 4; ++i)
        #pragma unroll
        for (int j = 0; j < 4; ++j) acc[i][j] += a[i] * bb[j];
    }
    __syncthreads();
  }
  #pragma unroll
  for (int i = 0; i < 4; ++i) {
    int m = m0 + ty * 4 + i;
    #pragma unroll
    for (int j = 0; j < 4; ++j) {
      int n = n0 + tx * 4 + j;
      if (n < N) C[(size_t)m * N + n] = acc[i][j] + bias[n];
    }
  }
}

// ---------------- LayerNorm (+optional residual, +optional bf16 copy) ------
__global__ __launch_bounds__(128) void ln_k(
    const float* __restrict__ A, const float* __restrict__ Bres,
    const float* __restrict__ g, const float* __restrict__ be,
    float* __restrict__ O, ushort_t* __restrict__ Ob) {
  int r = blockIdx.x, t = threadIdx.x;
  __shared__ float lds[2];
  float4 v = ((const float4*)(A + (size_t)r * DM))[t];
  if (Bres) {
    float4 u = ((const float4*)(Bres + (size_t)r * DM))[t];
    v.x += u.x; v.y += u.y; v.z += u.z; v.w += u.w;
  }
  float s = wave_sum64(v.x + v.y + v.z + v.w);
  int w = t >> 6;
  if ((t & 63) == 0) lds[w] = s;
  __syncthreads();
  float mu = (lds[0] + lds[1]) * (1.0f / 512.0f);
  __syncthreads();
  float dx = v.x - mu, dy = v.y - mu, dz = v.z - mu, dw = v.w - mu;
  float sq = wave_sum64(dx * dx + dy * dy + dz * dz + dw * dw);
  if ((t & 63) == 0) lds[w] = sq;
  __syncthreads();
  float var = (lds[0] + lds[1]) * (1.0f / 512.0f);
  float inv = 1.0f / sqrtf(var + 1e-5f);
  float4 gv = ((const float4*)g)[t];
  float4 bv = ((const float4*)be)[t];
  float4 o;
  o.x = dx * inv * gv.x + bv.x;
  o.y = dy * inv * gv.y + bv.y;
  o.z = dz * inv * gv.z + bv.z;
  o.w = dw * inv * gv.w + bv.w;
  ((float4*)(O + (size_t)r * DM))[t] = o;
  if (Ob) {
    ushort4 ob;
    ob.x = f2b(o.x); ob.y = f2b(o.y); ob.z = f2b(o.z); ob.w = f2b(o.w);
    ((ushort4*)(Ob + (size_t)r * DM))[t] = ob;
  }
}

// ---------------- M[b,h,l] = max_u(q.k_idx) - sum_u(q.k_idx)/Lx ------------
template <int UU>
__global__ __launch_bounds__(256) void qk_m_k(
    const float* __restrict__ Q, const float* __restrict__ K,
    const int* __restrict__ idx, float* __restrict__ Mout, int Lx) {
  int item = (blockIdx.x << 2) | (threadIdx.x >> 6);
  int lane = threadIdx.x & 63;
  int l = item % Lx;
  int bh = item / Lx;
  int h = bh & 7, b = bh >> 3;
  const float* Kbase = K + (size_t)b * Lx * DM + h * HD + lane;
  float qd = Q[((size_t)b * Lx + l) * DM + h * HD + lane];
  float maxv = -INFINITY, sumv = 0.f;
  const int* ip = idx + (size_t)l * UU;
  #pragma unroll
  for (int u0 = 0; u0 < UU; u0 += 8) {
    float p[8];
    #pragma unroll
    for (int j = 0; j < 8; ++j) {
      if (u0 + j < UU) {
        int ki = ip[u0 + j];
        p[j] = Kbase[(size_t)ki * DM];
      } else {
        p[j] = 0.f;
      }
    }
    #pragma unroll
    for (int j = 0; j < 8; ++j)
      if (u0 + j < UU) p[j] *= qd;
    #pragma unroll
    for (int off = 32; off > 0; off >>= 1) {
      #pragma unroll
      for (int j = 0; j < 8; ++j)
        if (u0 + j < UU) p[j] += __shfl_xor(p[j], off, 64);
    }
    #pragma unroll
    for (int j = 0; j < 8; ++j) {
      if (u0 + j < UU) { maxv = fmaxf(maxv, p[j]); sumv += p[j]; }
    }
  }
  if (lane == 0) Mout[item] = maxv - sumv / (float)Lx;
}

// ---------------- top-U indices of M per (b,h) -----------------------------
__global__ __launch_bounds__(256) void topk_k(
    const float* __restrict__ Mbuf, int* __restrict__ Mtop, int Lx, int U) {
  int bh = blockIdx.x;
  const float* m = Mbuf + (size_t)bh * Lx;
  __shared__ float mcopy[2048];
  __shared__ float sv[256];
  __shared__ int si[256];
  int t = threadIdx.x;
  for (int i = t; i < Lx; i += 256) mcopy[i] = m[i];
  __syncthreads();
  for (int u = 0; u < U; ++u) {
    float bv = -INFINITY;
    int bi = 0x7fffffff;
    for (int i = t; i < Lx; i += 256) {
      float v = mcopy[i];
      if (v > bv || (v == bv && i < bi)) { bv = v; bi = i; }
    }
    sv[t] = bv; si[t] = bi;
    __syncthreads();
    for (int s = 128; s > 0; s >>= 1) {
      if (t < s) {
        float v2 = sv[t + s]; int i2 = si[t + s];
        if (v2 > sv[t] || (v2 == sv[t] && i2 < si[t])) { sv[t] = v2; si[t] = i2; }
      }
      __syncthreads();
    }
    if (t == 0) {
      Mtop[bh * U + u] = si[0];
      mcopy[si[0]] = -INFINITY;
    }
    __syncthreads();
  }
}

// ---------------- meanV: two-stage coalesced column reduction --------------
__global__ __launch_bounds__(512) void meanv1_k(const float* __restrict__ V,
                                                float* __restrict__ part,
                                                int Lx) {
  int b = blockIdx.x >> 4, chunk = blockIdx.x & 15;
  int rows = Lx >> 4;
  int t = threadIdx.x;  // 512
  const float* vp = V + ((size_t)b * Lx + (size_t)chunk * rows) * DM + t;
  float s = 0.f;
  for (int l = 0; l < rows; ++l) s += vp[(size_t)l * DM];
  part[(size_t)blockIdx.x * DM + t] = s;
}
__global__ __launch_bounds__(512) void meanv2_k(const float* __restrict__ part,
                                                float* __restrict__ mv,
                                                int Lx) {
  int b = blockIdx.x, t = threadIdx.x;
  float s = 0.f;
  #pragma unroll
  for (int c = 0; c < 16; ++c) s += part[(size_t)(b * 16 + c) * DM + t];
  mv[b * DM + t] = s / (float)Lx;
}

__global__ void fillctx_k(ushort_t* __restrict__ ctx,
                          const float* __restrict__ mv, int Lx) {
  size_t i4 = (size_t)blockIdx.x * 256 + threadIdx.x;
  int col4 = (int)(i4 & 127);
  size_t row = i4 >> 7;
  int b = (int)(row / (size_t)Lx);
  const float* m = mv + b * DM + col4 * 4;
  ushort4 o;
  o.x = f2b(m[0]); o.y = f2b(m[1]); o.z = f2b(m[2]); o.w = f2b(m[3]);
  ((ushort4*)ctx)[i4] = o;
}

// ---------------- flash split-K attention for top-U queries ----------------
__global__ __launch_bounds__(512) void attn_flash_k(
    const float* __restrict__ Q, const float* __restrict__ K,
    const float* __restrict__ V, const int* __restrict__ Mtop,
    float* __restrict__ part, int Lx, int U, int nchunk) {
  int blk = blockIdx.x;
  int chunk = blk % nchunk, bh = blk / nchunk;
  int h = bh & 7, b = bh >> 3;
  int rows = Lx / nchunk;
  int ntile = rows >> 6;
  __shared__ float s_q[40 * 64];
  __shared__ float s_k[64 * 65];
  __shared__ float s_v[64 * 65];
  __shared__ float s_p[40 * 64];
  __shared__ float s_m[40], s_l[40], s_a[40];
  int t = threadIdx.x;
  int d = t & 63, wv = t >> 6;

  for (int i = t; i < U * 64; i += 512) {
    int u = i >> 6, dd = i & 63;
    int qi = Mtop[bh * U + u];
    s_q[i] = Q[((size_t)b * Lx + qi) * DM + h * HD + dd] * 0.125f;
  }
  if (t < U) { s_m[t] = -INFINITY; s_l[t] = 0.f; s_a[t] = 0.f; }
  float o[5] = {0.f, 0.f, 0.f, 0.f, 0.f};
  __syncthreads();

  const float* Kp = K + (size_t)b * Lx * DM + h * HD;
  const float* Vp = V + (size_t)b * Lx * DM + h * HD;

  for (int tile = 0; tile < ntile; ++tile) {
    int kr0 = chunk * rows + tile * 64;
    {
      int r = t >> 4, c4 = (t & 15) * 4;
      #pragma unroll
      for (int pass = 0; pass < 2; ++pass) {
        int rr = r + pass * 32;
        float4 kv = *(const float4*)&Kp[(size_t)(kr0 + rr) * DM + c4];
        float4 vv = *(const float4*)&Vp[(size_t)(kr0 + rr) * DM + c4];
        float* kd = &s_k[rr * 65 + c4];
        kd[0] = kv.x; kd[1] = kv.y; kd[2] = kv.z; kd[3] = kv.w;
        float* vd = &s_v[rr * 65 + c4];
        vd[0] = vv.x; vd[1] = vv.y; vd[2] = vv.z; vd[3] = vv.w;
      }
    }
    __syncthreads();
    {
      float kr[64];
      #pragma unroll
      for (int dd = 0; dd < 64; ++dd) kr[dd] = s_k[d * 65 + dd];
      for (int u = wv; u < U; u += 8) {
        float acc = 0.f;
        #pragma unroll
        for (int c = 0; c < 16; ++c) {
          float4 qv = *(const float4*)&s_q[u * 64 + c * 4];
          acc += qv.x * kr[c * 4] + qv.y * kr[c * 4 + 1] +
                 qv.z * kr[c * 4 + 2] + qv.w * kr[c * 4 + 3];
        }
        s_p[u * 64 + d] = acc;
      }
    }
    __syncthreads();
    for (int u = wv; u < U; u += 8) {
      float sv_ = s_p[u * 64 + d];
      float mx = wave_max64(sv_);
      float mold = s_m[u];
      float mnew = fmaxf(mold, mx);
      float e = expf(sv_ - mnew);
      float se = wave_sum64(e);
      s_p[u * 64 + d] = e;
      if (d == 0) {
        float alpha = expf(mold - mnew);
        s_a[u] = alpha;
        s_l[u] = s_l[u] * alpha + se;
        s_m[u] = mnew;
      }
    }
    __syncthreads();
    {
      float vr[64];
      #pragma unroll
      for (int k = 0; k < 64; ++k) vr[k] = s_v[k * 65 + d];
      int i = 0;
      for (int u = wv; u < U; u += 8, ++i) {
        float acc = 0.f;
        #pragma unroll
        for (int c = 0; c < 16; ++c) {
          float4 pv = *(const float4*)&s_p[u * 64 + c * 4];
          acc += pv.x * vr[c * 4] + pv.y * vr[c * 4 + 1] +
                 pv.z * vr[c * 4 + 2] + pv.w * vr[c * 4 + 3];
        }
        o[i] = o[i] * s_a[u] + acc;
      }
    }
    __syncthreads();
  }
  {
    int i = 0;
    for (int u = wv; u < U; u += 8, ++i) {
      float* pp = part + ((size_t)(bh * nchunk + chunk) * U + u) * 66;
      pp[d] = o[i];
      if (d == 0) { pp[64] = s_m[u]; pp[65] = s_l[u]; }
    }
  }
}

__global__ __launch_bounds__(64) void attn_merge_k(
    const float* __restrict__ part, const int* __restrict__ Mtop,
    ushort_t* __restrict__ ctx, int Lx, int U, int nchunk) {
  int bu = blockIdx.x;
  int u = bu % U, bh = bu / U;
  int h = bh & 7, b = bh >> 3;
  int d = threadIdx.x;  // 64
  float M = -INFINITY;
  for (int c = 0; c < nchunk; ++c)
    M = fmaxf(M, part[((size_t)(bh * nchunk + c) * U + u) * 66 + 64]);
  float L = 0.f, O = 0.f;
  for (int c = 0; c < nchunk; ++c) {
    const float* pp = part + ((size_t)(bh * nchunk + c) * U + u) * 66;
    float w = expf(pp[64] - M);
    L += pp[65] * w;
    O += pp[d] * w;
  }
  int qi = Mtop[bh * U + u];
  ctx[((size_t)b * Lx + qi) * DM + h * HD + d] = f2b(O / L);
}

// ---------------- distil im2col (circular, k=3) -> bf16, [t][c] layout -----
__global__ void im2col_k(const float* __restrict__ X,
                         ushort_t* __restrict__ A2) {
  int gid = blockIdx.x * 256 + threadIdx.x;  // 8192*3*128 ushort4 units
  int i4 = gid & 127;
  int rt = gid >> 7;
  int t = rt % 3, row = rt / 3;
  int b = row >> 11, l = row & 2047;
  int ls = (l + t - 1) & 2047;
  float4 v = ((const float4*)(X + ((size_t)b * 2048 + ls) * DM))[i4];
  ushort4 o;
  o.x = f2b(v.x); o.y = f2b(v.y); o.z = f2b(v.z); o.w = f2b(v.w);
  ((ushort4*)A2)[(size_t)row * 384 + t * 128 + i4] = o;
}

// ---------------- batch-norm stats: coalesced two-stage --------------------
__global__ __launch_bounds__(256) void bn1_k(const float* __restrict__ Y,
                                             float* __restrict__ ps,
                                             float* __restrict__ pq) {
  int blk = blockIdx.x;
  int t = threadIdx.x;
  float s0 = 0, q0 = 0, s1 = 0, q1 = 0;
  const float* base = Y + (size_t)blk * 256 * DM;
  for (int r = 0; r < 256; ++r) {
    float a = base[(size_t)r * DM + t];
    float b = base[(size_t)r * DM + t + 256];
    s0 += a; q0 += a * a; s1 += b; q1 += b * b;
  }
  ps[blk * DM + t] = s0; ps[blk * DM + t + 256] = s1;
  pq[blk * DM + t] = q0; pq[blk * DM + t + 256] = q1;
}
__global__ __launch_bounds__(512) void bn2_k(const float* __restrict__ ps,
                                             const float* __restrict__ pq,
                                             float* __restrict__ mu,
                                             float* __restrict__ var) {
  int t = threadIdx.x;
  float s = 0, q = 0;
  #pragma unroll
  for (int c = 0; c < 32; ++c) { s += ps[c * DM + t]; q += pq[c * DM + t]; }
  float m = s * (1.0f / 8192.f);
  mu[t] = m;
  var[t] = q * (1.0f / 8192.f) - m * m;
}

__global__ void bn_elu_k(const float* __restrict__ Y,
                         const float* __restrict__ mu,
                         const float* __restrict__ var,
                         const float* __restrict__ g,
                         const float* __restrict__ be, float* __restrict__ O) {
  size_t i = (size_t)blockIdx.x * 256 + threadIdx.x;
  int c = (int)(i & 511);
  float v = (Y[i] - mu[c]) / sqrtf(var[c] + 1e-5f) * g[c] + be[c];
  O[i] = v > 0.f ? v : expm1f(v);
}

__global__ void maxpool_k(const float* __restrict__ Y, float* __restrict__ O,
                          ushort_t* __restrict__ Ob) {
  size_t i = (size_t)blockIdx.x * 256 + threadIdx.x;  // 4*1024*512
  int c = (int)(i & 511);
  size_t row = i >> 9;
  int lo = (int)(row & 1023);
  int b = (int)(row >> 10);
  int l0 = 2 * lo - 1;
  float m = -INFINITY;
  #pragma unroll
  for (int tt = 0; tt < 3; ++tt) {
    int l = l0 + tt;
    if (l >= 0 && l < 2048) m = fmaxf(m, Y[((size_t)b * 2048 + l) * DM + c]);
  }
  O[i] = m;
  Ob[i] = f2b(m);
}

// ---------------------------------------------------------------------------
extern "C" void kernel_launch(void* const* d_in, const int* in_sizes, int n_in,
                              void* d_out, int out_size, void* d_ws,
                              size_t ws_size, hipStream_t stream) {
  (void)in_sizes; (void)n_in; (void)out_size; (void)ws_size;
  const float* x_enc  = (const float*)d_in[0];
  const float* tok_w  = (const float*)d_in[1];
  const float* Wq     = (const float*)d_in[2];
  const float* bq     = (const float*)d_in[3];
  const float* Wk     = (const float*)d_in[4];
  const float* bk     = (const float*)d_in[5];
  const float* Wv     = (const float*)d_in[6];
  const float* bv     = (const float*)d_in[7];
  const float* Wo     = (const float*)d_in[8];
  const float* bo     = (const float*)d_in[9];
  const float* W1     = (const float*)d_in[10];
  const float* b1     = (const float*)d_in[11];
  const float* W2     = (const float*)d_in[12];
  const float* b2     = (const float*)d_in[13];
  const float* ln1_g  = (const float*)d_in[14];
  const float* ln1_b  = (const float*)d_in[15];
  const float* ln2_g  = (const float*)d_in[16];
  const float* ln2_b  = (const float*)d_in[17];
  const float* conv_w = (const float*)d_in[18];
  const float* conv_b = (const float*)d_in[19];
  const float* bn_g   = (const float*)d_in[20];
  const float* bn_b   = (const float*)d_in[21];
  const float* normf_g = (const float*)d_in[22];
  const float* normf_b = (const float*)d_in[23];
  const float* proj_w = (const float*)d_in[24];
  const float* proj_b = (const float*)d_in[25];
  float* out = (float*)d_out;
  float* ws = (float*)d_ws;

  // ---- fp32 workspace layout (float offsets) ----
  float* X    = ws;                    // 4,194,304
  float* Qb   = ws + 4194304;          // 4,194,304
  float* Kb   = ws + 8388608;          // 4,194,304
  float* Vb   = ws + 12582912;         // 4,194,304
  ushort_t* CTXb = (ushort_t*)(ws + 16777216);  // bf16 ctx
  float* Y2   = ws + 20971520;         // 4,194,304 (attn partials / conv out)
  float* Mb   = ws + 25165824;         // 65,536
  float* MV   = ws + 25231360;         // 2,048
  float* MVP  = ws + 25233408;         // 32,768
  float* BNps = ws + 25266176;         // 16,384
  float* BNpq = ws + 25282560;         // 16,384
  float* BNmu = ws + 25298944;         // 512
  float* BNvr = ws + 25299456;         // 512
  float* ZB   = ws + 25299968;         // 512 (zero bias)
  int*   IDX  = (int*)(ws + 25300480); // 81,920
  int*   MT   = (int*)(ws + 25382400); // 1,280
  // ---- bf16 workspace ----
  ushort_t* U0  = (ushort_t*)(ws + 25383680);
  ushort_t* Xb  = U0;                  // 4,194,304
  ushort_t* Hb  = U0 + 4194304;        // 16,777,216
  ushort_t* Wqb = U0 + 20971520;
  ushort_t* Wkb = U0 + 21495808;
  ushort_t* Wvb = U0 + 22020096;
  ushort_t* Wob = U0 + 22544384;
  ushort_t* W1b = U0 + 23068672;
  ushort_t* W2b = U0 + 25165824;
  ushort_t* Cwb = U0 + 27262976;       // 786,432 (transposed [d][t][i])
  ushort_t* Twb = U0 + 28049408;       // 49,152 (tok_w bf16)
  ushort_t* Atok = U0 + 28098560;      // 786,432 (token im2col)
  float* PEf = ws + 39826432;          // 1,048,576 (PE table)

  castb_k<<<512, 256, 0, stream>>>(Wq, Wqb, 131072);
  castb_k<<<512, 256, 0, stream>>>(Wk, Wkb, 131072);
  castb_k<<<512, 256, 0, stream>>>(Wv, Wvb, 131072);
  castb_k<<<512, 256, 0, stream>>>(Wo, Wob, 131072);
  castb_k<<<2048, 256, 0, stream>>>(W1, W1b, 524288);
  castb_k<<<2048, 256, 0, stream>>>(W2, W2b, 524288);
  castw_conv_k<<<3072, 256, 0, stream>>>(conv_w, Cwb);
  castb_k<<<48, 256, 0, stream>>>(tok_w, Twb, 12288);
  zerofill_k<<<2, 256, 0, stream>>>(ZB, 512);

  // token embedding = im2col + GEMM(+PE)
  pe_k<<<4096, 256, 0, stream>>>(PEf);
  im2col_tok_k<<<3072, 256, 0, stream>>>(x_enc, Atok);
  mgemm_k<0, 2, 1><<<dim3(4, 64), 256, 0, stream>>>(
      Atok, Twb, ZB, X, Xb, PEf, 8192, DM, 96);

  for (int layer = 0; layer < 2; ++layer) {
    const int Lx = (layer == 0) ? 2048 : 1024;
    const int U  = (layer == 0) ? 40 : 35;
    const int M  = NB * Lx;
    const int NCH = 8;

    uint32_t kl0, kl1, s0, s1;
    threefry2x32(0u, 42u, 0u, (uint32_t)layer, &kl0, &kl1);
    threefry2x32(kl0, kl1, 0u, 1u, &s0, &s1);
    int nidx = Lx * U;
    gen_idx_k<<<(nidx + 255) / 256, 256, 0, stream>>>(IDX, nidx, Lx - 1, s0, s1);

    // QKV (bf16 MFMA)
    mgemm_k<0, 0, 0><<<dim3(4, M / 128), 256, 0, stream>>>(
        Xb, Wqb + (size_t)layer * 262144, bq + layer * DM, Qb, nullptr, nullptr,
        M, DM, DM);
    mgemm_k<0, 0, 0><<<dim3(4, M / 128), 256, 0, stream>>>(
        Xb, Wkb + (size_t)layer * 262144, bk + layer * DM, Kb, nullptr, nullptr,
        M, DM, DM);
    mgemm_k<0, 0, 0><<<dim3(4, M / 128), 256, 0, stream>>>(
        Xb, Wvb + (size_t)layer * 262144, bv + layer * DM, Vb, nullptr, nullptr,
        M, DM, DM);

    // ProbSparse attention
    if (layer == 0)
      qk_m_k<40><<<NB * NH * Lx / 4, 256, 0, stream>>>(Qb, Kb, IDX, Mb, Lx);
    else
      qk_m_k<35><<<NB * NH * Lx / 4, 256, 0, stream>>>(Qb, Kb, IDX, Mb, Lx);
    topk_k<<<NB * NH, 256, 0, stream>>>(Mb, MT, Lx, U);
    meanv1_k<<<NB * 16, 512, 0, stream>>>(Vb, MVP, Lx);
    meanv2_k<<<NB, 512, 0, stream>>>(MVP, MV, Lx);
    fillctx_k<<<(M * DM / 4) / 256, 256, 0, stream>>>(CTXb, MV, Lx);
    attn_flash_k<<<NB * NH * NCH, 512, 0, stream>>>(Qb, Kb, Vb, MT, Y2, Lx, U, NCH);
    attn_merge_k<<<NB * NH * U, 64, 0, stream>>>(Y2, MT, CTXb, Lx, U, NCH);

    // output projection + residual + LN1 (emits bf16 for FFN1)
    mgemm_k<0, 0, 0><<<dim3(4, M / 128), 256, 0, stream>>>(
        CTXb, Wob + (size_t)layer * 262144, bo + layer * DM, Y2, nullptr,
        nullptr, M, DM, DM);
    ln_k<<<M, 128, 0, stream>>>(X, Y2, ln1_g + layer * DM, ln1_b + layer * DM, X, Xb);

    // FFN (GELU fused; hidden kept in bf16); LN2 emits bf16
    mgemm_k<1, 1, 0><<<dim3(16, M / 128), 256, 0, stream>>>(
        Xb, W1b + (size_t)layer * 1048576, b1 + layer * 2048, nullptr, Hb,
        nullptr, M, 2048, DM);
    mgemm_k<0, 0, 0><<<dim3(4, M / 128), 256, 0, stream>>>(
        Hb, W2b + (size_t)layer * 1048576, b2 + layer * DM, Y2, nullptr,
        nullptr, M, DM, 2048);
    ln_k<<<M, 128, 0, stream>>>(X, Y2, ln2_g + layer * DM, ln2_b + layer * DM, X, Xb);

    if (layer == 0) {
      im2col_k<<<12288, 256, 0, stream>>>(X, Hb);
      mgemm_k<0, 0, 0><<<dim3(4, 64), 256, 0, stream>>>(
          Hb, Cwb, conv_b, Y2, nullptr, nullptr, 8192, DM, 1536);
      bn1_k<<<32, 256, 0, stream>>>(Y2, BNps, BNpq);
      bn2_k<<<1, 512, 0, stream>>>(BNps, BNpq, BNmu, BNvr);
      bn_elu_k<<<(8192 * 512) / 256, 256, 0, stream>>>(Y2, BNmu, BNvr, bn_g,
                                                       bn_b, Qb);
      maxpool_k<<<(NB * 1024 * 512) / 256, 256, 0, stream>>>(Qb, X, Xb);
    }
  }

  // final LN + projection (N=32, fp32)
  ln_k<<<NB * 1024, 128, 0, stream>>>(X, nullptr, normf_g, normf_b, Qb, nullptr);
  gemm_k<<<dim3(1, 4096 / 64), 256, 0, stream>>>(Qb, proj_w, proj_b, out,
                                                 4096, 32, DM);
}

// Round 6
// 1071.899 us; speedup vs baseline: 3.7923x; 1.0731x over previous
//
#include <hip/hip_runtime.h>
#include <cstdint>
#include <cmath>

// ---------------------------------------------------------------------------
// Informer encoder forward (B=4, L=2048, ENC_IN=32, D_MODEL=512, D_FF=2048,
// E_LAYERS=2, H=8, FACTOR=5).
// Round 6: l-major qk_m ordering (+ILP-20) for K-line sharing across heads;
// fused QKV GEMM (N=1536, 3 blocks/CU); fused bn_elu+maxpool.
// ---------------------------------------------------------------------------

#define NB 4
#define DM 512
#define NH 8
#define HD 64
#define QS 1536  // QKV row stride

typedef unsigned short ushort_t;
typedef __bf16 bf16x8 __attribute__((ext_vector_type(8)));
typedef float floatx4 __attribute__((ext_vector_type(4)));

__device__ inline ushort_t f2b(float f) {
  uint32_t u = __float_as_uint(f);
  uint32_t r = (u + 0x7fffu + ((u >> 16) & 1u)) >> 16;
  return (ushort_t)r;
}

__global__ void castb_k(const float* __restrict__ in,
                        ushort_t* __restrict__ out, int n4) {
  int i = blockIdx.x * 256 + threadIdx.x;
  if (i < n4) {
    float4 v = ((const float4*)in)[i];
    ushort4 o;
    o.x = f2b(v.x); o.y = f2b(v.y); o.z = f2b(v.z); o.w = f2b(v.w);
    ((ushort4*)out)[i] = o;
  }
}

__global__ void zerofill_k(float* __restrict__ p, int n) {
  int i = blockIdx.x * 256 + threadIdx.x;
  if (i < n) p[i] = 0.f;
}

// concat QKV bias: [layer][1536]  (0-511 q, 512-1023 k, 1024-1535 v)
__global__ void bqkv_k(const float* __restrict__ bq,
                       const float* __restrict__ bk,
                       const float* __restrict__ bv,
                       float* __restrict__ o) {
  int gid = blockIdx.x * 256 + threadIdx.x;  // 3072
  if (gid >= 3072) return;
  int layer = gid / 1536, r = gid - layer * 1536;
  float v;
  if (r < 512) v = bq[layer * 512 + r];
  else if (r < 1024) v = bk[layer * 512 + r - 512];
  else v = bv[layer * 512 + r - 1024];
  o[gid] = v;
}

// conv weight: (D, I, 3) -> bf16 (D, 3, I) so im2col is coalesced
__global__ void castw_conv_k(const float* __restrict__ in,
                             ushort_t* __restrict__ out) {
  int gid = blockIdx.x * 256 + threadIdx.x;  // 512*1536
  int d = gid / 1536, r = gid - d * 1536;
  int t = r >> 9, i = r & 511;
  out[gid] = f2b(in[d * 1536 + i * 3 + t]);
}

__host__ __device__ inline void threefry2x32(uint32_t k0, uint32_t k1,
                                             uint32_t c0, uint32_t c1,
                                             uint32_t* o0, uint32_t* o1) {
  uint32_t ks0 = k0, ks1 = k1, ks2 = k0 ^ k1 ^ 0x1BD11BDAu;
  uint32_t x0 = c0 + ks0;
  uint32_t x1 = c1 + ks1;
  const uint32_t rotA[4] = {13u, 15u, 26u, 6u};
  const uint32_t rotB[4] = {17u, 29u, 16u, 24u};
  uint32_t ks[3] = {ks0, ks1, ks2};
  #pragma unroll
  for (int i = 0; i < 5; ++i) {
    const uint32_t* r = (i & 1) ? rotB : rotA;
    #pragma unroll
    for (int j = 0; j < 4; ++j) {
      x0 += x1;
      x1 = (x1 << r[j]) | (x1 >> (32u - r[j]));
      x1 ^= x0;
    }
    x0 += ks[(i + 1) % 3];
    x1 += ks[(i + 2) % 3] + (uint32_t)(i + 1);
  }
  *o0 = x0; *o1 = x1;
}

__global__ void gen_idx_k(int* __restrict__ idx, int n, int mask,
                          uint32_t k0, uint32_t k1) {
  int i = blockIdx.x * 256 + threadIdx.x;
  if (i < n) {
    uint32_t o0, o1;
    threefry2x32(k0, k1, 0u, (uint32_t)i, &o0, &o1);
    idx[i] = (int)((o0 ^ o1) & (uint32_t)mask);
  }
}

__device__ inline float wave_sum64(float v) {
  #pragma unroll
  for (int o = 32; o > 0; o >>= 1) v += __shfl_xor(v, o, 64);
  return v;
}
__device__ inline float wave_max64(float v) {
  #pragma unroll
  for (int o = 32; o > 0; o >>= 1) v = fmaxf(v, __shfl_xor(v, o, 64));
  return v;
}

// ---------------- positional-encoding table (2048 x 512) -------------------
__global__ void pe_k(float* __restrict__ pe) {
  int i = blockIdx.x * 256 + threadIdx.x;  // 1,048,576
  int d = i & 511, l = i >> 9;
  int j2 = d & ~1;
  float div = expf((float)j2 * -1.7988946039e-2f);  // -ln(10000)/512
  float ang = (float)l * div;
  pe[i] = (d & 1) ? cosf(ang) : sinf(ang);
}

// ---------------- im2col for token conv: (B*L, 96) bf16 --------------------
__global__ void im2col_tok_k(const float* __restrict__ xe,
                             ushort_t* __restrict__ A) {
  int gid = blockIdx.x * 256 + threadIdx.x;  // 8192*96
  int col = gid % 96;
  int row = gid / 96;
  int c = col / 3, t = col - c * 3;
  int b = row >> 11, l = row & 2047;
  int ls = (l + t - 1) & 2047;
  A[gid] = f2b(xe[((size_t)b * 2048 + ls) * 32 + c]);
}

// ---------------- bf16 MFMA GEMM: C = act(A @ W^T + bias [+ pe]) -----------
__device__ inline void gload16(const ushort_t* g, ushort_t* l) {
  __builtin_amdgcn_global_load_lds(
      (const __attribute__((address_space(1))) unsigned int*)(const void*)g,
      (__attribute__((address_space(3))) unsigned int*)(void*)l, 16, 0, 0);
}

template <int GELU, int OMODE, int ADDPE>  // OMODE: 0 f32, 1 bf16, 2 both
__global__ __launch_bounds__(256) void mgemm_k(
    const ushort_t* __restrict__ A, const ushort_t* __restrict__ W,
    const float* __restrict__ bias, float* __restrict__ Cf,
    ushort_t* __restrict__ Cb, const float* __restrict__ pe,
    int M, int ldc, int K) {
  __shared__ ushort_t As[128 * 32];
  __shared__ ushort_t Bs[128 * 32];
  int m0 = blockIdx.y * 128, n0 = blockIdx.x * 128;
  int t = threadIdx.x;
  int lane = t & 63, wv = t >> 6;
  int sr = lane >> 2, sc = (lane & 3) * 8;
  int ra0 = wv * 32 + sr, ra1 = ra0 + 16;
  const ushort_t* gA0 = A + (size_t)(m0 + ra0) * K + sc;
  const ushort_t* gA1 = A + (size_t)(m0 + ra1) * K + sc;
  const ushort_t* gB0 = W + (size_t)(n0 + ra0) * K + sc;
  const ushort_t* gB1 = W + (size_t)(n0 + ra1) * K + sc;
  ushort_t* lA0 = As + wv * 1024;
  ushort_t* lA1 = lA0 + 512;
  ushort_t* lB0 = Bs + wv * 1024;
  ushort_t* lB1 = lB0 + 512;

  int quad = lane >> 4, lr = lane & 15;
  int wm = wv >> 1, wn = wv & 1;

  floatx4 acc[4][4] = {};
  for (int ks = 0; ks < K; ks += 32) {
    gload16(gA0, lA0);
    gload16(gA1, lA1);
    gload16(gB0, lB0);
    gload16(gB1, lB1);
    gA0 += 32; gA1 += 32; gB0 += 32; gB1 += 32;
    __syncthreads();
    bf16x8 av[4], bv[4];
    #pragma unroll
    for (int mt = 0; mt < 4; ++mt)
      av[mt] = *(const bf16x8*)&As[(wm * 64 + mt * 16 + lr) * 32 + quad * 8];
    #pragma unroll
    for (int nt = 0; nt < 4; ++nt)
      bv[nt] = *(const bf16x8*)&Bs[(wn * 64 + nt * 16 + lr) * 32 + quad * 8];
    #pragma unroll
    for (int mt = 0; mt < 4; ++mt)
      #pragma unroll
      for (int nt = 0; nt < 4; ++nt)
        acc[mt][nt] = __builtin_amdgcn_mfma_f32_16x16x32_bf16(
            av[mt], bv[nt], acc[mt][nt], 0, 0, 0);
    __syncthreads();
  }
  #pragma unroll
  for (int nt = 0; nt < 4; ++nt) {
    int col = n0 + wn * 64 + nt * 16 + lr;
    float bsv = bias[col];
    #pragma unroll
    for (int mt = 0; mt < 4; ++mt) {
      int row0 = m0 + wm * 64 + mt * 16 + quad * 4;
      #pragma unroll
      for (int r = 0; r < 4; ++r) {
        int row = row0 + r;
        float v = acc[mt][nt][r] + bsv;
        if (ADDPE) v += pe[(size_t)(row & 2047) * ldc + col];
        if (GELU) v = 0.5f * v * (1.0f + erff(v * 0.70710678118654752f));
        if (OMODE == 0 || OMODE == 2) Cf[(size_t)row * ldc + col] = v;
        if (OMODE == 1 || OMODE == 2) Cb[(size_t)row * ldc + col] = f2b(v);
      }
    }
  }
}

// ---------------- fp32 fallback GEMM (final projection, N=32) --------------
__global__ __launch_bounds__(256) void gemm_k(
    const float* __restrict__ A, const float* __restrict__ W,
    const float* __restrict__ bias, float* __restrict__ C,
    int M, int N, int K) {
  __shared__ float As2[16][64 + 4];
  __shared__ float Ws2[16][64 + 4];
  int m0 = blockIdx.y * 64, n0 = blockIdx.x * 64;
  int t = threadIdx.x;
  int tx = t & 15, ty = t >> 4;
  float acc[4][4] = {};
  for (int k0 = 0; k0 < K; k0 += 16) {
    #pragma unroll
    for (int i = 0; i < 4; ++i) {
      int li = t + i * 256;
      int m = li >> 4, kk = li & 15;
      As2[kk][m] = A[(size_t)(m0 + m) * K + k0 + kk];
    }
    #pragma unroll
    for (int i = 0; i < 4; ++i) {
      int li = t + i * 256;
      int n = li >> 4, kk = li & 15;
      int gn = n0 + n;
      Ws2[kk][n] = (gn < N) ? W[(size_t)gn * K + k0 + kk] : 0.0f;
    }
    __syncthreads();
    #pragma unroll
    for (int kk = 0; kk < 16; ++kk) {
      float4 avv = *(const float4*)&As2[kk][ty * 4];
      float4 bvv = *(const float4*)&Ws2[kk][tx * 4];
      float a[4] = {avv.x, avv.y, avv.z, avv.w};
      float bb[4] = {bvv.x, bvv.y, bvv.z, bvv.w};
      #pragma unroll
      for (int i = 0; i < 4; ++i)
        #pragma unroll
        for (int j = 0; j < 4; ++j) acc[i][j] += a[i] * bb[j];
    }
    __syncthreads();
  }
  #pragma unroll
  for (int i = 0; i < 4; ++i) {
    int m = m0 + ty * 4 + i;
    #pragma unroll
    for (int j = 0; j < 4; ++j) {
      int n = n0 + tx * 4 + j;
      if (n < N) C[(size_t)m * N + n] = acc[i][j] + bias[n];
    }
  }
}

// ---------------- LayerNorm (+optional residual, +optional bf16 copy) ------
__global__ __launch_bounds__(128) void ln_k(
    const float* __restrict__ A, const float* __restrict__ Bres,
    const float* __restrict__ g, const float* __restrict__ be,
    float* __restrict__ O, ushort_t* __restrict__ Ob) {
  int r = blockIdx.x, t = threadIdx.x;
  __shared__ float lds[2];
  float4 v = ((const float4*)(A + (size_t)r * DM))[t];
  if (Bres) {
    float4 u = ((const float4*)(Bres + (size_t)r * DM))[t];
    v.x += u.x; v.y += u.y; v.z += u.z; v.w += u.w;
  }
  float s = wave_sum64(v.x + v.y + v.z + v.w);
  int w = t >> 6;
  if ((t & 63) == 0) lds[w] = s;
  __syncthreads();
  float mu = (lds[0] + lds[1]) * (1.0f / 512.0f);
  __syncthreads();
  float dx = v.x - mu, dy = v.y - mu, dz = v.z - mu, dw = v.w - mu;
  float sq = wave_sum64(dx * dx + dy * dy + dz * dz + dw * dw);
  if ((t & 63) == 0) lds[w] = sq;
  __syncthreads();
  float var = (lds[0] + lds[1]) * (1.0f / 512.0f);
  float inv = 1.0f / sqrtf(var + 1e-5f);
  float4 gv = ((const float4*)g)[t];
  float4 bv = ((const float4*)be)[t];
  float4 o;
  o.x = dx * inv * gv.x + bv.x;
  o.y = dy * inv * gv.y + bv.y;
  o.z = dz * inv * gv.z + bv.z;
  o.w = dw * inv * gv.w + bv.w;
  ((float4*)(O + (size_t)r * DM))[t] = o;
  if (Ob) {
    ushort4 ob;
    ob.x = f2b(o.x); ob.y = f2b(o.y); ob.z = f2b(o.z); ob.w = f2b(o.w);
    ((ushort4*)(Ob + (size_t)r * DM))[t] = ob;
  }
}

// ---------------- M[b,h,l] from QKV (stride 1536), l-major, ILP-20 ---------
template <int UU>
__global__ __launch_bounds__(256, 2) void qk_m_k(
    const float* __restrict__ QKV, const int* __restrict__ idx,
    float* __restrict__ Mout, int Lx) {
  int item = (blockIdx.x << 2) | (threadIdx.x >> 6);
  int lane = threadIdx.x & 63;
  int l = item >> 5;            // l-major: all 32 bh of one l adjacent
  int bh = item & 31;
  int b = bh >> 3, h = bh & 7;
  const float* Kbase = QKV + (size_t)b * Lx * QS + 512 + h * HD + lane;
  float qd = QKV[((size_t)b * Lx + l) * QS + h * HD + lane];
  float maxv = -INFINITY, sumv = 0.f;
  const int* ip = idx + (size_t)l * UU;
  #pragma unroll
  for (int u0 = 0; u0 < UU; u0 += 20) {
    float p[20];
    #pragma unroll
    for (int j = 0; j < 20; ++j) {
      if (u0 + j < UU) {
        int ki = ip[u0 + j];
        p[j] = Kbase[(size_t)ki * QS];
      } else p[j] = 0.f;
    }
    #pragma unroll
    for (int j = 0; j < 20; ++j)
      if (u0 + j < UU) p[j] *= qd;
    #pragma unroll
    for (int off = 32; off > 0; off >>= 1) {
      #pragma unroll
      for (int j = 0; j < 20; ++j)
        if (u0 + j < UU) p[j] += __shfl_xor(p[j], off, 64);
    }
    #pragma unroll
    for (int j = 0; j < 20; ++j)
      if (u0 + j < UU) { maxv = fmaxf(maxv, p[j]); sumv += p[j]; }
  }
  if (lane == 0) Mout[(size_t)bh * Lx + l] = maxv - sumv / (float)Lx;
}

// ---------------- top-U indices of M per (b,h) -----------------------------
__global__ __launch_bounds__(256) void topk_k(
    const float* __restrict__ Mbuf, int* __restrict__ Mtop, int Lx, int U) {
  int bh = blockIdx.x;
  const float* m = Mbuf + (size_t)bh * Lx;
  __shared__ float mcopy[2048];
  __shared__ float sv[256];
  __shared__ int si[256];
  int t = threadIdx.x;
  for (int i = t; i < Lx; i += 256) mcopy[i] = m[i];
  __syncthreads();
  for (int u = 0; u < U; ++u) {
    float bv = -INFINITY;
    int bi = 0x7fffffff;
    for (int i = t; i < Lx; i += 256) {
      float v = mcopy[i];
      if (v > bv || (v == bv && i < bi)) { bv = v; bi = i; }
    }
    sv[t] = bv; si[t] = bi;
    __syncthreads();
    for (int s = 128; s > 0; s >>= 1) {
      if (t < s) {
        float v2 = sv[t + s]; int i2 = si[t + s];
        if (v2 > sv[t] || (v2 == sv[t] && i2 < si[t])) { sv[t] = v2; si[t] = i2; }
      }
      __syncthreads();
    }
    if (t == 0) {
      Mtop[bh * U + u] = si[0];
      mcopy[si[0]] = -INFINITY;
    }
    __syncthreads();
  }
}

// ---------------- meanV from QKV (V at +1024, stride 1536) -----------------
__global__ __launch_bounds__(512) void meanv1_k(const float* __restrict__ QKV,
                                                float* __restrict__ part,
                                                int Lx) {
  int b = blockIdx.x >> 4, chunk = blockIdx.x & 15;
  int rows = Lx >> 4;
  int t = threadIdx.x;  // 512
  const float* vp = QKV + ((size_t)b * Lx + (size_t)chunk * rows) * QS + 1024 + t;
  float s = 0.f;
  for (int l = 0; l < rows; ++l) s += vp[(size_t)l * QS];
  part[(size_t)blockIdx.x * DM + t] = s;
}
__global__ __launch_bounds__(512) void meanv2_k(const float* __restrict__ part,
                                                float* __restrict__ mv,
                                                int Lx) {
  int b = blockIdx.x, t = threadIdx.x;
  float s = 0.f;
  #pragma unroll
  for (int c = 0; c < 16; ++c) s += part[(size_t)(b * 16 + c) * DM + t];
  mv[b * DM + t] = s / (float)Lx;
}

__global__ void fillctx_k(ushort_t* __restrict__ ctx,
                          const float* __restrict__ mv, int Lx) {
  size_t i4 = (size_t)blockIdx.x * 256 + threadIdx.x;
  int col4 = (int)(i4 & 127);
  size_t row = i4 >> 7;
  int b = (int)(row / (size_t)Lx);
  const float* m = mv + b * DM + col4 * 4;
  ushort4 o;
  o.x = f2b(m[0]); o.y = f2b(m[1]); o.z = f2b(m[2]); o.w = f2b(m[3]);
  ((ushort4*)ctx)[i4] = o;
}

// ---------------- flash split-K attention (QKV stride 1536) ----------------
__global__ __launch_bounds__(512) void attn_flash_k(
    const float* __restrict__ QKV, const int* __restrict__ Mtop,
    float* __restrict__ part, int Lx, int U, int nchunk) {
  int blk = blockIdx.x;
  int chunk = blk % nchunk, bh = blk / nchunk;
  int h = bh & 7, b = bh >> 3;
  int rows = Lx / nchunk;
  int ntile = rows >> 6;
  __shared__ float s_q[40 * 64];
  __shared__ float s_k[64 * 65];
  __shared__ float s_v[64 * 65];
  __shared__ float s_p[40 * 64];
  __shared__ float s_m[40], s_l[40], s_a[40];
  int t = threadIdx.x;
  int d = t & 63, wv = t >> 6;

  for (int i = t; i < U * 64; i += 512) {
    int u = i >> 6, dd = i & 63;
    int qi = Mtop[bh * U + u];
    s_q[i] = QKV[((size_t)b * Lx + qi) * QS + h * HD + dd] * 0.125f;
  }
  if (t < U) { s_m[t] = -INFINITY; s_l[t] = 0.f; s_a[t] = 0.f; }
  float o[5] = {0.f, 0.f, 0.f, 0.f, 0.f};
  __syncthreads();

  const float* Kp = QKV + (size_t)b * Lx * QS + 512 + h * HD;
  const float* Vp = QKV + (size_t)b * Lx * QS + 1024 + h * HD;

  for (int tile = 0; tile < ntile; ++tile) {
    int kr0 = chunk * rows + tile * 64;
    {
      int r = t >> 4, c4 = (t & 15) * 4;
      #pragma unroll
      for (int pass = 0; pass < 2; ++pass) {
        int rr = r + pass * 32;
        float4 kv = *(const float4*)&Kp[(size_t)(kr0 + rr) * QS + c4];
        float4 vv = *(const float4*)&Vp[(size_t)(kr0 + rr) * QS + c4];
        float* kd = &s_k[rr * 65 + c4];
        kd[0] = kv.x; kd[1] = kv.y; kd[2] = kv.z; kd[3] = kv.w;
        float* vd = &s_v[rr * 65 + c4];
        vd[0] = vv.x; vd[1] = vv.y; vd[2] = vv.z; vd[3] = vv.w;
      }
    }
    __syncthreads();
    {
      float kr[64];
      #pragma unroll
      for (int dd = 0; dd < 64; ++dd) kr[dd] = s_k[d * 65 + dd];
      for (int u = wv; u < U; u += 8) {
        float acc = 0.f;
        #pragma unroll
        for (int c = 0; c < 16; ++c) {
          float4 qv = *(const float4*)&s_q[u * 64 + c * 4];
          acc += qv.x * kr[c * 4] + qv.y * kr[c * 4 + 1] +
                 qv.z * kr[c * 4 + 2] + qv.w * kr[c * 4 + 3];
        }
        s_p[u * 64 + d] = acc;
      }
    }
    __syncthreads();
    for (int u = wv; u < U; u += 8) {
      float sv_ = s_p[u * 64 + d];
      float mx = wave_max64(sv_);
      float mold = s_m[u];
      float mnew = fmaxf(mold, mx);
      float e = expf(sv_ - mnew);
      float se = wave_sum64(e);
      s_p[u * 64 + d] = e;
      if (d == 0) {
        float alpha = expf(mold - mnew);
        s_a[u] = alpha;
        s_l[u] = s_l[u] * alpha + se;
        s_m[u] = mnew;
      }
    }
    __syncthreads();
    {
      float vr[64];
      #pragma unroll
      for (int k = 0; k < 64; ++k) vr[k] = s_v[k * 65 + d];
      int i = 0;
      for (int u = wv; u < U; u += 8, ++i) {
        float acc = 0.f;
        #pragma unroll
        for (int c = 0; c < 16; ++c) {
          float4 pv = *(const float4*)&s_p[u * 64 + c * 4];
          acc += pv.x * vr[c * 4] + pv.y * vr[c * 4 + 1] +
                 pv.z * vr[c * 4 + 2] + pv.w * vr[c * 4 + 3];
        }
        o[i] = o[i] * s_a[u] + acc;
      }
    }
    __syncthreads();
  }
  {
    int i = 0;
    for (int u = wv; u < U; u += 8, ++i) {
      float* pp = part + ((size_t)(bh * nchunk + chunk) * U + u) * 66;
      pp[d] = o[i];
      if (d == 0) { pp[64] = s_m[u]; pp[65] = s_l[u]; }
    }
  }
}

__global__ __launch_bounds__(64) void attn_merge_k(
    const float* __restrict__ part, const int* __restrict__ Mtop,
    ushort_t* __restrict__ ctx, int Lx, int U, int nchunk) {
  int bu = blockIdx.x;
  int u = bu % U, bh = bu / U;
  int h = bh & 7, b = bh >> 3;
  int d = threadIdx.x;  // 64
  float M = -INFINITY;
  for (int c = 0; c < nchunk; ++c)
    M = fmaxf(M, part[((size_t)(bh * nchunk + c) * U + u) * 66 + 64]);
  float L = 0.f, O = 0.f;
  for (int c = 0; c < nchunk; ++c) {
    const float* pp = part + ((size_t)(bh * nchunk + c) * U + u) * 66;
    float w = expf(pp[64] - M);
    L += pp[65] * w;
    O += pp[d] * w;
  }
  int qi = Mtop[bh * U + u];
  ctx[((size_t)b * Lx + qi) * DM + h * HD + d] = f2b(O / L);
}

// ---------------- distil im2col (circular, k=3) -> bf16, [t][c] layout -----
__global__ void im2col_k(const float* __restrict__ X,
                         ushort_t* __restrict__ A2) {
  int gid = blockIdx.x * 256 + threadIdx.x;  // 8192*3*128 ushort4 units
  int i4 = gid & 127;
  int rt = gid >> 7;
  int t = rt % 3, row = rt / 3;
  int b = row >> 11, l = row & 2047;
  int ls = (l + t - 1) & 2047;
  float4 v = ((const float4*)(X + ((size_t)b * 2048 + ls) * DM))[i4];
  ushort4 o;
  o.x = f2b(v.x); o.y = f2b(v.y); o.z = f2b(v.z); o.w = f2b(v.w);
  ((ushort4*)A2)[(size_t)row * 384 + t * 128 + i4] = o;
}

// ---------------- batch-norm stats: coalesced two-stage --------------------
__global__ __launch_bounds__(256) void bn1_k(const float* __restrict__ Y,
                                             float* __restrict__ ps,
                                             float* __restrict__ pq) {
  int blk = blockIdx.x;
  int t = threadIdx.x;
  float s0 = 0, q0 = 0, s1 = 0, q1 = 0;
  const float* base = Y + (size_t)blk * 256 * DM;
  for (int r = 0; r < 256; ++r) {
    float a = base[(size_t)r * DM + t];
    float b = base[(size_t)r * DM + t + 256];
    s0 += a; q0 += a * a; s1 += b; q1 += b * b;
  }
  ps[blk * DM + t] = s0; ps[blk * DM + t + 256] = s1;
  pq[blk * DM + t] = q0; pq[blk * DM + t + 256] = q1;
}
__global__ __launch_bounds__(512) void bn2_k(const float* __restrict__ ps,
                                             const float* __restrict__ pq,
                                             float* __restrict__ mu,
                                             float* __restrict__ var) {
  int t = threadIdx.x;
  float s = 0, q = 0;
  #pragma unroll
  for (int c = 0; c < 32; ++c) { s += ps[c * DM + t]; q += pq[c * DM + t]; }
  float m = s * (1.0f / 8192.f);
  mu[t] = m;
  var[t] = q * (1.0f / 8192.f) - m * m;
}

// fused bn+elu+maxpool(k=3,s=2,pad=1): reads conv out, writes X (fp32+bf16)
__global__ void bnpool_k(const float* __restrict__ Y,
                         const float* __restrict__ mu,
                         const float* __restrict__ var,
                         const float* __restrict__ g,
                         const float* __restrict__ be, float* __restrict__ O,
                         ushort_t* __restrict__ Ob) {
  size_t i = (size_t)blockIdx.x * 256 + threadIdx.x;  // 4*1024*512
  int c = (int)(i & 511);
  size_t row = i >> 9;
  int lo = (int)(row & 1023);
  int b = (int)(row >> 10);
  float sc = g[c] / sqrtf(var[c] + 1e-5f);
  float sh = be[c] - mu[c] * sc;
  int l0 = 2 * lo - 1;
  float m = -INFINITY;
  #pragma unroll
  for (int tt = 0; tt < 3; ++tt) {
    int l = l0 + tt;
    if (l >= 0 && l < 2048) {
      float v = Y[((size_t)b * 2048 + l) * DM + c] * sc + sh;
      v = v > 0.f ? v : expm1f(v);
      m = fmaxf(m, v);
    }
  }
  O[i] = m;
  Ob[i] = f2b(m);
}

// ---------------------------------------------------------------------------
extern "C" void kernel_launch(void* const* d_in, const int* in_sizes, int n_in,
                              void* d_out, int out_size, void* d_ws,
                              size_t ws_size, hipStream_t stream) {
  (void)in_sizes; (void)n_in; (void)out_size; (void)ws_size;
  const float* x_enc  = (const float*)d_in[0];
  const float* tok_w  = (const float*)d_in[1];
  const float* Wq     = (const float*)d_in[2];
  const float* bq     = (const float*)d_in[3];
  const float* Wk     = (const float*)d_in[4];
  const float* bk     = (const float*)d_in[5];
  const float* Wv     = (const float*)d_in[6];
  const float* bv     = (const float*)d_in[7];
  const float* Wo     = (const float*)d_in[8];
  const float* bo     = (const float*)d_in[9];
  const float* W1     = (const float*)d_in[10];
  const float* b1     = (const float*)d_in[11];
  const float* W2     = (const float*)d_in[12];
  const float* b2     = (const float*)d_in[13];
  const float* ln1_g  = (const float*)d_in[14];
  const float* ln1_b  = (const float*)d_in[15];
  const float* ln2_g  = (const float*)d_in[16];
  const float* ln2_b  = (const float*)d_in[17];
  const float* conv_w = (const float*)d_in[18];
  const float* conv_b = (const float*)d_in[19];
  const float* bn_g   = (const float*)d_in[20];
  const float* bn_b   = (const float*)d_in[21];
  const float* normf_g = (const float*)d_in[22];
  const float* normf_b = (const float*)d_in[23];
  const float* proj_w = (const float*)d_in[24];
  const float* proj_b = (const float*)d_in[25];
  float* out = (float*)d_out;
  float* ws = (float*)d_ws;

  // ---- fp32 workspace layout (float offsets) ----
  float* X    = ws;                    // 4,194,304
  float* QKV  = ws + 4194304;          // 12,582,912 (8192 x 1536)
  ushort_t* CTXb = (ushort_t*)(ws + 16777216);  // bf16 ctx
  float* Y2   = ws + 20971520;         // 4,194,304 (attn partials / conv out)
  float* Mb   = ws + 25165824;         // 65,536
  float* MV   = ws + 25231360;         // 2,048
  float* MVP  = ws + 25233408;         // 32,768
  float* BNps = ws + 25266176;         // 16,384
  float* BNpq = ws + 25282560;         // 16,384
  float* BNmu = ws + 25298944;         // 512
  float* BNvr = ws + 25299456;         // 512
  float* ZB   = ws + 25299968;         // 512 (zero bias)
  float* BQKV = ws + 25300480;         // 3,072 (concat qkv bias, 2 layers)
  int*   IDX  = (int*)(ws + 25303552); // 81,920
  int*   MT   = (int*)(ws + 25385472); // 1,280
  // ---- bf16 workspace ----
  ushort_t* U0   = (ushort_t*)(ws + 25386752);
  ushort_t* Xb   = U0;                 // 4,194,304
  ushort_t* Hb   = U0 + 4194304;       // 16,777,216
  ushort_t* Wqkvb= U0 + 20971520;      // 1,572,864 (2 layers x 1536 x 512)
  ushort_t* Wob  = U0 + 22544384;      // 524,288
  ushort_t* W1b  = U0 + 23068672;      // 2,097,152
  ushort_t* W2b  = U0 + 25165824;      // 2,097,152
  ushort_t* Cwb  = U0 + 27262976;      // 786,432
  ushort_t* Twb  = U0 + 28049408;      // 49,152
  ushort_t* Atok = U0 + 28098560;      // 786,432
  float* PEf = ws + 39829248;          // 1,048,576 (PE table)

  // weight casts: QKV concat per layer (rows 0-511 Q, 512-1023 K, 1024-1535 V)
  for (int ly = 0; ly < 2; ++ly) {
    castb_k<<<256, 256, 0, stream>>>(Wq + ly * 262144, Wqkvb + ly * 786432, 65536);
    castb_k<<<256, 256, 0, stream>>>(Wk + ly * 262144, Wqkvb + ly * 786432 + 262144, 65536);
    castb_k<<<256, 256, 0, stream>>>(Wv + ly * 262144, Wqkvb + ly * 786432 + 524288, 65536);
  }
  castb_k<<<512, 256, 0, stream>>>(Wo, Wob, 131072);
  castb_k<<<2048, 256, 0, stream>>>(W1, W1b, 524288);
  castb_k<<<2048, 256, 0, stream>>>(W2, W2b, 524288);
  castw_conv_k<<<3072, 256, 0, stream>>>(conv_w, Cwb);
  castb_k<<<48, 256, 0, stream>>>(tok_w, Twb, 12288);
  zerofill_k<<<2, 256, 0, stream>>>(ZB, 512);
  bqkv_k<<<12, 256, 0, stream>>>(bq, bk, bv, BQKV);

  // token embedding = im2col + GEMM(+PE)
  pe_k<<<4096, 256, 0, stream>>>(PEf);
  im2col_tok_k<<<3072, 256, 0, stream>>>(x_enc, Atok);
  mgemm_k<0, 2, 1><<<dim3(4, 64), 256, 0, stream>>>(
      Atok, Twb, ZB, X, Xb, PEf, 8192, DM, 96);

  for (int layer = 0; layer < 2; ++layer) {
    const int Lx = (layer == 0) ? 2048 : 1024;
    const int U  = (layer == 0) ? 40 : 35;
    const int M  = NB * Lx;
    const int NCH = 8;

    uint32_t kl0, kl1, s0, s1;
    threefry2x32(0u, 42u, 0u, (uint32_t)layer, &kl0, &kl1);
    threefry2x32(kl0, kl1, 0u, 1u, &s0, &s1);
    int nidx = Lx * U;
    gen_idx_k<<<(nidx + 255) / 256, 256, 0, stream>>>(IDX, nidx, Lx - 1, s0, s1);

    // fused QKV GEMM: N=1536, 3 blocks/CU
    mgemm_k<0, 0, 0><<<dim3(12, M / 128), 256, 0, stream>>>(
        Xb, Wqkvb + (size_t)layer * 786432, BQKV + layer * 1536, QKV, nullptr,
        nullptr, M, QS, DM);

    // ProbSparse attention
    if (layer == 0)
      qk_m_k<40><<<32 * Lx / 4, 256, 0, stream>>>(QKV, IDX, Mb, Lx);
    else
      qk_m_k<35><<<32 * Lx / 4, 256, 0, stream>>>(QKV, IDX, Mb, Lx);
    topk_k<<<NB * NH, 256, 0, stream>>>(Mb, MT, Lx, U);
    meanv1_k<<<NB * 16, 512, 0, stream>>>(QKV, MVP, Lx);
    meanv2_k<<<NB, 512, 0, stream>>>(MVP, MV, Lx);
    fillctx_k<<<(M * DM / 4) / 256, 256, 0, stream>>>(CTXb, MV, Lx);
    attn_flash_k<<<NB * NH * NCH, 512, 0, stream>>>(QKV, MT, Y2, Lx, U, NCH);
    attn_merge_k<<<NB * NH * U, 64, 0, stream>>>(Y2, MT, CTXb, Lx, U, NCH);

    // output projection + residual + LN1 (emits bf16 for FFN1)
    mgemm_k<0, 0, 0><<<dim3(4, M / 128), 256, 0, stream>>>(
        CTXb, Wob + (size_t)layer * 262144, bo + layer * DM, Y2, nullptr,
        nullptr, M, DM, DM);
    ln_k<<<M, 128, 0, stream>>>(X, Y2, ln1_g + layer * DM, ln1_b + layer * DM, X, Xb);

    // FFN (GELU fused; hidden kept in bf16); LN2 emits bf16
    mgemm_k<1, 1, 0><<<dim3(16, M / 128), 256, 0, stream>>>(
        Xb, W1b + (size_t)layer * 1048576, b1 + layer * 2048, nullptr, Hb,
        nullptr, M, 2048, DM);
    mgemm_k<0, 0, 0><<<dim3(4, M / 128), 256, 0, stream>>>(
        Hb, W2b + (size_t)layer * 1048576, b2 + layer * DM, Y2, nullptr,
        nullptr, M, DM, 2048);
    ln_k<<<M, 128, 0, stream>>>(X, Y2, ln2_g + layer * DM, ln2_b + layer * DM, X, Xb);

    if (layer == 0) {
      im2col_k<<<12288, 256, 0, stream>>>(X, Hb);
      mgemm_k<0, 0, 0><<<dim3(4, 64), 256, 0, stream>>>(
          Hb, Cwb, conv_b, Y2, nullptr, nullptr, 8192, DM, 1536);
      bn1_k<<<32, 256, 0, stream>>>(Y2, BNps, BNpq);
      bn2_k<<<1, 512, 0, stream>>>(BNps, BNpq, BNmu, BNvr);
      bnpool_k<<<(NB * 1024 * 512) / 256, 256, 0, stream>>>(
          Y2, BNmu, BNvr, bn_g, bn_b, X, Xb);
    }
  }

  // final LN + projection (N=32, fp32); QKV region reused as scratch
  ln_k<<<NB * 1024, 128, 0, stream>>>(X, nullptr, normf_g, normf_b, QKV, nullptr);
  gemm_k<<<dim3(1, 4096 / 64), 256, 0, stream>>>(QKV, proj_w, proj_b, out,
                                                 4096, 32, DM);
}

// Round 7
// 941.996 us; speedup vs baseline: 4.3153x; 1.1379x over previous
//
#include <hip/hip_runtime.h>
#include <cstdint>
#include <cmath>

// ---------------------------------------------------------------------------
// Informer encoder forward (B=4, L=2048, ENC_IN=32, D_MODEL=512, D_FF=2048,
// E_LAYERS=2, H=8, FACTOR=5).
// Round 7: qk_m restructured — one wave per (b,l), full-row K reads, 8 head
// dots per 3-step xor-reduce (8x fewer waves, 16x fewer shuffle ops).
// ---------------------------------------------------------------------------

#define NB 4
#define DM 512
#define NH 8
#define HD 64
#define QS 1536  // QKV row stride

typedef unsigned short ushort_t;
typedef __bf16 bf16x8 __attribute__((ext_vector_type(8)));
typedef float floatx4 __attribute__((ext_vector_type(4)));

__device__ inline ushort_t f2b(float f) {
  uint32_t u = __float_as_uint(f);
  uint32_t r = (u + 0x7fffu + ((u >> 16) & 1u)) >> 16;
  return (ushort_t)r;
}

__global__ void castb_k(const float* __restrict__ in,
                        ushort_t* __restrict__ out, int n4) {
  int i = blockIdx.x * 256 + threadIdx.x;
  if (i < n4) {
    float4 v = ((const float4*)in)[i];
    ushort4 o;
    o.x = f2b(v.x); o.y = f2b(v.y); o.z = f2b(v.z); o.w = f2b(v.w);
    ((ushort4*)out)[i] = o;
  }
}

__global__ void zerofill_k(float* __restrict__ p, int n) {
  int i = blockIdx.x * 256 + threadIdx.x;
  if (i < n) p[i] = 0.f;
}

// concat QKV bias: [layer][1536]  (0-511 q, 512-1023 k, 1024-1535 v)
__global__ void bqkv_k(const float* __restrict__ bq,
                       const float* __restrict__ bk,
                       const float* __restrict__ bv,
                       float* __restrict__ o) {
  int gid = blockIdx.x * 256 + threadIdx.x;  // 3072
  if (gid >= 3072) return;
  int layer = gid / 1536, r = gid - layer * 1536;
  float v;
  if (r < 512) v = bq[layer * 512 + r];
  else if (r < 1024) v = bk[layer * 512 + r - 512];
  else v = bv[layer * 512 + r - 1024];
  o[gid] = v;
}

// conv weight: (D, I, 3) -> bf16 (D, 3, I) so im2col is coalesced
__global__ void castw_conv_k(const float* __restrict__ in,
                             ushort_t* __restrict__ out) {
  int gid = blockIdx.x * 256 + threadIdx.x;  // 512*1536
  int d = gid / 1536, r = gid - d * 1536;
  int t = r >> 9, i = r & 511;
  out[gid] = f2b(in[d * 1536 + i * 3 + t]);
}

__host__ __device__ inline void threefry2x32(uint32_t k0, uint32_t k1,
                                             uint32_t c0, uint32_t c1,
                                             uint32_t* o0, uint32_t* o1) {
  uint32_t ks0 = k0, ks1 = k1, ks2 = k0 ^ k1 ^ 0x1BD11BDAu;
  uint32_t x0 = c0 + ks0;
  uint32_t x1 = c1 + ks1;
  const uint32_t rotA[4] = {13u, 15u, 26u, 6u};
  const uint32_t rotB[4] = {17u, 29u, 16u, 24u};
  uint32_t ks[3] = {ks0, ks1, ks2};
  #pragma unroll
  for (int i = 0; i < 5; ++i) {
    const uint32_t* r = (i & 1) ? rotB : rotA;
    #pragma unroll
    for (int j = 0; j < 4; ++j) {
      x0 += x1;
      x1 = (x1 << r[j]) | (x1 >> (32u - r[j]));
      x1 ^= x0;
    }
    x0 += ks[(i + 1) % 3];
    x1 += ks[(i + 2) % 3] + (uint32_t)(i + 1);
  }
  *o0 = x0; *o1 = x1;
}

__global__ void gen_idx_k(int* __restrict__ idx, int n, int mask,
                          uint32_t k0, uint32_t k1) {
  int i = blockIdx.x * 256 + threadIdx.x;
  if (i < n) {
    uint32_t o0, o1;
    threefry2x32(k0, k1, 0u, (uint32_t)i, &o0, &o1);
    idx[i] = (int)((o0 ^ o1) & (uint32_t)mask);
  }
}

__device__ inline float wave_sum64(float v) {
  #pragma unroll
  for (int o = 32; o > 0; o >>= 1) v += __shfl_xor(v, o, 64);
  return v;
}
__device__ inline float wave_max64(float v) {
  #pragma unroll
  for (int o = 32; o > 0; o >>= 1) v = fmaxf(v, __shfl_xor(v, o, 64));
  return v;
}

// ---------------- positional-encoding table (2048 x 512) -------------------
__global__ void pe_k(float* __restrict__ pe) {
  int i = blockIdx.x * 256 + threadIdx.x;  // 1,048,576
  int d = i & 511, l = i >> 9;
  int j2 = d & ~1;
  float div = expf((float)j2 * -1.7988946039e-2f);  // -ln(10000)/512
  float ang = (float)l * div;
  pe[i] = (d & 1) ? cosf(ang) : sinf(ang);
}

// ---------------- im2col for token conv: (B*L, 96) bf16 --------------------
__global__ void im2col_tok_k(const float* __restrict__ xe,
                             ushort_t* __restrict__ A) {
  int gid = blockIdx.x * 256 + threadIdx.x;  // 8192*96
  int col = gid % 96;
  int row = gid / 96;
  int c = col / 3, t = col - c * 3;
  int b = row >> 11, l = row & 2047;
  int ls = (l + t - 1) & 2047;
  A[gid] = f2b(xe[((size_t)b * 2048 + ls) * 32 + c]);
}

// ---------------- bf16 MFMA GEMM: C = act(A @ W^T + bias [+ pe]) -----------
__device__ inline void gload16(const ushort_t* g, ushort_t* l) {
  __builtin_amdgcn_global_load_lds(
      (const __attribute__((address_space(1))) unsigned int*)(const void*)g,
      (__attribute__((address_space(3))) unsigned int*)(void*)l, 16, 0, 0);
}

template <int GELU, int OMODE, int ADDPE>  // OMODE: 0 f32, 1 bf16, 2 both
__global__ __launch_bounds__(256) void mgemm_k(
    const ushort_t* __restrict__ A, const ushort_t* __restrict__ W,
    const float* __restrict__ bias, float* __restrict__ Cf,
    ushort_t* __restrict__ Cb, const float* __restrict__ pe,
    int M, int ldc, int K) {
  __shared__ ushort_t As[128 * 32];
  __shared__ ushort_t Bs[128 * 32];
  int m0 = blockIdx.y * 128, n0 = blockIdx.x * 128;
  int t = threadIdx.x;
  int lane = t & 63, wv = t >> 6;
  int sr = lane >> 2, sc = (lane & 3) * 8;
  int ra0 = wv * 32 + sr, ra1 = ra0 + 16;
  const ushort_t* gA0 = A + (size_t)(m0 + ra0) * K + sc;
  const ushort_t* gA1 = A + (size_t)(m0 + ra1) * K + sc;
  const ushort_t* gB0 = W + (size_t)(n0 + ra0) * K + sc;
  const ushort_t* gB1 = W + (size_t)(n0 + ra1) * K + sc;
  ushort_t* lA0 = As + wv * 1024;
  ushort_t* lA1 = lA0 + 512;
  ushort_t* lB0 = Bs + wv * 1024;
  ushort_t* lB1 = lB0 + 512;

  int quad = lane >> 4, lr = lane & 15;
  int wm = wv >> 1, wn = wv & 1;

  floatx4 acc[4][4] = {};
  for (int ks = 0; ks < K; ks += 32) {
    gload16(gA0, lA0);
    gload16(gA1, lA1);
    gload16(gB0, lB0);
    gload16(gB1, lB1);
    gA0 += 32; gA1 += 32; gB0 += 32; gB1 += 32;
    __syncthreads();
    bf16x8 av[4], bv[4];
    #pragma unroll
    for (int mt = 0; mt < 4; ++mt)
      av[mt] = *(const bf16x8*)&As[(wm * 64 + mt * 16 + lr) * 32 + quad * 8];
    #pragma unroll
    for (int nt = 0; nt < 4; ++nt)
      bv[nt] = *(const bf16x8*)&Bs[(wn * 64 + nt * 16 + lr) * 32 + quad * 8];
    #pragma unroll
    for (int mt = 0; mt < 4; ++mt)
      #pragma unroll
      for (int nt = 0; nt < 4; ++nt)
        acc[mt][nt] = __builtin_amdgcn_mfma_f32_16x16x32_bf16(
            av[mt], bv[nt], acc[mt][nt], 0, 0, 0);
    __syncthreads();
  }
  #pragma unroll
  for (int nt = 0; nt < 4; ++nt) {
    int col = n0 + wn * 64 + nt * 16 + lr;
    float bsv = bias[col];
    #pragma unroll
    for (int mt = 0; mt < 4; ++mt) {
      int row0 = m0 + wm * 64 + mt * 16 + quad * 4;
      #pragma unroll
      for (int r = 0; r < 4; ++r) {
        int row = row0 + r;
        float v = acc[mt][nt][r] + bsv;
        if (ADDPE) v += pe[(size_t)(row & 2047) * ldc + col];
        if (GELU) v = 0.5f * v * (1.0f + erff(v * 0.70710678118654752f));
        if (OMODE == 0 || OMODE == 2) Cf[(size_t)row * ldc + col] = v;
        if (OMODE == 1 || OMODE == 2) Cb[(size_t)row * ldc + col] = f2b(v);
      }
    }
  }
}

// ---------------- fp32 fallback GEMM (final projection, N=32) --------------
__global__ __launch_bounds__(256) void gemm_k(
    const float* __restrict__ A, const float* __restrict__ W,
    const float* __restrict__ bias, float* __restrict__ C,
    int M, int N, int K) {
  __shared__ float As2[16][64 + 4];
  __shared__ float Ws2[16][64 + 4];
  int m0 = blockIdx.y * 64, n0 = blockIdx.x * 64;
  int t = threadIdx.x;
  int tx = t & 15, ty = t >> 4;
  float acc[4][4] = {};
  for (int k0 = 0; k0 < K; k0 += 16) {
    #pragma unroll
    for (int i = 0; i < 4; ++i) {
      int li = t + i * 256;
      int m = li >> 4, kk = li & 15;
      As2[kk][m] = A[(size_t)(m0 + m) * K + k0 + kk];
    }
    #pragma unroll
    for (int i = 0; i < 4; ++i) {
      int li = t + i * 256;
      int n = li >> 4, kk = li & 15;
      int gn = n0 + n;
      Ws2[kk][n] = (gn < N) ? W[(size_t)gn * K + k0 + kk] : 0.0f;
    }
    __syncthreads();
    #pragma unroll
    for (int kk = 0; kk < 16; ++kk) {
      float4 avv = *(const float4*)&As2[kk][ty * 4];
      float4 bvv = *(const float4*)&Ws2[kk][tx * 4];
      float a[4] = {avv.x, avv.y, avv.z, avv.w};
      float bb[4] = {bvv.x, bvv.y, bvv.z, bvv.w};
      #pragma unroll
      for (int i = 0; i < 4; ++i)
        #pragma unroll
        for (int j = 0; j < 4; ++j) acc[i][j] += a[i] * bb[j];
    }
    __syncthreads();
  }
  #pragma unroll
  for (int i = 0; i < 4; ++i) {
    int m = m0 + ty * 4 + i;
    #pragma unroll
    for (int j = 0; j < 4; ++j) {
      int n = n0 + tx * 4 + j;
      if (n < N) C[(size_t)m * N + n] = acc[i][j] + bias[n];
    }
  }
}

// ---------------- LayerNorm (+optional residual, +optional bf16 copy) ------
__global__ __launch_bounds__(128) void ln_k(
    const float* __restrict__ A, const float* __restrict__ Bres,
    const float* __restrict__ g, const float* __restrict__ be,
    float* __restrict__ O, ushort_t* __restrict__ Ob) {
  int r = blockIdx.x, t = threadIdx.x;
  __shared__ float lds[2];
  float4 v = ((const float4*)(A + (size_t)r * DM))[t];
  if (Bres) {
    float4 u = ((const float4*)(Bres + (size_t)r * DM))[t];
    v.x += u.x; v.y += u.y; v.z += u.z; v.w += u.w;
  }
  float s = wave_sum64(v.x + v.y + v.z + v.w);
  int w = t >> 6;
  if ((t & 63) == 0) lds[w] = s;
  __syncthreads();
  float mu = (lds[0] + lds[1]) * (1.0f / 512.0f);
  __syncthreads();
  float dx = v.x - mu, dy = v.y - mu, dz = v.z - mu, dw = v.w - mu;
  float sq = wave_sum64(dx * dx + dy * dy + dz * dz + dw * dw);
  if ((t & 63) == 0) lds[w] = sq;
  __syncthreads();
  float var = (lds[0] + lds[1]) * (1.0f / 512.0f);
  float inv = 1.0f / sqrtf(var + 1e-5f);
  float4 gv = ((const float4*)g)[t];
  float4 bv = ((const float4*)be)[t];
  float4 o;
  o.x = dx * inv * gv.x + bv.x;
  o.y = dy * inv * gv.y + bv.y;
  o.z = dz * inv * gv.z + bv.z;
  o.w = dw * inv * gv.w + bv.w;
  ((float4*)(O + (size_t)r * DM))[t] = o;
  if (Ob) {
    ushort4 ob;
    ob.x = f2b(o.x); ob.y = f2b(o.y); ob.z = f2b(o.z); ob.w = f2b(o.w);
    ((ushort4*)(Ob + (size_t)r * DM))[t] = ob;
  }
}

// ---------------- M[b,h,l]: one wave per (b,l), all 8 heads at once --------
// Lane j covers dims [8j,8j+8) of the 512-wide row => 8-lane group = head.
// Per sample: 2 coalesced dwordx4 loads + 8 FMA + xor-reduce(1,2,4).
template <int UU>
__global__ __launch_bounds__(256) void qk_m_k(
    const float* __restrict__ QKV, const int* __restrict__ idx,
    float* __restrict__ Mout, int Lx) {
  int l = blockIdx.x;
  int b = threadIdx.x >> 6;  // wave = batch
  int lane = threadIdx.x & 63;
  const float* base = QKV + (size_t)b * Lx * QS;
  const float* qp = base + (size_t)l * QS + lane * 8;
  float4 q0 = *(const float4*)qp;
  float4 q1 = *(const float4*)(qp + 4);
  const float* Kbase = base + 512 + lane * 8;
  const int* ip = idx + (size_t)l * UU;
  float maxv = -INFINITY, sumv = 0.f;
  #pragma unroll
  for (int u0 = 0; u0 < UU; u0 += 8) {
    float4 k0[8], k1[8];
    #pragma unroll
    for (int j = 0; j < 8; ++j) {
      if (u0 + j < UU) {
        const float* kp = Kbase + (size_t)ip[u0 + j] * QS;
        k0[j] = *(const float4*)kp;
        k1[j] = *(const float4*)(kp + 4);
      }
    }
    #pragma unroll
    for (int j = 0; j < 8; ++j) {
      if (u0 + j < UU) {
        float p = q0.x * k0[j].x + q0.y * k0[j].y + q0.z * k0[j].z +
                  q0.w * k0[j].w + q1.x * k1[j].x + q1.y * k1[j].y +
                  q1.z * k1[j].z + q1.w * k1[j].w;
        p += __shfl_xor(p, 1, 64);
        p += __shfl_xor(p, 2, 64);
        p += __shfl_xor(p, 4, 64);
        maxv = fmaxf(maxv, p);
        sumv += p;
      }
    }
  }
  if ((lane & 7) == 0) {
    int h = lane >> 3;
    Mout[(size_t)(b * 8 + h) * Lx + l] = maxv - sumv / (float)Lx;
  }
}

// ---------------- top-U indices of M per (b,h) -----------------------------
__global__ __launch_bounds__(256) void topk_k(
    const float* __restrict__ Mbuf, int* __restrict__ Mtop, int Lx, int U) {
  int bh = blockIdx.x;
  const float* m = Mbuf + (size_t)bh * Lx;
  __shared__ float mcopy[2048];
  __shared__ float sv[256];
  __shared__ int si[256];
  int t = threadIdx.x;
  for (int i = t; i < Lx; i += 256) mcopy[i] = m[i];
  __syncthreads();
  for (int u = 0; u < U; ++u) {
    float bv = -INFINITY;
    int bi = 0x7fffffff;
    for (int i = t; i < Lx; i += 256) {
      float v = mcopy[i];
      if (v > bv || (v == bv && i < bi)) { bv = v; bi = i; }
    }
    sv[t] = bv; si[t] = bi;
    __syncthreads();
    for (int s = 128; s > 0; s >>= 1) {
      if (t < s) {
        float v2 = sv[t + s]; int i2 = si[t + s];
        if (v2 > sv[t] || (v2 == sv[t] && i2 < si[t])) { sv[t] = v2; si[t] = i2; }
      }
      __syncthreads();
    }
    if (t == 0) {
      Mtop[bh * U + u] = si[0];
      mcopy[si[0]] = -INFINITY;
    }
    __syncthreads();
  }
}

// ---------------- meanV from QKV (V at +1024, stride 1536) -----------------
__global__ __launch_bounds__(512) void meanv1_k(const float* __restrict__ QKV,
                                                float* __restrict__ part,
                                                int Lx) {
  int b = blockIdx.x >> 4, chunk = blockIdx.x & 15;
  int rows = Lx >> 4;
  int t = threadIdx.x;  // 512
  const float* vp = QKV + ((size_t)b * Lx + (size_t)chunk * rows) * QS + 1024 + t;
  float s = 0.f;
  for (int l = 0; l < rows; ++l) s += vp[(size_t)l * QS];
  part[(size_t)blockIdx.x * DM + t] = s;
}
__global__ __launch_bounds__(512) void meanv2_k(const float* __restrict__ part,
                                                float* __restrict__ mv,
                                                int Lx) {
  int b = blockIdx.x, t = threadIdx.x;
  float s = 0.f;
  #pragma unroll
  for (int c = 0; c < 16; ++c) s += part[(size_t)(b * 16 + c) * DM + t];
  mv[b * DM + t] = s / (float)Lx;
}

__global__ void fillctx_k(ushort_t* __restrict__ ctx,
                          const float* __restrict__ mv, int Lx) {
  size_t i4 = (size_t)blockIdx.x * 256 + threadIdx.x;
  int col4 = (int)(i4 & 127);
  size_t row = i4 >> 7;
  int b = (int)(row / (size_t)Lx);
  const float* m = mv + b * DM + col4 * 4;
  ushort4 o;
  o.x = f2b(m[0]); o.y = f2b(m[1]); o.z = f2b(m[2]); o.w = f2b(m[3]);
  ((ushort4*)ctx)[i4] = o;
}

// ---------------- flash split-K attention (QKV stride 1536) ----------------
__global__ __launch_bounds__(512) void attn_flash_k(
    const float* __restrict__ QKV, const int* __restrict__ Mtop,
    float* __restrict__ part, int Lx, int U, int nchunk) {
  int blk = blockIdx.x;
  int chunk = blk % nchunk, bh = blk / nchunk;
  int h = bh & 7, b = bh >> 3;
  int rows = Lx / nchunk;
  int ntile = rows >> 6;
  __shared__ float s_q[40 * 64];
  __shared__ float s_k[64 * 65];
  __shared__ float s_v[64 * 65];
  __shared__ float s_p[40 * 64];
  __shared__ float s_m[40], s_l[40], s_a[40];
  int t = threadIdx.x;
  int d = t & 63, wv = t >> 6;

  for (int i = t; i < U * 64; i += 512) {
    int u = i >> 6, dd = i & 63;
    int qi = Mtop[bh * U + u];
    s_q[i] = QKV[((size_t)b * Lx + qi) * QS + h * HD + dd] * 0.125f;
  }
  if (t < U) { s_m[t] = -INFINITY; s_l[t] = 0.f; s_a[t] = 0.f; }
  float o[5] = {0.f, 0.f, 0.f, 0.f, 0.f};
  __syncthreads();

  const float* Kp = QKV + (size_t)b * Lx * QS + 512 + h * HD;
  const float* Vp = QKV + (size_t)b * Lx * QS + 1024 + h * HD;

  for (int tile = 0; tile < ntile; ++tile) {
    int kr0 = chunk * rows + tile * 64;
    {
      int r = t >> 4, c4 = (t & 15) * 4;
      #pragma unroll
      for (int pass = 0; pass < 2; ++pass) {
        int rr = r + pass * 32;
        float4 kv = *(const float4*)&Kp[(size_t)(kr0 + rr) * QS + c4];
        float4 vv = *(const float4*)&Vp[(size_t)(kr0 + rr) * QS + c4];
        float* kd = &s_k[rr * 65 + c4];
        kd[0] = kv.x; kd[1] = kv.y; kd[2] = kv.z; kd[3] = kv.w;
        float* vd = &s_v[rr * 65 + c4];
        vd[0] = vv.x; vd[1] = vv.y; vd[2] = vv.z; vd[3] = vv.w;
      }
    }
    __syncthreads();
    {
      float kr[64];
      #pragma unroll
      for (int dd = 0; dd < 64; ++dd) kr[dd] = s_k[d * 65 + dd];
      for (int u = wv; u < U; u += 8) {
        float acc = 0.f;
        #pragma unroll
        for (int c = 0; c < 16; ++c) {
          float4 qv = *(const float4*)&s_q[u * 64 + c * 4];
          acc += qv.x * kr[c * 4] + qv.y * kr[c * 4 + 1] +
                 qv.z * kr[c * 4 + 2] + qv.w * kr[c * 4 + 3];
        }
        s_p[u * 64 + d] = acc;
      }
    }
    __syncthreads();
    for (int u = wv; u < U; u += 8) {
      float sv_ = s_p[u * 64 + d];
      float mx = wave_max64(sv_);
      float mold = s_m[u];
      float mnew = fmaxf(mold, mx);
      float e = expf(sv_ - mnew);
      float se = wave_sum64(e);
      s_p[u * 64 + d] = e;
      if (d == 0) {
        float alpha = expf(mold - mnew);
        s_a[u] = alpha;
        s_l[u] = s_l[u] * alpha + se;
        s_m[u] = mnew;
      }
    }
    __syncthreads();
    {
      float vr[64];
      #pragma unroll
      for (int k = 0; k < 64; ++k) vr[k] = s_v[k * 65 + d];
      int i = 0;
      for (int u = wv; u < U; u += 8, ++i) {
        float acc = 0.f;
        #pragma unroll
        for (int c = 0; c < 16; ++c) {
          float4 pv = *(const float4*)&s_p[u * 64 + c * 4];
          acc += pv.x * vr[c * 4] + pv.y * vr[c * 4 + 1] +
                 pv.z * vr[c * 4 + 2] + pv.w * vr[c * 4 + 3];
        }
        o[i] = o[i] * s_a[u] + acc;
      }
    }
    __syncthreads();
  }
  {
    int i = 0;
    for (int u = wv; u < U; u += 8, ++i) {
      float* pp = part + ((size_t)(bh * nchunk + chunk) * U + u) * 66;
      pp[d] = o[i];
      if (d == 0) { pp[64] = s_m[u]; pp[65] = s_l[u]; }
    }
  }
}

__global__ __launch_bounds__(64) void attn_merge_k(
    const float* __restrict__ part, const int* __restrict__ Mtop,
    ushort_t* __restrict__ ctx, int Lx, int U, int nchunk) {
  int bu = blockIdx.x;
  int u = bu % U, bh = bu / U;
  int h = bh & 7, b = bh >> 3;
  int d = threadIdx.x;  // 64
  float M = -INFINITY;
  for (int c = 0; c < nchunk; ++c)
    M = fmaxf(M, part[((size_t)(bh * nchunk + c) * U + u) * 66 + 64]);
  float L = 0.f, O = 0.f;
  for (int c = 0; c < nchunk; ++c) {
    const float* pp = part + ((size_t)(bh * nchunk + c) * U + u) * 66;
    float w = expf(pp[64] - M);
    L += pp[65] * w;
    O += pp[d] * w;
  }
  int qi = Mtop[bh * U + u];
  ctx[((size_t)b * Lx + qi) * DM + h * HD + d] = f2b(O / L);
}

// ---------------- distil im2col (circular, k=3) -> bf16, [t][c] layout -----
__global__ void im2col_k(const float* __restrict__ X,
                         ushort_t* __restrict__ A2) {
  int gid = blockIdx.x * 256 + threadIdx.x;  // 8192*3*128 ushort4 units
  int i4 = gid & 127;
  int rt = gid >> 7;
  int t = rt % 3, row = rt / 3;
  int b = row >> 11, l = row & 2047;
  int ls = (l + t - 1) & 2047;
  float4 v = ((const float4*)(X + ((size_t)b * 2048 + ls) * DM))[i4];
  ushort4 o;
  o.x = f2b(v.x); o.y = f2b(v.y); o.z = f2b(v.z); o.w = f2b(v.w);
  ((ushort4*)A2)[(size_t)row * 384 + t * 128 + i4] = o;
}

// ---------------- batch-norm stats: coalesced two-stage --------------------
__global__ __launch_bounds__(256) void bn1_k(const float* __restrict__ Y,
                                             float* __restrict__ ps,
                                             float* __restrict__ pq) {
  int blk = blockIdx.x;
  int t = threadIdx.x;
  float s0 = 0, q0 = 0, s1 = 0, q1 = 0;
  const float* base = Y + (size_t)blk * 256 * DM;
  for (int r = 0; r < 256; ++r) {
    float a = base[(size_t)r * DM + t];
    float b = base[(size_t)r * DM + t + 256];
    s0 += a; q0 += a * a; s1 += b; q1 += b * b;
  }
  ps[blk * DM + t] = s0; ps[blk * DM + t + 256] = s1;
  pq[blk * DM + t] = q0; pq[blk * DM + t + 256] = q1;
}
__global__ __launch_bounds__(512) void bn2_k(const float* __restrict__ ps,
                                             const float* __restrict__ pq,
                                             float* __restrict__ mu,
                                             float* __restrict__ var) {
  int t = threadIdx.x;
  float s = 0, q = 0;
  #pragma unroll
  for (int c = 0; c < 32; ++c) { s += ps[c * DM + t]; q += pq[c * DM + t]; }
  float m = s * (1.0f / 8192.f);
  mu[t] = m;
  var[t] = q * (1.0f / 8192.f) - m * m;
}

// fused bn+elu+maxpool(k=3,s=2,pad=1): reads conv out, writes X (fp32+bf16)
__global__ void bnpool_k(const float* __restrict__ Y,
                         const float* __restrict__ mu,
                         const float* __restrict__ var,
                         const float* __restrict__ g,
                         const float* __restrict__ be, float* __restrict__ O,
                         ushort_t* __restrict__ Ob) {
  size_t i = (size_t)blockIdx.x * 256 + threadIdx.x;  // 4*1024*512
  int c = (int)(i & 511);
  size_t row = i >> 9;
  int lo = (int)(row & 1023);
  int b = (int)(row >> 10);
  float sc = g[c] / sqrtf(var[c] + 1e-5f);
  float sh = be[c] - mu[c] * sc;
  int l0 = 2 * lo - 1;
  float m = -INFINITY;
  #pragma unroll
  for (int tt = 0; tt < 3; ++tt) {
    int l = l0 + tt;
    if (l >= 0 && l < 2048) {
      float v = Y[((size_t)b * 2048 + l) * DM + c] * sc + sh;
      v = v > 0.f ? v : expm1f(v);
      m = fmaxf(m, v);
    }
  }
  O[i] = m;
  Ob[i] = f2b(m);
}

// ---------------------------------------------------------------------------
extern "C" void kernel_launch(void* const* d_in, const int* in_sizes, int n_in,
                              void* d_out, int out_size, void* d_ws,
                              size_t ws_size, hipStream_t stream) {
  (void)in_sizes; (void)n_in; (void)out_size; (void)ws_size;
  const float* x_enc  = (const float*)d_in[0];
  const float* tok_w  = (const float*)d_in[1];
  const float* Wq     = (const float*)d_in[2];
  const float* bq     = (const float*)d_in[3];
  const float* Wk     = (const float*)d_in[4];
  const float* bk     = (const float*)d_in[5];
  const float* Wv     = (const float*)d_in[6];
  const float* bv     = (const float*)d_in[7];
  const float* Wo     = (const float*)d_in[8];
  const float* bo     = (const float*)d_in[9];
  const float* W1     = (const float*)d_in[10];
  const float* b1     = (const float*)d_in[11];
  const float* W2     = (const float*)d_in[12];
  const float* b2     = (const float*)d_in[13];
  const float* ln1_g  = (const float*)d_in[14];
  const float* ln1_b  = (const float*)d_in[15];
  const float* ln2_g  = (const float*)d_in[16];
  const float* ln2_b  = (const float*)d_in[17];
  const float* conv_w = (const float*)d_in[18];
  const float* conv_b = (const float*)d_in[19];
  const float* bn_g   = (const float*)d_in[20];
  const float* bn_b   = (const float*)d_in[21];
  const float* normf_g = (const float*)d_in[22];
  const float* normf_b = (const float*)d_in[23];
  const float* proj_w = (const float*)d_in[24];
  const float* proj_b = (const float*)d_in[25];
  float* out = (float*)d_out;
  float* ws = (float*)d_ws;

  // ---- fp32 workspace layout (float offsets) ----
  float* X    = ws;                    // 4,194,304
  float* QKV  = ws + 4194304;          // 12,582,912 (8192 x 1536)
  ushort_t* CTXb = (ushort_t*)(ws + 16777216);  // bf16 ctx
  float* Y2   = ws + 20971520;         // 4,194,304 (attn partials / conv out)
  float* Mb   = ws + 25165824;         // 65,536
  float* MV   = ws + 25231360;         // 2,048
  float* MVP  = ws + 25233408;         // 32,768
  float* BNps = ws + 25266176;         // 16,384
  float* BNpq = ws + 25282560;         // 16,384
  float* BNmu = ws + 25298944;         // 512
  float* BNvr = ws + 25299456;         // 512
  float* ZB   = ws + 25299968;         // 512 (zero bias)
  float* BQKV = ws + 25300480;         // 3,072 (concat qkv bias, 2 layers)
  int*   IDX  = (int*)(ws + 25303552); // 81,920
  int*   MT   = (int*)(ws + 25385472); // 1,280
  // ---- bf16 workspace ----
  ushort_t* U0   = (ushort_t*)(ws + 25386752);
  ushort_t* Xb   = U0;                 // 4,194,304
  ushort_t* Hb   = U0 + 4194304;       // 16,777,216
  ushort_t* Wqkvb= U0 + 20971520;      // 1,572,864 (2 layers x 1536 x 512)
  ushort_t* Wob  = U0 + 22544384;      // 524,288
  ushort_t* W1b  = U0 + 23068672;      // 2,097,152
  ushort_t* W2b  = U0 + 25165824;      // 2,097,152
  ushort_t* Cwb  = U0 + 27262976;      // 786,432
  ushort_t* Twb  = U0 + 28049408;      // 49,152
  ushort_t* Atok = U0 + 28098560;      // 786,432
  float* PEf = ws + 39829248;          // 1,048,576 (PE table)

  // weight casts: QKV concat per layer (rows 0-511 Q, 512-1023 K, 1024-1535 V)
  for (int ly = 0; ly < 2; ++ly) {
    castb_k<<<256, 256, 0, stream>>>(Wq + ly * 262144, Wqkvb + ly * 786432, 65536);
    castb_k<<<256, 256, 0, stream>>>(Wk + ly * 262144, Wqkvb + ly * 786432 + 262144, 65536);
    castb_k<<<256, 256, 0, stream>>>(Wv + ly * 262144, Wqkvb + ly * 786432 + 524288, 65536);
  }
  castb_k<<<512, 256, 0, stream>>>(Wo, Wob, 131072);
  castb_k<<<2048, 256, 0, stream>>>(W1, W1b, 524288);
  castb_k<<<2048, 256, 0, stream>>>(W2, W2b, 524288);
  castw_conv_k<<<3072, 256, 0, stream>>>(conv_w, Cwb);
  castb_k<<<48, 256, 0, stream>>>(tok_w, Twb, 12288);
  zerofill_k<<<2, 256, 0, stream>>>(ZB, 512);
  bqkv_k<<<12, 256, 0, stream>>>(bq, bk, bv, BQKV);

  // token embedding = im2col + GEMM(+PE)
  pe_k<<<4096, 256, 0, stream>>>(PEf);
  im2col_tok_k<<<3072, 256, 0, stream>>>(x_enc, Atok);
  mgemm_k<0, 2, 1><<<dim3(4, 64), 256, 0, stream>>>(
      Atok, Twb, ZB, X, Xb, PEf, 8192, DM, 96);

  for (int layer = 0; layer < 2; ++layer) {
    const int Lx = (layer == 0) ? 2048 : 1024;
    const int U  = (layer == 0) ? 40 : 35;
    const int M  = NB * Lx;
    const int NCH = 8;

    uint32_t kl0, kl1, s0, s1;
    threefry2x32(0u, 42u, 0u, (uint32_t)layer, &kl0, &kl1);
    threefry2x32(kl0, kl1, 0u, 1u, &s0, &s1);
    int nidx = Lx * U;
    gen_idx_k<<<(nidx + 255) / 256, 256, 0, stream>>>(IDX, nidx, Lx - 1, s0, s1);

    // fused QKV GEMM: N=1536, 3 blocks/CU
    mgemm_k<0, 0, 0><<<dim3(12, M / 128), 256, 0, stream>>>(
        Xb, Wqkvb + (size_t)layer * 786432, BQKV + layer * 1536, QKV, nullptr,
        nullptr, M, QS, DM);

    // ProbSparse attention: one wave per (b,l)
    if (layer == 0)
      qk_m_k<40><<<Lx, 256, 0, stream>>>(QKV, IDX, Mb, Lx);
    else
      qk_m_k<35><<<Lx, 256, 0, stream>>>(QKV, IDX, Mb, Lx);
    topk_k<<<NB * NH, 256, 0, stream>>>(Mb, MT, Lx, U);
    meanv1_k<<<NB * 16, 512, 0, stream>>>(QKV, MVP, Lx);
    meanv2_k<<<NB, 512, 0, stream>>>(MVP, MV, Lx);
    fillctx_k<<<(M * DM / 4) / 256, 256, 0, stream>>>(CTXb, MV, Lx);
    attn_flash_k<<<NB * NH * NCH, 512, 0, stream>>>(QKV, MT, Y2, Lx, U, NCH);
    attn_merge_k<<<NB * NH * U, 64, 0, stream>>>(Y2, MT, CTXb, Lx, U, NCH);

    // output projection + residual + LN1 (emits bf16 for FFN1)
    mgemm_k<0, 0, 0><<<dim3(4, M / 128), 256, 0, stream>>>(
        CTXb, Wob + (size_t)layer * 262144, bo + layer * DM, Y2, nullptr,
        nullptr, M, DM, DM);
    ln_k<<<M, 128, 0, stream>>>(X, Y2, ln1_g + layer * DM, ln1_b + layer * DM, X, Xb);

    // FFN (GELU fused; hidden kept in bf16); LN2 emits bf16
    mgemm_k<1, 1, 0><<<dim3(16, M / 128), 256, 0, stream>>>(
        Xb, W1b + (size_t)layer * 1048576, b1 + layer * 2048, nullptr, Hb,
        nullptr, M, 2048, DM);
    mgemm_k<0, 0, 0><<<dim3(4, M / 128), 256, 0, stream>>>(
        Hb, W2b + (size_t)layer * 1048576, b2 + layer * DM, Y2, nullptr,
        nullptr, M, DM, 2048);
    ln_k<<<M, 128, 0, stream>>>(X, Y2, ln2_g + layer * DM, ln2_b + layer * DM, X, Xb);

    if (layer == 0) {
      im2col_k<<<12288, 256, 0, stream>>>(X, Hb);
      mgemm_k<0, 0, 0><<<dim3(4, 64), 256, 0, stream>>>(
          Hb, Cwb, conv_b, Y2, nullptr, nullptr, 8192, DM, 1536);
      bn1_k<<<32, 256, 0, stream>>>(Y2, BNps, BNpq);
      bn2_k<<<1, 512, 0, stream>>>(BNps, BNpq, BNmu, BNvr);
      bnpool_k<<<(NB * 1024 * 512) / 256, 256, 0, stream>>>(
          Y2, BNmu, BNvr, bn_g, bn_b, X, Xb);
    }
  }

  // final LN + projection (N=32, fp32); QKV region reused as scratch
  ln_k<<<NB * 1024, 128, 0, stream>>>(X, nullptr, normf_g, normf_b, QKV, nullptr);
  gemm_k<<<dim3(1, 4096 / 64), 256, 0, stream>>>(QKV, proj_w, proj_b, out,
                                                 4096, 32, DM);
}

// Round 8
// 931.999 us; speedup vs baseline: 4.3616x; 1.0107x over previous
//
#include <hip/hip_runtime.h>
#include <cstdint>
#include <cmath>

// ---------------------------------------------------------------------------
// Informer encoder forward (B=4, L=2048, ENC_IN=32, D_MODEL=512, D_FF=2048,
// E_LAYERS=2, H=8, FACTOR=5).
// Round 8: qk_m gathers K rows in bf16 (half the bytes; bf16 QKV copy aliased
// over the FFN-hidden buffer); preamble setup kernels fused 15 -> 6.
// ---------------------------------------------------------------------------

#define NB 4
#define DM 512
#define NH 8
#define HD 64
#define QS 1536  // QKV row stride

typedef unsigned short ushort_t;
typedef __bf16 bf16x8 __attribute__((ext_vector_type(8)));
typedef float floatx4 __attribute__((ext_vector_type(4)));
typedef unsigned short ushort8_t __attribute__((ext_vector_type(8)));

__device__ inline ushort_t f2b(float f) {
  uint32_t u = __float_as_uint(f);
  uint32_t r = (u + 0x7fffu + ((u >> 16) & 1u)) >> 16;
  return (ushort_t)r;
}
__device__ inline float b2f(ushort_t u) {
  return __uint_as_float((uint32_t)u << 16);
}

// ---------------- fused weight casts ---------------------------------------
// QKV concat: 2 layers x 1536 rows x 512 (rows 0-511 Q, 512-1023 K, 1024-1535 V)
__global__ void castqkv_k(const float* __restrict__ Wq,
                          const float* __restrict__ Wk,
                          const float* __restrict__ Wv,
                          ushort_t* __restrict__ out) {
  int gid = blockIdx.x * 256 + threadIdx.x;  // 393216 float4 units
  if (gid >= 393216) return;
  int ly = gid / 196608, r4 = gid - ly * 196608;
  int r = r4 >> 7, c4 = r4 & 127;
  int sel = r >> 9, srow = r & 511;
  const float* src = (sel == 0 ? Wq : sel == 1 ? Wk : Wv) + ly * 262144 +
                     srow * 512 + c4 * 4;
  float4 v = *(const float4*)src;
  ushort4 o;
  o.x = f2b(v.x); o.y = f2b(v.y); o.z = f2b(v.z); o.w = f2b(v.w);
  ((ushort4*)out)[ly * 196608 + r * 128 + c4] = o;
}

// Wo (131072 u4) | W1 (524288) | W2 (524288) | tok_w (12288): straight casts
__global__ void castw3_k(const float* __restrict__ Wo,
                         const float* __restrict__ W1,
                         const float* __restrict__ W2,
                         const float* __restrict__ tw,
                         ushort_t* __restrict__ oWo, ushort_t* __restrict__ oW1,
                         ushort_t* __restrict__ oW2, ushort_t* __restrict__ otw) {
  int gid = blockIdx.x * 256 + threadIdx.x;  // 1,191,936 float4 units
  if (gid >= 1191936) return;
  const float* src;
  ushort4* dst;
  int i;
  if (gid < 131072) { src = Wo; dst = (ushort4*)oWo; i = gid; }
  else if (gid < 655360) { src = W1; dst = (ushort4*)oW1; i = gid - 131072; }
  else if (gid < 1179648) { src = W2; dst = (ushort4*)oW2; i = gid - 655360; }
  else { src = tw; dst = (ushort4*)otw; i = gid - 1179648; }
  float4 v = ((const float4*)src)[i];
  ushort4 o;
  o.x = f2b(v.x); o.y = f2b(v.y); o.z = f2b(v.z); o.w = f2b(v.w);
  dst[i] = o;
}

// conv weight: (D, I, 3) -> bf16 (D, 3, I) so im2col is coalesced
__global__ void castw_conv_k(const float* __restrict__ in,
                             ushort_t* __restrict__ out) {
  int gid = blockIdx.x * 256 + threadIdx.x;  // 512*1536
  int d = gid / 1536, r = gid - d * 1536;
  int t = r >> 9, i = r & 511;
  out[gid] = f2b(in[d * 1536 + i * 3 + t]);
}

// small setup: ZB zero (512) + BQKV concat (3072)
__global__ void setup_small_k(const float* __restrict__ bq,
                              const float* __restrict__ bk,
                              const float* __restrict__ bv,
                              float* __restrict__ ZB,
                              float* __restrict__ BQKV) {
  int gid = blockIdx.x * 256 + threadIdx.x;  // 3584
  if (gid >= 3584) return;
  if (gid < 512) { ZB[gid] = 0.f; return; }
  int g = gid - 512;
  int layer = g / 1536, r = g - layer * 1536;
  float v;
  if (r < 512) v = bq[layer * 512 + r];
  else if (r < 1024) v = bk[layer * 512 + r - 512];
  else v = bv[layer * 512 + r - 1024];
  BQKV[g] = v;
}

__host__ __device__ inline void threefry2x32(uint32_t k0, uint32_t k1,
                                             uint32_t c0, uint32_t c1,
                                             uint32_t* o0, uint32_t* o1) {
  uint32_t ks0 = k0, ks1 = k1, ks2 = k0 ^ k1 ^ 0x1BD11BDAu;
  uint32_t x0 = c0 + ks0;
  uint32_t x1 = c1 + ks1;
  const uint32_t rotA[4] = {13u, 15u, 26u, 6u};
  const uint32_t rotB[4] = {17u, 29u, 16u, 24u};
  uint32_t ks[3] = {ks0, ks1, ks2};
  #pragma unroll
  for (int i = 0; i < 5; ++i) {
    const uint32_t* r = (i & 1) ? rotB : rotA;
    #pragma unroll
    for (int j = 0; j < 4; ++j) {
      x0 += x1;
      x1 = (x1 << r[j]) | (x1 >> (32u - r[j]));
      x1 ^= x0;
    }
    x0 += ks[(i + 1) % 3];
    x1 += ks[(i + 2) % 3] + (uint32_t)(i + 1);
  }
  *o0 = x0; *o1 = x1;
}

__global__ void gen_idx_k(int* __restrict__ idx, int n, int mask,
                          uint32_t k0, uint32_t k1) {
  int i = blockIdx.x * 256 + threadIdx.x;
  if (i < n) {
    uint32_t o0, o1;
    threefry2x32(k0, k1, 0u, (uint32_t)i, &o0, &o1);
    idx[i] = (int)((o0 ^ o1) & (uint32_t)mask);
  }
}

__device__ inline float wave_sum64(float v) {
  #pragma unroll
  for (int o = 32; o > 0; o >>= 1) v += __shfl_xor(v, o, 64);
  return v;
}
__device__ inline float wave_max64(float v) {
  #pragma unroll
  for (int o = 32; o > 0; o >>= 1) v = fmaxf(v, __shfl_xor(v, o, 64));
  return v;
}

// ---------------- positional-encoding table (2048 x 512) -------------------
__global__ void pe_k(float* __restrict__ pe) {
  int i = blockIdx.x * 256 + threadIdx.x;  // 1,048,576
  int d = i & 511, l = i >> 9;
  int j2 = d & ~1;
  float div = expf((float)j2 * -1.7988946039e-2f);  // -ln(10000)/512
  float ang = (float)l * div;
  pe[i] = (d & 1) ? cosf(ang) : sinf(ang);
}

// ---------------- im2col for token conv: (B*L, 96) bf16 --------------------
__global__ void im2col_tok_k(const float* __restrict__ xe,
                             ushort_t* __restrict__ A) {
  int gid = blockIdx.x * 256 + threadIdx.x;  // 8192*96
  int col = gid % 96;
  int row = gid / 96;
  int c = col / 3, t = col - c * 3;
  int b = row >> 11, l = row & 2047;
  int ls = (l + t - 1) & 2047;
  A[gid] = f2b(xe[((size_t)b * 2048 + ls) * 32 + c]);
}

// ---------------- bf16 MFMA GEMM: C = act(A @ W^T + bias [+ pe]) -----------
__device__ inline void gload16(const ushort_t* g, ushort_t* l) {
  __builtin_amdgcn_global_load_lds(
      (const __attribute__((address_space(1))) unsigned int*)(const void*)g,
      (__attribute__((address_space(3))) unsigned int*)(void*)l, 16, 0, 0);
}

template <int GELU, int OMODE, int ADDPE>  // OMODE: 0 f32, 1 bf16, 2 both
__global__ __launch_bounds__(256) void mgemm_k(
    const ushort_t* __restrict__ A, const ushort_t* __restrict__ W,
    const float* __restrict__ bias, float* __restrict__ Cf,
    ushort_t* __restrict__ Cb, const float* __restrict__ pe,
    int M, int ldc, int K) {
  __shared__ ushort_t As[128 * 32];
  __shared__ ushort_t Bs[128 * 32];
  int m0 = blockIdx.y * 128, n0 = blockIdx.x * 128;
  int t = threadIdx.x;
  int lane = t & 63, wv = t >> 6;
  int sr = lane >> 2, sc = (lane & 3) * 8;
  int ra0 = wv * 32 + sr, ra1 = ra0 + 16;
  const ushort_t* gA0 = A + (size_t)(m0 + ra0) * K + sc;
  const ushort_t* gA1 = A + (size_t)(m0 + ra1) * K + sc;
  const ushort_t* gB0 = W + (size_t)(n0 + ra0) * K + sc;
  const ushort_t* gB1 = W + (size_t)(n0 + ra1) * K + sc;
  ushort_t* lA0 = As + wv * 1024;
  ushort_t* lA1 = lA0 + 512;
  ushort_t* lB0 = Bs + wv * 1024;
  ushort_t* lB1 = lB0 + 512;

  int quad = lane >> 4, lr = lane & 15;
  int wm = wv >> 1, wn = wv & 1;

  floatx4 acc[4][4] = {};
  for (int ks = 0; ks < K; ks += 32) {
    gload16(gA0, lA0);
    gload16(gA1, lA1);
    gload16(gB0, lB0);
    gload16(gB1, lB1);
    gA0 += 32; gA1 += 32; gB0 += 32; gB1 += 32;
    __syncthreads();
    bf16x8 av[4], bv[4];
    #pragma unroll
    for (int mt = 0; mt < 4; ++mt)
      av[mt] = *(const bf16x8*)&As[(wm * 64 + mt * 16 + lr) * 32 + quad * 8];
    #pragma unroll
    for (int nt = 0; nt < 4; ++nt)
      bv[nt] = *(const bf16x8*)&Bs[(wn * 64 + nt * 16 + lr) * 32 + quad * 8];
    #pragma unroll
    for (int mt = 0; mt < 4; ++mt)
      #pragma unroll
      for (int nt = 0; nt < 4; ++nt)
        acc[mt][nt] = __builtin_amdgcn_mfma_f32_16x16x32_bf16(
            av[mt], bv[nt], acc[mt][nt], 0, 0, 0);
    __syncthreads();
  }
  #pragma unroll
  for (int nt = 0; nt < 4; ++nt) {
    int col = n0 + wn * 64 + nt * 16 + lr;
    float bsv = bias[col];
    #pragma unroll
    for (int mt = 0; mt < 4; ++mt) {
      int row0 = m0 + wm * 64 + mt * 16 + quad * 4;
      #pragma unroll
      for (int r = 0; r < 4; ++r) {
        int row = row0 + r;
        float v = acc[mt][nt][r] + bsv;
        if (ADDPE) v += pe[(size_t)(row & 2047) * ldc + col];
        if (GELU) v = 0.5f * v * (1.0f + erff(v * 0.70710678118654752f));
        if (OMODE == 0 || OMODE == 2) Cf[(size_t)row * ldc + col] = v;
        if (OMODE == 1 || OMODE == 2) Cb[(size_t)row * ldc + col] = f2b(v);
      }
    }
  }
}

// ---------------- fp32 fallback GEMM (final projection, N=32) --------------
__global__ __launch_bounds__(256) void gemm_k(
    const float* __restrict__ A, const float* __restrict__ W,
    const float* __restrict__ bias, float* __restrict__ C,
    int M, int N, int K) {
  __shared__ float As2[16][64 + 4];
  __shared__ float Ws2[16][64 + 4];
  int m0 = blockIdx.y * 64, n0 = blockIdx.x * 64;
  int t = threadIdx.x;
  int tx = t & 15, ty = t >> 4;
  float acc[4][4] = {};
  for (int k0 = 0; k0 < K; k0 += 16) {
    #pragma unroll
    for (int i = 0; i < 4; ++i) {
      int li = t + i * 256;
      int m = li >> 4, kk = li & 15;
      As2[kk][m] = A[(size_t)(m0 + m) * K + k0 + kk];
    }
    #pragma unroll
    for (int i = 0; i < 4; ++i) {
      int li = t + i * 256;
      int n = li >> 4, kk = li & 15;
      int gn = n0 + n;
      Ws2[kk][n] = (gn < N) ? W[(size_t)gn * K + k0 + kk] : 0.0f;
    }
    __syncthreads();
    #pragma unroll
    for (int kk = 0; kk < 16; ++kk) {
      float4 avv = *(const float4*)&As2[kk][ty * 4];
      float4 bvv = *(const float4*)&Ws2[kk][tx * 4];
      float a[4] = {avv.x, avv.y, avv.z, avv.w};
      float bb[4] = {bvv.x, bvv.y, bvv.z, bvv.w};
      #pragma unroll
      for (int i = 0; i < 4; ++i)
        #pragma unroll
        for (int j = 0; j < 4; ++j) acc[i][j] += a[i] * bb[j];
    }
    __syncthreads();
  }
  #pragma unroll
  for (int i = 0; i < 4; ++i) {
    int m = m0 + ty * 4 + i;
    #pragma unroll
    for (int j = 0; j < 4; ++j) {
      int n = n0 + tx * 4 + j;
      if (n < N) C[(size_t)m * N + n] = acc[i][j] + bias[n];
    }
  }
}

// ---------------- LayerNorm (+optional residual, +optional bf16 copy) ------
__global__ __launch_bounds__(128) void ln_k(
    const float* __restrict__ A, const float* __restrict__ Bres,
    const float* __restrict__ g, const float* __restrict__ be,
    float* __restrict__ O, ushort_t* __restrict__ Ob) {
  int r = blockIdx.x, t = threadIdx.x;
  __shared__ float lds[2];
  float4 v = ((const float4*)(A + (size_t)r * DM))[t];
  if (Bres) {
    float4 u = ((const float4*)(Bres + (size_t)r * DM))[t];
    v.x += u.x; v.y += u.y; v.z += u.z; v.w += u.w;
  }
  float s = wave_sum64(v.x + v.y + v.z + v.w);
  int w = t >> 6;
  if ((t & 63) == 0) lds[w] = s;
  __syncthreads();
  float mu = (lds[0] + lds[1]) * (1.0f / 512.0f);
  __syncthreads();
  float dx = v.x - mu, dy = v.y - mu, dz = v.z - mu, dw = v.w - mu;
  float sq = wave_sum64(dx * dx + dy * dy + dz * dz + dw * dw);
  if ((t & 63) == 0) lds[w] = sq;
  __syncthreads();
  float var = (lds[0] + lds[1]) * (1.0f / 512.0f);
  float inv = 1.0f / sqrtf(var + 1e-5f);
  float4 gv = ((const float4*)g)[t];
  float4 bv = ((const float4*)be)[t];
  float4 o;
  o.x = dx * inv * gv.x + bv.x;
  o.y = dy * inv * gv.y + bv.y;
  o.z = dz * inv * gv.z + bv.z;
  o.w = dw * inv * gv.w + bv.w;
  ((float4*)(O + (size_t)r * DM))[t] = o;
  if (Ob) {
    ushort4 ob;
    ob.x = f2b(o.x); ob.y = f2b(o.y); ob.z = f2b(o.z); ob.w = f2b(o.w);
    ((ushort4*)(Ob + (size_t)r * DM))[t] = ob;
  }
}

// ---------------- M[b,h,l]: one wave per (b,l), bf16 K rows ----------------
// Lane j covers dims [8j,8j+8); 8-lane group = head. Per sample: ONE 16B load
// (8 bf16) + 8 FMA + xor-reduce(1,2,4).
template <int UU>
__global__ __launch_bounds__(256) void qk_m_k(
    const float* __restrict__ QKV, const ushort_t* __restrict__ QKVb,
    const int* __restrict__ idx, float* __restrict__ Mout, int Lx) {
  int l = blockIdx.x;
  int b = threadIdx.x >> 6;  // wave = batch
  int lane = threadIdx.x & 63;
  const float* qp = QKV + ((size_t)b * Lx + l) * QS + lane * 8;
  float q[8];
  {
    float4 q0 = *(const float4*)qp;
    float4 q1 = *(const float4*)(qp + 4);
    q[0] = q0.x; q[1] = q0.y; q[2] = q0.z; q[3] = q0.w;
    q[4] = q1.x; q[5] = q1.y; q[6] = q1.z; q[7] = q1.w;
  }
  const ushort_t* Kbase = QKVb + (size_t)b * Lx * QS + 512 + lane * 8;
  const int* ip = idx + (size_t)l * UU;
  float maxv = -INFINITY, sumv = 0.f;
  #pragma unroll
  for (int u0 = 0; u0 < UU; u0 += 8) {
    ushort8_t kv[8];
    #pragma unroll
    for (int j = 0; j < 8; ++j) {
      if (u0 + j < UU)
        kv[j] = *(const ushort8_t*)(Kbase + (size_t)ip[u0 + j] * QS);
    }
    #pragma unroll
    for (int j = 0; j < 8; ++j) {
      if (u0 + j < UU) {
        float p = 0.f;
        #pragma unroll
        for (int c = 0; c < 8; ++c) p += q[c] * b2f(kv[j][c]);
        p += __shfl_xor(p, 1, 64);
        p += __shfl_xor(p, 2, 64);
        p += __shfl_xor(p, 4, 64);
        maxv = fmaxf(maxv, p);
        sumv += p;
      }
    }
  }
  if ((lane & 7) == 0) {
    int h = lane >> 3;
    Mout[(size_t)(b * 8 + h) * Lx + l] = maxv - sumv / (float)Lx;
  }
}

// ---------------- top-U indices of M per (b,h) -----------------------------
__global__ __launch_bounds__(256) void topk_k(
    const float* __restrict__ Mbuf, int* __restrict__ Mtop, int Lx, int U) {
  int bh = blockIdx.x;
  const float* m = Mbuf + (size_t)bh * Lx;
  __shared__ float mcopy[2048];
  __shared__ float sv[256];
  __shared__ int si[256];
  int t = threadIdx.x;
  for (int i = t; i < Lx; i += 256) mcopy[i] = m[i];
  __syncthreads();
  for (int u = 0; u < U; ++u) {
    float bv = -INFINITY;
    int bi = 0x7fffffff;
    for (int i = t; i < Lx; i += 256) {
      float v = mcopy[i];
      if (v > bv || (v == bv && i < bi)) { bv = v; bi = i; }
    }
    sv[t] = bv; si[t] = bi;
    __syncthreads();
    for (int s = 128; s > 0; s >>= 1) {
      if (t < s) {
        float v2 = sv[t + s]; int i2 = si[t + s];
        if (v2 > sv[t] || (v2 == sv[t] && i2 < si[t])) { sv[t] = v2; si[t] = i2; }
      }
      __syncthreads();
    }
    if (t == 0) {
      Mtop[bh * U + u] = si[0];
      mcopy[si[0]] = -INFINITY;
    }
    __syncthreads();
  }
}

// ---------------- meanV from QKV (V at +1024, stride 1536) -----------------
__global__ __launch_bounds__(512) void meanv1_k(const float* __restrict__ QKV,
                                                float* __restrict__ part,
                                                int Lx) {
  int b = blockIdx.x >> 4, chunk = blockIdx.x & 15;
  int rows = Lx >> 4;
  int t = threadIdx.x;  // 512
  const float* vp = QKV + ((size_t)b * Lx + (size_t)chunk * rows) * QS + 1024 + t;
  float s = 0.f;
  for (int l = 0; l < rows; ++l) s += vp[(size_t)l * QS];
  part[(size_t)blockIdx.x * DM + t] = s;
}
__global__ __launch_bounds__(512) void meanv2_k(const float* __restrict__ part,
                                                float* __restrict__ mv,
                                                int Lx) {
  int b = blockIdx.x, t = threadIdx.x;
  float s = 0.f;
  #pragma unroll
  for (int c = 0; c < 16; ++c) s += part[(size_t)(b * 16 + c) * DM + t];
  mv[b * DM + t] = s / (float)Lx;
}

__global__ void fillctx_k(ushort_t* __restrict__ ctx,
                          const float* __restrict__ mv, int Lx) {
  size_t i4 = (size_t)blockIdx.x * 256 + threadIdx.x;
  int col4 = (int)(i4 & 127);
  size_t row = i4 >> 7;
  int b = (int)(row / (size_t)Lx);
  const float* m = mv + b * DM + col4 * 4;
  ushort4 o;
  o.x = f2b(m[0]); o.y = f2b(m[1]); o.z = f2b(m[2]); o.w = f2b(m[3]);
  ((ushort4*)ctx)[i4] = o;
}

// ---------------- flash split-K attention (QKV stride 1536) ----------------
__global__ __launch_bounds__(512) void attn_flash_k(
    const float* __restrict__ QKV, const int* __restrict__ Mtop,
    float* __restrict__ part, int Lx, int U, int nchunk) {
  int blk = blockIdx.x;
  int chunk = blk % nchunk, bh = blk / nchunk;
  int h = bh & 7, b = bh >> 3;
  int rows = Lx / nchunk;
  int ntile = rows >> 6;
  __shared__ float s_q[40 * 64];
  __shared__ float s_k[64 * 65];
  __shared__ float s_v[64 * 65];
  __shared__ float s_p[40 * 64];
  __shared__ float s_m[40], s_l[40], s_a[40];
  int t = threadIdx.x;
  int d = t & 63, wv = t >> 6;

  for (int i = t; i < U * 64; i += 512) {
    int u = i >> 6, dd = i & 63;
    int qi = Mtop[bh * U + u];
    s_q[i] = QKV[((size_t)b * Lx + qi) * QS + h * HD + dd] * 0.125f;
  }
  if (t < U) { s_m[t] = -INFINITY; s_l[t] = 0.f; s_a[t] = 0.f; }
  float o[5] = {0.f, 0.f, 0.f, 0.f, 0.f};
  __syncthreads();

  const float* Kp = QKV + (size_t)b * Lx * QS + 512 + h * HD;
  const float* Vp = QKV + (size_t)b * Lx * QS + 1024 + h * HD;

  for (int tile = 0; tile < ntile; ++tile) {
    int kr0 = chunk * rows + tile * 64;
    {
      int r = t >> 4, c4 = (t & 15) * 4;
      #pragma unroll
      for (int pass = 0; pass < 2; ++pass) {
        int rr = r + pass * 32;
        float4 kv = *(const float4*)&Kp[(size_t)(kr0 + rr) * QS + c4];
        float4 vv = *(const float4*)&Vp[(size_t)(kr0 + rr) * QS + c4];
        float* kd = &s_k[rr * 65 + c4];
        kd[0] = kv.x; kd[1] = kv.y; kd[2] = kv.z; kd[3] = kv.w;
        float* vd = &s_v[rr * 65 + c4];
        vd[0] = vv.x; vd[1] = vv.y; vd[2] = vv.z; vd[3] = vv.w;
      }
    }
    __syncthreads();
    {
      float kr[64];
      #pragma unroll
      for (int dd = 0; dd < 64; ++dd) kr[dd] = s_k[d * 65 + dd];
      for (int u = wv; u < U; u += 8) {
        float acc = 0.f;
        #pragma unroll
        for (int c = 0; c < 16; ++c) {
          float4 qv = *(const float4*)&s_q[u * 64 + c * 4];
          acc += qv.x * kr[c * 4] + qv.y * kr[c * 4 + 1] +
                 qv.z * kr[c * 4 + 2] + qv.w * kr[c * 4 + 3];
        }
        s_p[u * 64 + d] = acc;
      }
    }
    __syncthreads();
    for (int u = wv; u < U; u += 8) {
      float sv_ = s_p[u * 64 + d];
      float mx = wave_max64(sv_);
      float mold = s_m[u];
      float mnew = fmaxf(mold, mx);
      float e = expf(sv_ - mnew);
      float se = wave_sum64(e);
      s_p[u * 64 + d] = e;
      if (d == 0) {
        float alpha = expf(mold - mnew);
        s_a[u] = alpha;
        s_l[u] = s_l[u] * alpha + se;
        s_m[u] = mnew;
      }
    }
    __syncthreads();
    {
      float vr[64];
      #pragma unroll
      for (int k = 0; k < 64; ++k) vr[k] = s_v[k * 65 + d];
      int i = 0;
      for (int u = wv; u < U; u += 8, ++i) {
        float acc = 0.f;
        #pragma unroll
        for (int c = 0; c < 16; ++c) {
          float4 pv = *(const float4*)&s_p[u * 64 + c * 4];
          acc += pv.x * vr[c * 4] + pv.y * vr[c * 4 + 1] +
                 pv.z * vr[c * 4 + 2] + pv.w * vr[c * 4 + 3];
        }
        o[i] = o[i] * s_a[u] + acc;
      }
    }
    __syncthreads();
  }
  {
    int i = 0;
    for (int u = wv; u < U; u += 8, ++i) {
      float* pp = part + ((size_t)(bh * nchunk + chunk) * U + u) * 66;
      pp[d] = o[i];
      if (d == 0) { pp[64] = s_m[u]; pp[65] = s_l[u]; }
    }
  }
}

__global__ __launch_bounds__(64) void attn_merge_k(
    const float* __restrict__ part, const int* __restrict__ Mtop,
    ushort_t* __restrict__ ctx, int Lx, int U, int nchunk) {
  int bu = blockIdx.x;
  int u = bu % U, bh = bu / U;
  int h = bh & 7, b = bh >> 3;
  int d = threadIdx.x;  // 64
  float M = -INFINITY;
  for (int c = 0; c < nchunk; ++c)
    M = fmaxf(M, part[((size_t)(bh * nchunk + c) * U + u) * 66 + 64]);
  float L = 0.f, O = 0.f;
  for (int c = 0; c < nchunk; ++c) {
    const float* pp = part + ((size_t)(bh * nchunk + c) * U + u) * 66;
    float w = expf(pp[64] - M);
    L += pp[65] * w;
    O += pp[d] * w;
  }
  int qi = Mtop[bh * U + u];
  ctx[((size_t)b * Lx + qi) * DM + h * HD + d] = f2b(O / L);
}

// ---------------- distil im2col (circular, k=3) -> bf16, [t][c] layout -----
__global__ void im2col_k(const float* __restrict__ X,
                         ushort_t* __restrict__ A2) {
  int gid = blockIdx.x * 256 + threadIdx.x;  // 8192*3*128 ushort4 units
  int i4 = gid & 127;
  int rt = gid >> 7;
  int t = rt % 3, row = rt / 3;
  int b = row >> 11, l = row & 2047;
  int ls = (l + t - 1) & 2047;
  float4 v = ((const float4*)(X + ((size_t)b * 2048 + ls) * DM))[i4];
  ushort4 o;
  o.x = f2b(v.x); o.y = f2b(v.y); o.z = f2b(v.z); o.w = f2b(v.w);
  ((ushort4*)A2)[(size_t)row * 384 + t * 128 + i4] = o;
}

// ---------------- batch-norm stats: coalesced two-stage --------------------
__global__ __launch_bounds__(256) void bn1_k(const float* __restrict__ Y,
                                             float* __restrict__ ps,
                                             float* __restrict__ pq) {
  int blk = blockIdx.x;
  int t = threadIdx.x;
  float s0 = 0, q0 = 0, s1 = 0, q1 = 0;
  const float* base = Y + (size_t)blk * 256 * DM;
  for (int r = 0; r < 256; ++r) {
    float a = base[(size_t)r * DM + t];
    float b = base[(size_t)r * DM + t + 256];
    s0 += a; q0 += a * a; s1 += b; q1 += b * b;
  }
  ps[blk * DM + t] = s0; ps[blk * DM + t + 256] = s1;
  pq[blk * DM + t] = q0; pq[blk * DM + t + 256] = q1;
}
__global__ __launch_bounds__(512) void bn2_k(const float* __restrict__ ps,
                                             const float* __restrict__ pq,
                                             float* __restrict__ mu,
                                             float* __restrict__ var) {
  int t = threadIdx.x;
  float s = 0, q = 0;
  #pragma unroll
  for (int c = 0; c < 32; ++c) { s += ps[c * DM + t]; q += pq[c * DM + t]; }
  float m = s * (1.0f / 8192.f);
  mu[t] = m;
  var[t] = q * (1.0f / 8192.f) - m * m;
}

// fused bn+elu+maxpool(k=3,s=2,pad=1): reads conv out, writes X (fp32+bf16)
__global__ void bnpool_k(const float* __restrict__ Y,
                         const float* __restrict__ mu,
                         const float* __restrict__ var,
                         const float* __restrict__ g,
                         const float* __restrict__ be, float* __restrict__ O,
                         ushort_t* __restrict__ Ob) {
  size_t i = (size_t)blockIdx.x * 256 + threadIdx.x;  // 4*1024*512
  int c = (int)(i & 511);
  size_t row = i >> 9;
  int lo = (int)(row & 1023);
  int b = (int)(row >> 10);
  float sc = g[c] / sqrtf(var[c] + 1e-5f);
  float sh = be[c] - mu[c] * sc;
  int l0 = 2 * lo - 1;
  float m = -INFINITY;
  #pragma unroll
  for (int tt = 0; tt < 3; ++tt) {
    int l = l0 + tt;
    if (l >= 0 && l < 2048) {
      float v = Y[((size_t)b * 2048 + l) * DM + c] * sc + sh;
      v = v > 0.f ? v : expm1f(v);
      m = fmaxf(m, v);
    }
  }
  O[i] = m;
  Ob[i] = f2b(m);
}

// ---------------------------------------------------------------------------
extern "C" void kernel_launch(void* const* d_in, const int* in_sizes, int n_in,
                              void* d_out, int out_size, void* d_ws,
                              size_t ws_size, hipStream_t stream) {
  (void)in_sizes; (void)n_in; (void)out_size; (void)ws_size;
  const float* x_enc  = (const float*)d_in[0];
  const float* tok_w  = (const float*)d_in[1];
  const float* Wq     = (const float*)d_in[2];
  const float* bq     = (const float*)d_in[3];
  const float* Wk     = (const float*)d_in[4];
  const float* bk     = (const float*)d_in[5];
  const float* Wv     = (const float*)d_in[6];
  const float* bv     = (const float*)d_in[7];
  const float* Wo     = (const float*)d_in[8];
  const float* bo     = (const float*)d_in[9];
  const float* W1     = (const float*)d_in[10];
  const float* b1     = (const float*)d_in[11];
  const float* W2     = (const float*)d_in[12];
  const float* b2     = (const float*)d_in[13];
  const float* ln1_g  = (const float*)d_in[14];
  const float* ln1_b  = (const float*)d_in[15];
  const float* ln2_g  = (const float*)d_in[16];
  const float* ln2_b  = (const float*)d_in[17];
  const float* conv_w = (const float*)d_in[18];
  const float* conv_b = (const float*)d_in[19];
  const float* bn_g   = (const float*)d_in[20];
  const float* bn_b   = (const float*)d_in[21];
  const float* normf_g = (const float*)d_in[22];
  const float* normf_b = (const float*)d_in[23];
  const float* proj_w = (const float*)d_in[24];
  const float* proj_b = (const float*)d_in[25];
  float* out = (float*)d_out;
  float* ws = (float*)d_ws;

  // ---- fp32 workspace layout (float offsets) ----
  float* X    = ws;                    // 4,194,304
  float* QKV  = ws + 4194304;          // 12,582,912 (8192 x 1536)
  ushort_t* CTXb = (ushort_t*)(ws + 16777216);  // bf16 ctx
  float* Y2   = ws + 20971520;         // 4,194,304 (attn partials / conv out)
  float* Mb   = ws + 25165824;         // 65,536
  float* MV   = ws + 25231360;         // 2,048
  float* MVP  = ws + 25233408;         // 32,768
  float* BNps = ws + 25266176;         // 16,384
  float* BNpq = ws + 25282560;         // 16,384
  float* BNmu = ws + 25298944;         // 512
  float* BNvr = ws + 25299456;         // 512
  float* ZB   = ws + 25299968;         // 512 (zero bias)
  float* BQKV = ws + 25300480;         // 3,072 (concat qkv bias, 2 layers)
  int*   IDX  = (int*)(ws + 25303552); // 81,920
  int*   MT   = (int*)(ws + 25385472); // 1,280
  // ---- bf16 workspace ----
  ushort_t* U0   = (ushort_t*)(ws + 25386752);
  ushort_t* Xb   = U0;                 // 4,194,304
  ushort_t* Hb   = U0 + 4194304;       // 16,777,216 (FFN hidden / im2col)
  ushort_t* QKVb = Hb;                 // alias: bf16 QKV (12,582,912) —
                                       // live only QKV-GEMM -> qk_m, before
                                       // any FFN/im2col use of Hb
  ushort_t* Wqkvb= U0 + 20971520;      // 1,572,864 (2 layers x 1536 x 512)
  ushort_t* Wob  = U0 + 22544384;      // 524,288
  ushort_t* W1b  = U0 + 23068672;      // 2,097,152
  ushort_t* W2b  = U0 + 25165824;      // 2,097,152
  ushort_t* Cwb  = U0 + 27262976;      // 786,432
  ushort_t* Twb  = U0 + 28049408;      // 49,152
  ushort_t* Atok = U0 + 28098560;      // 786,432
  float* PEf = ws + 39829248;          // 1,048,576 (PE table)

  // ---- fused preamble (6 dispatches) ----
  castqkv_k<<<1536, 256, 0, stream>>>(Wq, Wk, Wv, Wqkvb);
  castw3_k<<<4656, 256, 0, stream>>>(Wo, W1, W2, tok_w, Wob, W1b, W2b, Twb);
  castw_conv_k<<<3072, 256, 0, stream>>>(conv_w, Cwb);
  setup_small_k<<<14, 256, 0, stream>>>(bq, bk, bv, ZB, BQKV);
  pe_k<<<4096, 256, 0, stream>>>(PEf);
  im2col_tok_k<<<3072, 256, 0, stream>>>(x_enc, Atok);

  // token embedding GEMM (+PE)
  mgemm_k<0, 2, 1><<<dim3(4, 64), 256, 0, stream>>>(
      Atok, Twb, ZB, X, Xb, PEf, 8192, DM, 96);

  for (int layer = 0; layer < 2; ++layer) {
    const int Lx = (layer == 0) ? 2048 : 1024;
    const int U  = (layer == 0) ? 40 : 35;
    const int M  = NB * Lx;
    const int NCH = 8;

    uint32_t kl0, kl1, s0, s1;
    threefry2x32(0u, 42u, 0u, (uint32_t)layer, &kl0, &kl1);
    threefry2x32(kl0, kl1, 0u, 1u, &s0, &s1);
    int nidx = Lx * U;
    gen_idx_k<<<(nidx + 255) / 256, 256, 0, stream>>>(IDX, nidx, Lx - 1, s0, s1);

    // fused QKV GEMM: N=1536, emits fp32 + bf16 copies
    mgemm_k<0, 2, 0><<<dim3(12, M / 128), 256, 0, stream>>>(
        Xb, Wqkvb + (size_t)layer * 786432, BQKV + layer * 1536, QKV, QKVb,
        nullptr, M, QS, DM);

    // ProbSparse attention: one wave per (b,l), bf16 K gather
    if (layer == 0)
      qk_m_k<40><<<Lx, 256, 0, stream>>>(QKV, QKVb, IDX, Mb, Lx);
    else
      qk_m_k<35><<<Lx, 256, 0, stream>>>(QKV, QKVb, IDX, Mb, Lx);
    topk_k<<<NB * NH, 256, 0, stream>>>(Mb, MT, Lx, U);
    meanv1_k<<<NB * 16, 512, 0, stream>>>(QKV, MVP, Lx);
    meanv2_k<<<NB, 512, 0, stream>>>(MVP, MV, Lx);
    fillctx_k<<<(M * DM / 4) / 256, 256, 0, stream>>>(CTXb, MV, Lx);
    attn_flash_k<<<NB * NH * NCH, 512, 0, stream>>>(QKV, MT, Y2, Lx, U, NCH);
    attn_merge_k<<<NB * NH * U, 64, 0, stream>>>(Y2, MT, CTXb, Lx, U, NCH);

    // output projection + residual + LN1 (emits bf16 for FFN1)
    mgemm_k<0, 0, 0><<<dim3(4, M / 128), 256, 0, stream>>>(
        CTXb, Wob + (size_t)layer * 262144, bo + layer * DM, Y2, nullptr,
        nullptr, M, DM, DM);
    ln_k<<<M, 128, 0, stream>>>(X, Y2, ln1_g + layer * DM, ln1_b + layer * DM, X, Xb);

    // FFN (GELU fused; hidden kept in bf16); LN2 emits bf16
    mgemm_k<1, 1, 0><<<dim3(16, M / 128), 256, 0, stream>>>(
        Xb, W1b + (size_t)layer * 1048576, b1 + layer * 2048, nullptr, Hb,
        nullptr, M, 2048, DM);
    mgemm_k<0, 0, 0><<<dim3(4, M / 128), 256, 0, stream>>>(
        Hb, W2b + (size_t)layer * 1048576, b2 + layer * DM, Y2, nullptr,
        nullptr, M, DM, 2048);
    ln_k<<<M, 128, 0, stream>>>(X, Y2, ln2_g + layer * DM, ln2_b + layer * DM, X, Xb);

    if (layer == 0) {
      im2col_k<<<12288, 256, 0, stream>>>(X, Hb);
      mgemm_k<0, 0, 0><<<dim3(4, 64), 256, 0, stream>>>(
          Hb, Cwb, conv_b, Y2, nullptr, nullptr, 8192, DM, 1536);
      bn1_k<<<32, 256, 0, stream>>>(Y2, BNps, BNpq);
      bn2_k<<<1, 512, 0, stream>>>(BNps, BNpq, BNmu, BNvr);
      bnpool_k<<<(NB * 1024 * 512) / 256, 256, 0, stream>>>(
          Y2, BNmu, BNvr, bn_g, bn_b, X, Xb);
    }
  }

  // final LN + projection (N=32, fp32); QKV region reused as scratch
  ln_k<<<NB * 1024, 128, 0, stream>>>(X, nullptr, normf_g, normf_b, QKV, nullptr);
  gemm_k<<<dim3(1, 4096 / 64), 256, 0, stream>>>(QKV, proj_w, proj_b, out,
                                                 4096, 32, DM);
}

// Round 9
// 846.955 us; speedup vs baseline: 4.7995x; 1.1004x over previous
//
#include <hip/hip_runtime.h>
#include <cstdint>
#include <cmath>

// ---------------------------------------------------------------------------
// Informer encoder forward (B=4, L=2048, ENC_IN=32, D_MODEL=512, D_FF=2048,
// E_LAYERS=2, H=8, FACTOR=5).
// Round 9: XCD-aware grid swizzle on all MFMA GEMMs (co-locate A-tile sharers
// per XCD-L2); QKV kept bf16-only end-to-end (attention reads bf16).
// ---------------------------------------------------------------------------

#define NB 4
#define DM 512
#define NH 8
#define HD 64
#define QS 1536  // QKV row stride

typedef unsigned short ushort_t;
typedef __bf16 bf16x8 __attribute__((ext_vector_type(8)));
typedef float floatx4 __attribute__((ext_vector_type(4)));
typedef unsigned short ushort8_t __attribute__((ext_vector_type(8)));

__device__ inline ushort_t f2b(float f) {
  uint32_t u = __float_as_uint(f);
  uint32_t r = (u + 0x7fffu + ((u >> 16) & 1u)) >> 16;
  return (ushort_t)r;
}
__device__ inline float b2f(ushort_t u) {
  return __uint_as_float((uint32_t)u << 16);
}

// ---------------- fused weight casts ---------------------------------------
__global__ void castqkv_k(const float* __restrict__ Wq,
                          const float* __restrict__ Wk,
                          const float* __restrict__ Wv,
                          ushort_t* __restrict__ out) {
  int gid = blockIdx.x * 256 + threadIdx.x;  // 393216 float4 units
  if (gid >= 393216) return;
  int ly = gid / 196608, r4 = gid - ly * 196608;
  int r = r4 >> 7, c4 = r4 & 127;
  int sel = r >> 9, srow = r & 511;
  const float* src = (sel == 0 ? Wq : sel == 1 ? Wk : Wv) + ly * 262144 +
                     srow * 512 + c4 * 4;
  float4 v = *(const float4*)src;
  ushort4 o;
  o.x = f2b(v.x); o.y = f2b(v.y); o.z = f2b(v.z); o.w = f2b(v.w);
  ((ushort4*)out)[ly * 196608 + r * 128 + c4] = o;
}

__global__ void castw3_k(const float* __restrict__ Wo,
                         const float* __restrict__ W1,
                         const float* __restrict__ W2,
                         const float* __restrict__ tw,
                         ushort_t* __restrict__ oWo, ushort_t* __restrict__ oW1,
                         ushort_t* __restrict__ oW2, ushort_t* __restrict__ otw) {
  int gid = blockIdx.x * 256 + threadIdx.x;  // 1,191,936 float4 units
  if (gid >= 1191936) return;
  const float* src;
  ushort4* dst;
  int i;
  if (gid < 131072) { src = Wo; dst = (ushort4*)oWo; i = gid; }
  else if (gid < 655360) { src = W1; dst = (ushort4*)oW1; i = gid - 131072; }
  else if (gid < 1179648) { src = W2; dst = (ushort4*)oW2; i = gid - 655360; }
  else { src = tw; dst = (ushort4*)otw; i = gid - 1179648; }
  float4 v = ((const float4*)src)[i];
  ushort4 o;
  o.x = f2b(v.x); o.y = f2b(v.y); o.z = f2b(v.z); o.w = f2b(v.w);
  dst[i] = o;
}

__global__ void castw_conv_k(const float* __restrict__ in,
                             ushort_t* __restrict__ out) {
  int gid = blockIdx.x * 256 + threadIdx.x;  // 512*1536
  int d = gid / 1536, r = gid - d * 1536;
  int t = r >> 9, i = r & 511;
  out[gid] = f2b(in[d * 1536 + i * 3 + t]);
}

__global__ void setup_small_k(const float* __restrict__ bq,
                              const float* __restrict__ bk,
                              const float* __restrict__ bv,
                              float* __restrict__ ZB,
                              float* __restrict__ BQKV) {
  int gid = blockIdx.x * 256 + threadIdx.x;  // 3584
  if (gid >= 3584) return;
  if (gid < 512) { ZB[gid] = 0.f; return; }
  int g = gid - 512;
  int layer = g / 1536, r = g - layer * 1536;
  float v;
  if (r < 512) v = bq[layer * 512 + r];
  else if (r < 1024) v = bk[layer * 512 + r - 512];
  else v = bv[layer * 512 + r - 1024];
  BQKV[g] = v;
}

__host__ __device__ inline void threefry2x32(uint32_t k0, uint32_t k1,
                                             uint32_t c0, uint32_t c1,
                                             uint32_t* o0, uint32_t* o1) {
  uint32_t ks0 = k0, ks1 = k1, ks2 = k0 ^ k1 ^ 0x1BD11BDAu;
  uint32_t x0 = c0 + ks0;
  uint32_t x1 = c1 + ks1;
  const uint32_t rotA[4] = {13u, 15u, 26u, 6u};
  const uint32_t rotB[4] = {17u, 29u, 16u, 24u};
  uint32_t ks[3] = {ks0, ks1, ks2};
  #pragma unroll
  for (int i = 0; i < 5; ++i) {
    const uint32_t* r = (i & 1) ? rotB : rotA;
    #pragma unroll
    for (int j = 0; j < 4; ++j) {
      x0 += x1;
      x1 = (x1 << r[j]) | (x1 >> (32u - r[j]));
      x1 ^= x0;
    }
    x0 += ks[(i + 1) % 3];
    x1 += ks[(i + 2) % 3] + (uint32_t)(i + 1);
  }
  *o0 = x0; *o1 = x1;
}

__global__ void gen_idx_k(int* __restrict__ idx, int n, int mask,
                          uint32_t k0, uint32_t k1) {
  int i = blockIdx.x * 256 + threadIdx.x;
  if (i < n) {
    uint32_t o0, o1;
    threefry2x32(k0, k1, 0u, (uint32_t)i, &o0, &o1);
    idx[i] = (int)((o0 ^ o1) & (uint32_t)mask);
  }
}

__device__ inline float wave_sum64(float v) {
  #pragma unroll
  for (int o = 32; o > 0; o >>= 1) v += __shfl_xor(v, o, 64);
  return v;
}
__device__ inline float wave_max64(float v) {
  #pragma unroll
  for (int o = 32; o > 0; o >>= 1) v = fmaxf(v, __shfl_xor(v, o, 64));
  return v;
}

// ---------------- positional-encoding table (2048 x 512) -------------------
__global__ void pe_k(float* __restrict__ pe) {
  int i = blockIdx.x * 256 + threadIdx.x;  // 1,048,576
  int d = i & 511, l = i >> 9;
  int j2 = d & ~1;
  float div = expf((float)j2 * -1.7988946039e-2f);  // -ln(10000)/512
  float ang = (float)l * div;
  pe[i] = (d & 1) ? cosf(ang) : sinf(ang);
}

// ---------------- im2col for token conv: (B*L, 96) bf16 --------------------
__global__ void im2col_tok_k(const float* __restrict__ xe,
                             ushort_t* __restrict__ A) {
  int gid = blockIdx.x * 256 + threadIdx.x;  // 8192*96
  int col = gid % 96;
  int row = gid / 96;
  int c = col / 3, t = col - c * 3;
  int b = row >> 11, l = row & 2047;
  int ls = (l + t - 1) & 2047;
  A[gid] = f2b(xe[((size_t)b * 2048 + ls) * 32 + c]);
}

// ---------------- bf16 MFMA GEMM with XCD swizzle --------------------------
// 1-D grid of X*Y blocks (Y = M/128, Y % 8 == 0). Swizzle co-locates the X
// blocks sharing an A row-tile on one XCD (id%8 round-robin assumption).
__device__ inline void gload16(const ushort_t* g, ushort_t* l) {
  __builtin_amdgcn_global_load_lds(
      (const __attribute__((address_space(1))) unsigned int*)(const void*)g,
      (__attribute__((address_space(3))) unsigned int*)(void*)l, 16, 0, 0);
}

template <int GELU, int OMODE, int ADDPE>  // OMODE: 0 f32, 1 bf16, 2 both
__global__ __launch_bounds__(256) void mgemm_k(
    const ushort_t* __restrict__ A, const ushort_t* __restrict__ W,
    const float* __restrict__ bias, float* __restrict__ Cf,
    ushort_t* __restrict__ Cb, const float* __restrict__ pe,
    int X, int ldc, int K) {
  __shared__ ushort_t As[128 * 32];
  __shared__ ushort_t Bs[128 * 32];
  int id = blockIdx.x;
  int cc = id & 7, j = id >> 3;
  int bx = j % X;
  int by = (j / X) * 8 + cc;
  int m0 = by * 128, n0 = bx * 128;
  int t = threadIdx.x;
  int lane = t & 63, wv = t >> 6;
  int sr = lane >> 2, sc = (lane & 3) * 8;
  int ra0 = wv * 32 + sr, ra1 = ra0 + 16;
  const ushort_t* gA0 = A + (size_t)(m0 + ra0) * K + sc;
  const ushort_t* gA1 = A + (size_t)(m0 + ra1) * K + sc;
  const ushort_t* gB0 = W + (size_t)(n0 + ra0) * K + sc;
  const ushort_t* gB1 = W + (size_t)(n0 + ra1) * K + sc;
  ushort_t* lA0 = As + wv * 1024;
  ushort_t* lA1 = lA0 + 512;
  ushort_t* lB0 = Bs + wv * 1024;
  ushort_t* lB1 = lB0 + 512;

  int quad = lane >> 4, lr = lane & 15;
  int wm = wv >> 1, wn = wv & 1;

  floatx4 acc[4][4] = {};
  for (int ks = 0; ks < K; ks += 32) {
    gload16(gA0, lA0);
    gload16(gA1, lA1);
    gload16(gB0, lB0);
    gload16(gB1, lB1);
    gA0 += 32; gA1 += 32; gB0 += 32; gB1 += 32;
    __syncthreads();
    bf16x8 av[4], bv[4];
    #pragma unroll
    for (int mt = 0; mt < 4; ++mt)
      av[mt] = *(const bf16x8*)&As[(wm * 64 + mt * 16 + lr) * 32 + quad * 8];
    #pragma unroll
    for (int nt = 0; nt < 4; ++nt)
      bv[nt] = *(const bf16x8*)&Bs[(wn * 64 + nt * 16 + lr) * 32 + quad * 8];
    #pragma unroll
    for (int mt = 0; mt < 4; ++mt)
      #pragma unroll
      for (int nt = 0; nt < 4; ++nt)
        acc[mt][nt] = __builtin_amdgcn_mfma_f32_16x16x32_bf16(
            av[mt], bv[nt], acc[mt][nt], 0, 0, 0);
    __syncthreads();
  }
  #pragma unroll
  for (int nt = 0; nt < 4; ++nt) {
    int col = n0 + wn * 64 + nt * 16 + lr;
    float bsv = bias[col];
    #pragma unroll
    for (int mt = 0; mt < 4; ++mt) {
      int row0 = m0 + wm * 64 + mt * 16 + quad * 4;
      #pragma unroll
      for (int r = 0; r < 4; ++r) {
        int row = row0 + r;
        float v = acc[mt][nt][r] + bsv;
        if (ADDPE) v += pe[(size_t)(row & 2047) * ldc + col];
        if (GELU) v = 0.5f * v * (1.0f + erff(v * 0.70710678118654752f));
        if (OMODE == 0 || OMODE == 2) Cf[(size_t)row * ldc + col] = v;
        if (OMODE == 1 || OMODE == 2) Cb[(size_t)row * ldc + col] = f2b(v);
      }
    }
  }
}

// ---------------- fp32 fallback GEMM (final projection, N=32) --------------
__global__ __launch_bounds__(256) void gemm_k(
    const float* __restrict__ A, const float* __restrict__ W,
    const float* __restrict__ bias, float* __restrict__ C,
    int M, int N, int K) {
  __shared__ float As2[16][64 + 4];
  __shared__ float Ws2[16][64 + 4];
  int m0 = blockIdx.y * 64, n0 = blockIdx.x * 64;
  int t = threadIdx.x;
  int tx = t & 15, ty = t >> 4;
  float acc[4][4] = {};
  for (int k0 = 0; k0 < K; k0 += 16) {
    #pragma unroll
    for (int i = 0; i < 4; ++i) {
      int li = t + i * 256;
      int m = li >> 4, kk = li & 15;
      As2[kk][m] = A[(size_t)(m0 + m) * K + k0 + kk];
    }
    #pragma unroll
    for (int i = 0; i < 4; ++i) {
      int li = t + i * 256;
      int n = li >> 4, kk = li & 15;
      int gn = n0 + n;
      Ws2[kk][n] = (gn < N) ? W[(size_t)gn * K + k0 + kk] : 0.0f;
    }
    __syncthreads();
    #pragma unroll
    for (int kk = 0; kk < 16; ++kk) {
      float4 avv = *(const float4*)&As2[kk][ty * 4];
      float4 bvv = *(const float4*)&Ws2[kk][tx * 4];
      float a[4] = {avv.x, avv.y, avv.z, avv.w};
      float bb[4] = {bvv.x, bvv.y, bvv.z, bvv.w};
      #pragma unroll
      for (int i = 0; i < 4; ++i)
        #pragma unroll
        for (int j = 0; j < 4; ++j) acc[i][j] += a[i] * bb[j];
    }
    __syncthreads();
  }
  #pragma unroll
  for (int i = 0; i < 4; ++i) {
    int m = m0 + ty * 4 + i;
    #pragma unroll
    for (int j = 0; j < 4; ++j) {
      int n = n0 + tx * 4 + j;
      if (n < N) C[(size_t)m * N + n] = acc[i][j] + bias[n];
    }
  }
}

// ---------------- LayerNorm (+optional residual, +optional bf16 copy) ------
__global__ __launch_bounds__(128) void ln_k(
    const float* __restrict__ A, const float* __restrict__ Bres,
    const float* __restrict__ g, const float* __restrict__ be,
    float* __restrict__ O, ushort_t* __restrict__ Ob) {
  int r = blockIdx.x, t = threadIdx.x;
  __shared__ float lds[2];
  float4 v = ((const float4*)(A + (size_t)r * DM))[t];
  if (Bres) {
    float4 u = ((const float4*)(Bres + (size_t)r * DM))[t];
    v.x += u.x; v.y += u.y; v.z += u.z; v.w += u.w;
  }
  float s = wave_sum64(v.x + v.y + v.z + v.w);
  int w = t >> 6;
  if ((t & 63) == 0) lds[w] = s;
  __syncthreads();
  float mu = (lds[0] + lds[1]) * (1.0f / 512.0f);
  __syncthreads();
  float dx = v.x - mu, dy = v.y - mu, dz = v.z - mu, dw = v.w - mu;
  float sq = wave_sum64(dx * dx + dy * dy + dz * dz + dw * dw);
  if ((t & 63) == 0) lds[w] = sq;
  __syncthreads();
  float var = (lds[0] + lds[1]) * (1.0f / 512.0f);
  float inv = 1.0f / sqrtf(var + 1e-5f);
  float4 gv = ((const float4*)g)[t];
  float4 bv = ((const float4*)be)[t];
  float4 o;
  o.x = dx * inv * gv.x + bv.x;
  o.y = dy * inv * gv.y + bv.y;
  o.z = dz * inv * gv.z + bv.z;
  o.w = dw * inv * gv.w + bv.w;
  ((float4*)(O + (size_t)r * DM))[t] = o;
  if (Ob) {
    ushort4 ob;
    ob.x = f2b(o.x); ob.y = f2b(o.y); ob.z = f2b(o.z); ob.w = f2b(o.w);
    ((ushort4*)(Ob + (size_t)r * DM))[t] = ob;
  }
}

// ---------------- M[b,h,l]: one wave per (b,l), all-bf16 QKV ---------------
template <int UU>
__global__ __launch_bounds__(256) void qk_m_k(
    const ushort_t* __restrict__ QKVb, const int* __restrict__ idx,
    float* __restrict__ Mout, int Lx) {
  int l = blockIdx.x;
  int b = threadIdx.x >> 6;  // wave = batch
  int lane = threadIdx.x & 63;
  const ushort_t* qp = QKVb + ((size_t)b * Lx + l) * QS + lane * 8;
  float q[8];
  {
    ushort8_t qv = *(const ushort8_t*)qp;
    #pragma unroll
    for (int c = 0; c < 8; ++c) q[c] = b2f(qv[c]);
  }
  const ushort_t* Kbase = QKVb + (size_t)b * Lx * QS + 512 + lane * 8;
  const int* ip = idx + (size_t)l * UU;
  float maxv = -INFINITY, sumv = 0.f;
  #pragma unroll
  for (int u0 = 0; u0 < UU; u0 += 8) {
    ushort8_t kv[8];
    #pragma unroll
    for (int j = 0; j < 8; ++j) {
      if (u0 + j < UU)
        kv[j] = *(const ushort8_t*)(Kbase + (size_t)ip[u0 + j] * QS);
    }
    #pragma unroll
    for (int j = 0; j < 8; ++j) {
      if (u0 + j < UU) {
        float p = 0.f;
        #pragma unroll
        for (int c = 0; c < 8; ++c) p += q[c] * b2f(kv[j][c]);
        p += __shfl_xor(p, 1, 64);
        p += __shfl_xor(p, 2, 64);
        p += __shfl_xor(p, 4, 64);
        maxv = fmaxf(maxv, p);
        sumv += p;
      }
    }
  }
  if ((lane & 7) == 0) {
    int h = lane >> 3;
    Mout[(size_t)(b * 8 + h) * Lx + l] = maxv - sumv / (float)Lx;
  }
}

// ---------------- top-U indices of M per (b,h) -----------------------------
__global__ __launch_bounds__(256) void topk_k(
    const float* __restrict__ Mbuf, int* __restrict__ Mtop, int Lx, int U) {
  int bh = blockIdx.x;
  const float* m = Mbuf + (size_t)bh * Lx;
  __shared__ float mcopy[2048];
  __shared__ float sv[256];
  __shared__ int si[256];
  int t = threadIdx.x;
  for (int i = t; i < Lx; i += 256) mcopy[i] = m[i];
  __syncthreads();
  for (int u = 0; u < U; ++u) {
    float bv = -INFINITY;
    int bi = 0x7fffffff;
    for (int i = t; i < Lx; i += 256) {
      float v = mcopy[i];
      if (v > bv || (v == bv && i < bi)) { bv = v; bi = i; }
    }
    sv[t] = bv; si[t] = bi;
    __syncthreads();
    for (int s = 128; s > 0; s >>= 1) {
      if (t < s) {
        float v2 = sv[t + s]; int i2 = si[t + s];
        if (v2 > sv[t] || (v2 == sv[t] && i2 < si[t])) { sv[t] = v2; si[t] = i2; }
      }
      __syncthreads();
    }
    if (t == 0) {
      Mtop[bh * U + u] = si[0];
      mcopy[si[0]] = -INFINITY;
    }
    __syncthreads();
  }
}

// ---------------- meanV from bf16 QKV (V at +1024) -------------------------
__global__ __launch_bounds__(512) void meanv1_k(const ushort_t* __restrict__ QKVb,
                                                float* __restrict__ part,
                                                int Lx) {
  int b = blockIdx.x >> 4, chunk = blockIdx.x & 15;
  int rows = Lx >> 4;
  int t = threadIdx.x;  // 512
  const ushort_t* vp =
      QKVb + ((size_t)b * Lx + (size_t)chunk * rows) * QS + 1024 + t;
  float s = 0.f;
  for (int l = 0; l < rows; ++l) s += b2f(vp[(size_t)l * QS]);
  part[(size_t)blockIdx.x * DM + t] = s;
}
__global__ __launch_bounds__(512) void meanv2_k(const float* __restrict__ part,
                                                float* __restrict__ mv,
                                                int Lx) {
  int b = blockIdx.x, t = threadIdx.x;
  float s = 0.f;
  #pragma unroll
  for (int c = 0; c < 16; ++c) s += part[(size_t)(b * 16 + c) * DM + t];
  mv[b * DM + t] = s / (float)Lx;
}

__global__ void fillctx_k(ushort_t* __restrict__ ctx,
                          const float* __restrict__ mv, int Lx) {
  size_t i4 = (size_t)blockIdx.x * 256 + threadIdx.x;
  int col4 = (int)(i4 & 127);
  size_t row = i4 >> 7;
  int b = (int)(row / (size_t)Lx);
  const float* m = mv + b * DM + col4 * 4;
  ushort4 o;
  o.x = f2b(m[0]); o.y = f2b(m[1]); o.z = f2b(m[2]); o.w = f2b(m[3]);
  ((ushort4*)ctx)[i4] = o;
}

// ---------------- flash split-K attention (bf16 QKV) -----------------------
__global__ __launch_bounds__(512) void attn_flash_k(
    const ushort_t* __restrict__ QKVb, const int* __restrict__ Mtop,
    float* __restrict__ part, int Lx, int U, int nchunk) {
  int blk = blockIdx.x;
  int chunk = blk % nchunk, bh = blk / nchunk;
  int h = bh & 7, b = bh >> 3;
  int rows = Lx / nchunk;
  int ntile = rows >> 6;
  __shared__ float s_q[40 * 64];
  __shared__ float s_k[64 * 65];
  __shared__ float s_v[64 * 65];
  __shared__ float s_p[40 * 64];
  __shared__ float s_m[40], s_l[40], s_a[40];
  int t = threadIdx.x;
  int d = t & 63, wv = t >> 6;

  for (int i = t; i < U * 64; i += 512) {
    int u = i >> 6, dd = i & 63;
    int qi = Mtop[bh * U + u];
    s_q[i] = b2f(QKVb[((size_t)b * Lx + qi) * QS + h * HD + dd]) * 0.125f;
  }
  if (t < U) { s_m[t] = -INFINITY; s_l[t] = 0.f; s_a[t] = 0.f; }
  float o[5] = {0.f, 0.f, 0.f, 0.f, 0.f};
  __syncthreads();

  const ushort_t* Kp = QKVb + (size_t)b * Lx * QS + 512 + h * HD;
  const ushort_t* Vp = QKVb + (size_t)b * Lx * QS + 1024 + h * HD;

  for (int tile = 0; tile < ntile; ++tile) {
    int kr0 = chunk * rows + tile * 64;
    {
      int r = t >> 3, c8 = (t & 7) * 8;  // 8 threads/row x 64 rows
      ushort8_t kv = *(const ushort8_t*)&Kp[(size_t)(kr0 + r) * QS + c8];
      ushort8_t vv = *(const ushort8_t*)&Vp[(size_t)(kr0 + r) * QS + c8];
      float* kd = &s_k[r * 65 + c8];
      float* vd = &s_v[r * 65 + c8];
      #pragma unroll
      for (int jj = 0; jj < 8; ++jj) {
        kd[jj] = b2f(kv[jj]);
        vd[jj] = b2f(vv[jj]);
      }
    }
    __syncthreads();
    {
      float kr[64];
      #pragma unroll
      for (int dd = 0; dd < 64; ++dd) kr[dd] = s_k[d * 65 + dd];
      for (int u = wv; u < U; u += 8) {
        float acc = 0.f;
        #pragma unroll
        for (int c = 0; c < 16; ++c) {
          float4 qv = *(const float4*)&s_q[u * 64 + c * 4];
          acc += qv.x * kr[c * 4] + qv.y * kr[c * 4 + 1] +
                 qv.z * kr[c * 4 + 2] + qv.w * kr[c * 4 + 3];
        }
        s_p[u * 64 + d] = acc;
      }
    }
    __syncthreads();
    for (int u = wv; u < U; u += 8) {
      float sv_ = s_p[u * 64 + d];
      float mx = wave_max64(sv_);
      float mold = s_m[u];
      float mnew = fmaxf(mold, mx);
      float e = expf(sv_ - mnew);
      float se = wave_sum64(e);
      s_p[u * 64 + d] = e;
      if (d == 0) {
        float alpha = expf(mold - mnew);
        s_a[u] = alpha;
        s_l[u] = s_l[u] * alpha + se;
        s_m[u] = mnew;
      }
    }
    __syncthreads();
    {
      float vr[64];
      #pragma unroll
      for (int k = 0; k < 64; ++k) vr[k] = s_v[k * 65 + d];
      int i = 0;
      for (int u = wv; u < U; u += 8, ++i) {
        float acc = 0.f;
        #pragma unroll
        for (int c = 0; c < 16; ++c) {
          float4 pv = *(const float4*)&s_p[u * 64 + c * 4];
          acc += pv.x * vr[c * 4] + pv.y * vr[c * 4 + 1] +
                 pv.z * vr[c * 4 + 2] + pv.w * vr[c * 4 + 3];
        }
        o[i] = o[i] * s_a[u] + acc;
      }
    }
    __syncthreads();
  }
  {
    int i = 0;
    for (int u = wv; u < U; u += 8, ++i) {
      float* pp = part + ((size_t)(bh * nchunk + chunk) * U + u) * 66;
      pp[d] = o[i];
      if (d == 0) { pp[64] = s_m[u]; pp[65] = s_l[u]; }
    }
  }
}

__global__ __launch_bounds__(64) void attn_merge_k(
    const float* __restrict__ part, const int* __restrict__ Mtop,
    ushort_t* __restrict__ ctx, int Lx, int U, int nchunk) {
  int bu = blockIdx.x;
  int u = bu % U, bh = bu / U;
  int h = bh & 7, b = bh >> 3;
  int d = threadIdx.x;  // 64
  float M = -INFINITY;
  for (int c = 0; c < nchunk; ++c)
    M = fmaxf(M, part[((size_t)(bh * nchunk + c) * U + u) * 66 + 64]);
  float L = 0.f, O = 0.f;
  for (int c = 0; c < nchunk; ++c) {
    const float* pp = part + ((size_t)(bh * nchunk + c) * U + u) * 66;
    float w = expf(pp[64] - M);
    L += pp[65] * w;
    O += pp[d] * w;
  }
  int qi = Mtop[bh * U + u];
  ctx[((size_t)b * Lx + qi) * DM + h * HD + d] = f2b(O / L);
}

// ---------------- distil im2col (circular, k=3) -> bf16, [t][c] layout -----
__global__ void im2col_k(const float* __restrict__ X,
                         ushort_t* __restrict__ A2) {
  int gid = blockIdx.x * 256 + threadIdx.x;  // 8192*3*128 ushort4 units
  int i4 = gid & 127;
  int rt = gid >> 7;
  int t = rt % 3, row = rt / 3;
  int b = row >> 11, l = row & 2047;
  int ls = (l + t - 1) & 2047;
  float4 v = ((const float4*)(X + ((size_t)b * 2048 + ls) * DM))[i4];
  ushort4 o;
  o.x = f2b(v.x); o.y = f2b(v.y); o.z = f2b(v.z); o.w = f2b(v.w);
  ((ushort4*)A2)[(size_t)row * 384 + t * 128 + i4] = o;
}

// ---------------- batch-norm stats: coalesced two-stage --------------------
__global__ __launch_bounds__(256) void bn1_k(const float* __restrict__ Y,
                                             float* __restrict__ ps,
                                             float* __restrict__ pq) {
  int blk = blockIdx.x;
  int t = threadIdx.x;
  float s0 = 0, q0 = 0, s1 = 0, q1 = 0;
  const float* base = Y + (size_t)blk * 256 * DM;
  for (int r = 0; r < 256; ++r) {
    float a = base[(size_t)r * DM + t];
    float b = base[(size_t)r * DM + t + 256];
    s0 += a; q0 += a * a; s1 += b; q1 += b * b;
  }
  ps[blk * DM + t] = s0; ps[blk * DM + t + 256] = s1;
  pq[blk * DM + t] = q0; pq[blk * DM + t + 256] = q1;
}
__global__ __launch_bounds__(512) void bn2_k(const float* __restrict__ ps,
                                             const float* __restrict__ pq,
                                             float* __restrict__ mu,
                                             float* __restrict__ var) {
  int t = threadIdx.x;
  float s = 0, q = 0;
  #pragma unroll
  for (int c = 0; c < 32; ++c) { s += ps[c * DM + t]; q += pq[c * DM + t]; }
  float m = s * (1.0f / 8192.f);
  mu[t] = m;
  var[t] = q * (1.0f / 8192.f) - m * m;
}

// fused bn+elu+maxpool(k=3,s=2,pad=1)
__global__ void bnpool_k(const float* __restrict__ Y,
                         const float* __restrict__ mu,
                         const float* __restrict__ var,
                         const float* __restrict__ g,
                         const float* __restrict__ be, float* __restrict__ O,
                         ushort_t* __restrict__ Ob) {
  size_t i = (size_t)blockIdx.x * 256 + threadIdx.x;  // 4*1024*512
  int c = (int)(i & 511);
  size_t row = i >> 9;
  int lo = (int)(row & 1023);
  int b = (int)(row >> 10);
  float sc = g[c] / sqrtf(var[c] + 1e-5f);
  float sh = be[c] - mu[c] * sc;
  int l0 = 2 * lo - 1;
  float m = -INFINITY;
  #pragma unroll
  for (int tt = 0; tt < 3; ++tt) {
    int l = l0 + tt;
    if (l >= 0 && l < 2048) {
      float v = Y[((size_t)b * 2048 + l) * DM + c] * sc + sh;
      v = v > 0.f ? v : expm1f(v);
      m = fmaxf(m, v);
    }
  }
  O[i] = m;
  Ob[i] = f2b(m);
}

// ---------------------------------------------------------------------------
extern "C" void kernel_launch(void* const* d_in, const int* in_sizes, int n_in,
                              void* d_out, int out_size, void* d_ws,
                              size_t ws_size, hipStream_t stream) {
  (void)in_sizes; (void)n_in; (void)out_size; (void)ws_size;
  const float* x_enc  = (const float*)d_in[0];
  const float* tok_w  = (const float*)d_in[1];
  const float* Wq     = (const float*)d_in[2];
  const float* bq     = (const float*)d_in[3];
  const float* Wk     = (const float*)d_in[4];
  const float* bk     = (const float*)d_in[5];
  const float* Wv     = (const float*)d_in[6];
  const float* bv     = (const float*)d_in[7];
  const float* Wo     = (const float*)d_in[8];
  const float* bo     = (const float*)d_in[9];
  const float* W1     = (const float*)d_in[10];
  const float* b1     = (const float*)d_in[11];
  const float* W2     = (const float*)d_in[12];
  const float* b2     = (const float*)d_in[13];
  const float* ln1_g  = (const float*)d_in[14];
  const float* ln1_b  = (const float*)d_in[15];
  const float* ln2_g  = (const float*)d_in[16];
  const float* ln2_b  = (const float*)d_in[17];
  const float* conv_w = (const float*)d_in[18];
  const float* conv_b = (const float*)d_in[19];
  const float* bn_g   = (const float*)d_in[20];
  const float* bn_b   = (const float*)d_in[21];
  const float* normf_g = (const float*)d_in[22];
  const float* normf_b = (const float*)d_in[23];
  const float* proj_w = (const float*)d_in[24];
  const float* proj_b = (const float*)d_in[25];
  float* out = (float*)d_out;
  float* ws = (float*)d_ws;

  // ---- fp32 workspace layout (float offsets) ----
  float* X    = ws;                    // 4,194,304
  float* SCR  = ws + 4194304;          // 12,582,912 (final-LN scratch, free)
  ushort_t* CTXb = (ushort_t*)(ws + 16777216);  // bf16 ctx
  float* Y2   = ws + 20971520;         // 4,194,304 (attn partials / conv out)
  float* Mb   = ws + 25165824;         // 65,536
  float* MV   = ws + 25231360;         // 2,048
  float* MVP  = ws + 25233408;         // 32,768
  float* BNps = ws + 25266176;         // 16,384
  float* BNpq = ws + 25282560;         // 16,384
  float* BNmu = ws + 25298944;         // 512
  float* BNvr = ws + 25299456;         // 512
  float* ZB   = ws + 25299968;         // 512 (zero bias)
  float* BQKV = ws + 25300480;         // 3,072 (concat qkv bias, 2 layers)
  int*   IDX  = (int*)(ws + 25303552); // 81,920
  int*   MT   = (int*)(ws + 25385472); // 1,280
  // ---- bf16 workspace ----
  ushort_t* U0   = (ushort_t*)(ws + 25386752);
  ushort_t* Xb   = U0;                 // 4,194,304
  ushort_t* Hb   = U0 + 4194304;       // 16,777,216 (FFN hidden / im2col)
  ushort_t* QKVb = Hb;                 // alias: bf16 QKV (12,582,912) — live
                                       // QKV-GEMM -> attn, before FFN uses Hb
  ushort_t* Wqkvb= U0 + 20971520;      // 1,572,864
  ushort_t* Wob  = U0 + 22544384;      // 524,288
  ushort_t* W1b  = U0 + 23068672;      // 2,097,152
  ushort_t* W2b  = U0 + 25165824;      // 2,097,152
  ushort_t* Cwb  = U0 + 27262976;      // 786,432
  ushort_t* Twb  = U0 + 28049408;      // 49,152
  ushort_t* Atok = U0 + 28098560;      // 786,432
  float* PEf = ws + 39829248;          // 1,048,576 (PE table)

  // ---- fused preamble ----
  castqkv_k<<<1536, 256, 0, stream>>>(Wq, Wk, Wv, Wqkvb);
  castw3_k<<<4656, 256, 0, stream>>>(Wo, W1, W2, tok_w, Wob, W1b, W2b, Twb);
  castw_conv_k<<<3072, 256, 0, stream>>>(conv_w, Cwb);
  setup_small_k<<<14, 256, 0, stream>>>(bq, bk, bv, ZB, BQKV);
  pe_k<<<4096, 256, 0, stream>>>(PEf);
  im2col_tok_k<<<3072, 256, 0, stream>>>(x_enc, Atok);

  // token embedding GEMM (+PE): X=4, Y=64 -> 256 blocks
  mgemm_k<0, 2, 1><<<256, 256, 0, stream>>>(
      Atok, Twb, ZB, X, Xb, PEf, 4, DM, 96);

  for (int layer = 0; layer < 2; ++layer) {
    const int Lx = (layer == 0) ? 2048 : 1024;
    const int U  = (layer == 0) ? 40 : 35;
    const int M  = NB * Lx;
    const int Yt = M / 128;
    const int NCH = 8;

    uint32_t kl0, kl1, s0, s1;
    threefry2x32(0u, 42u, 0u, (uint32_t)layer, &kl0, &kl1);
    threefry2x32(kl0, kl1, 0u, 1u, &s0, &s1);
    int nidx = Lx * U;
    gen_idx_k<<<(nidx + 255) / 256, 256, 0, stream>>>(IDX, nidx, Lx - 1, s0, s1);

    // fused QKV GEMM: bf16-only output, XCD-swizzled
    mgemm_k<0, 1, 0><<<12 * Yt, 256, 0, stream>>>(
        Xb, Wqkvb + (size_t)layer * 786432, BQKV + layer * 1536, nullptr, QKVb,
        nullptr, 12, QS, DM);

    // ProbSparse attention (all bf16 QKV)
    if (layer == 0)
      qk_m_k<40><<<Lx, 256, 0, stream>>>(QKVb, IDX, Mb, Lx);
    else
      qk_m_k<35><<<Lx, 256, 0, stream>>>(QKVb, IDX, Mb, Lx);
    topk_k<<<NB * NH, 256, 0, stream>>>(Mb, MT, Lx, U);
    meanv1_k<<<NB * 16, 512, 0, stream>>>(QKVb, MVP, Lx);
    meanv2_k<<<NB, 512, 0, stream>>>(MVP, MV, Lx);
    fillctx_k<<<(M * DM / 4) / 256, 256, 0, stream>>>(CTXb, MV, Lx);
    attn_flash_k<<<NB * NH * NCH, 512, 0, stream>>>(QKVb, MT, Y2, Lx, U, NCH);
    attn_merge_k<<<NB * NH * U, 64, 0, stream>>>(Y2, MT, CTXb, Lx, U, NCH);

    // output projection + residual + LN1 (emits bf16 for FFN1)
    mgemm_k<0, 0, 0><<<4 * Yt, 256, 0, stream>>>(
        CTXb, Wob + (size_t)layer * 262144, bo + layer * DM, Y2, nullptr,
        nullptr, 4, DM, DM);
    ln_k<<<M, 128, 0, stream>>>(X, Y2, ln1_g + layer * DM, ln1_b + layer * DM, X, Xb);

    // FFN (GELU fused; hidden kept in bf16); LN2 emits bf16
    mgemm_k<1, 1, 0><<<16 * Yt, 256, 0, stream>>>(
        Xb, W1b + (size_t)layer * 1048576, b1 + layer * 2048, nullptr, Hb,
        nullptr, 16, 2048, DM);
    mgemm_k<0, 0, 0><<<4 * Yt, 256, 0, stream>>>(
        Hb, W2b + (size_t)layer * 1048576, b2 + layer * DM, Y2, nullptr,
        nullptr, 4, DM, 2048);
    ln_k<<<M, 128, 0, stream>>>(X, Y2, ln2_g + layer * DM, ln2_b + layer * DM, X, Xb);

    if (layer == 0) {
      im2col_k<<<12288, 256, 0, stream>>>(X, Hb);
      mgemm_k<0, 0, 0><<<4 * 64, 256, 0, stream>>>(
          Hb, Cwb, conv_b, Y2, nullptr, nullptr, 4, DM, 1536);
      bn1_k<<<32, 256, 0, stream>>>(Y2, BNps, BNpq);
      bn2_k<<<1, 512, 0, stream>>>(BNps, BNpq, BNmu, BNvr);
      bnpool_k<<<(NB * 1024 * 512) / 256, 256, 0, stream>>>(
          Y2, BNmu, BNvr, bn_g, bn_b, X, Xb);
    }
  }

  // final LN + projection (N=32, fp32)
  ln_k<<<NB * 1024, 128, 0, stream>>>(X, nullptr, normf_g, normf_b, SCR, nullptr);
  gemm_k<<<dim3(1, 4096 / 64), 256, 0, stream>>>(SCR, proj_w, proj_b, out,
                                                 4096, 32, DM);
}